// Round 7
// baseline (992.654 us; speedup 1.0000x reference)
//
#include <hip/hip_runtime.h>
#include <cmath>

#define ALPHA 0.5f

// ============================================================================
// prep_all: pm_zero (16384 blocks) + weight transpose (792 blocks) fused into
// one launch — independent work, saves a launch gap and overlaps.
// ============================================================================
__global__ __launch_bounds__(256) void prep_all(
    const float* __restrict__ dw5, const float* __restrict__ dw4,
    const float* __restrict__ dw3, const float* __restrict__ dw2,
    const float* __restrict__ ew2, const float* __restrict__ ew3,
    const float* __restrict__ ew4, const float* __restrict__ ew5,
    float* __restrict__ t5, float* __restrict__ t4,
    float* __restrict__ t3, float* __restrict__ t2,
    float* __restrict__ e2, float* __restrict__ e3,
    float* __restrict__ e4, float* __restrict__ e5,
    float4* __restrict__ Pm4)
{
    const int bid = blockIdx.x;
    if (bid < 16384) {
        Pm4[bid * 256 + threadIdx.x] = make_float4(0.f, 0.f, 0.f, 0.f);
        return;
    }
    int idx = (bid - 16384) * 256 + threadIdx.x;   // total 202752
    if (idx >= 202752) return;
    const float* w; float* t; int CIN, COUT, loc; bool enc = false;
    if (idx < 36864)       { w = dw5; t = t5; CIN = 64; COUT = 64; loc = idx; }
    else if (idx < 73728)  { w = dw4; t = t4; CIN = 64; COUT = 64; loc = idx - 36864; }
    else if (idx < 92160)  { w = dw3; t = t3; CIN = 64; COUT = 32; loc = idx - 73728; }
    else if (idx < 101376) { w = dw2; t = t2; CIN = 32; COUT = 32; loc = idx - 92160; }
    else if (idx < 110592) { w = ew2; t = e2; CIN = 32; COUT = 32; loc = idx - 101376; enc = true; }
    else if (idx < 129024) { w = ew3; t = e3; CIN = 32; COUT = 64; loc = idx - 110592; enc = true; }
    else if (idx < 165888) { w = ew4; t = e4; CIN = 64; COUT = 64; loc = idx - 129024; enc = true; }
    else                   { w = ew5; t = e5; CIN = 64; COUT = 64; loc = idx - 165888; enc = true; }
    int wk = loc % 9; int r = loc / 9; int ci, co;
    if (enc) { ci = r % CIN;  co = r / CIN;  }   // src [co][ci][k]
    else     { co = r % COUT; ci = r / COUT; }   // src [ci][co][k]
    t[wk * CIN * COUT + ci * COUT + co] = w[loc];
}

// ============================================================================
// Encoder (unchanged from round 6).
// ============================================================================
__device__ __forceinline__ int a1map(int iy, int col) {
    return (col & 7)
         | ((iy & 2) << 2)                   // iy[1]        -> bit3
         | (((iy ^ (iy >> 2)) & 1) << 4)     // iy[0]^iy[2]  -> bit4
         | ((col & 8) << 2)                  // col[3]       -> bit5
         | ((iy & 4) << 4)                   // iy[2]        -> bit6
         | ((iy & 8) << 4);                  // iy[3]        -> bit7
}

__global__ __launch_bounds__(256, 4) void enc_fused(
    const float* __restrict__ x,
    const float* __restrict__ w1,  const float* __restrict__ b1,
    const float* __restrict__ w2t, const float* __restrict__ b2,
    const float* __restrict__ w3t, const float* __restrict__ b3,
    const float* __restrict__ w4t, const float* __restrict__ b4,
    const float* __restrict__ w5t, const float* __restrict__ b5,
    float* __restrict__ hout)
{
    __shared__ __align__(16) float smem[10240];   // 40960 B -> 4 blocks/CU
    float* a1s  = smem;          // [32][256] permuted conv1 output (8192 fl)
    float* bse  = smem + 8192;   // region B (2048 fl): aliased by phase
    float* imgs = bse;           // phase0: [32][40] = 1280
    float* a2s  = bse;           // phase1+: [32][64] = 2048
    float* a3s  = smem;          // post-conv2 overlay of a1s: [64][16] = 1024
    float* a4s  = smem + 1024;   // [64][4] = 256
    float* reds = smem + 1280;   // [4][64] = 256

    const int n = blockIdx.x;
    const int tid = threadIdx.x;

    const float* xi = x + n * 1024;
    #pragma unroll
    for (int i = 0; i < 4; i++) {
        int idx = tid + 256 * i;
        int iy = idx >> 5, ix = idx & 31;
        int col = (ix & 1) ? 20 + (ix >> 1) : (ix >> 1);
        imgs[iy * 40 + col] = xi[idx];
    }
    __syncthreads();

    // conv1
    {
        const int oy = tid >> 4, ox = tid & 15;
        float patch[9];
        #pragma unroll
        for (int ky = 0; ky < 3; ky++) {
            const int iy = 2 * oy - 1 + ky;
            #pragma unroll
            for (int kx = 0; kx < 3; kx++) {
                const int ix = 2 * ox - 1 + kx;
                bool v = (iy >= 0) && (ix >= 0);
                int col = (ix & 1) ? 20 + (ix >> 1) : (ix >> 1);
                patch[ky * 3 + kx] = v ? imgs[iy * 40 + col] : 0.f;
            }
        }
        const int ocol = (ox & 1) ? 8 + (ox >> 1) : (ox >> 1);
        const int sidx = a1map(oy, ocol);
        for (int c = 0; c < 32; c++) {
            float acc = b1[c];
            #pragma unroll
            for (int k = 0; k < 9; k++) acc = fmaf(patch[k], w1[c * 9 + k], acc);
            a1s[c * 256 + sidx] = fmaxf(acc, 0.f);
        }
    }
    __syncthreads();

    // conv2 (4 waves, 8 co per thread)
    {
        const int p = tid & 63, oy = p >> 3, ox = p & 7;
        const int c0u = __builtin_amdgcn_readfirstlane(tid >> 6);
        const int cobase = c0u * 8;
        float acc[8];
        #pragma unroll
        for (int r = 0; r < 8; r++) acc[r] = b2[cobase + r];
        int offs[9]; bool val[9];
        #pragma unroll
        for (int ky = 0; ky < 3; ky++) {
            const int iy = 2 * oy - 1 + ky;
            #pragma unroll
            for (int kx = 0; kx < 3; kx++) {
                const int ix = 2 * ox - 1 + kx;
                const bool v = (iy >= 0) && (ix >= 0);
                const int col = (ix & 1) ? 8 + (ix >> 1) : (ix >> 1);
                offs[ky * 3 + kx] = v ? a1map(iy, col) : 0;
                val[ky * 3 + kx] = v;
            }
        }
        for (int ci = 0; ci < 32; ci++) {
            float patch[9];
            #pragma unroll
            for (int k = 0; k < 9; k++)
                patch[k] = val[k] ? a1s[ci * 256 + offs[k]] : 0.f;
            const float* wci = w2t + ci * 32 + cobase;
            #pragma unroll
            for (int k = 0; k < 9; k++) {
                #pragma unroll
                for (int r = 0; r < 8; r++)
                    acc[r] = fmaf(patch[k], wci[k * 1024 + r], acc[r]);
            }
        }
        __syncthreads();
        #pragma unroll
        for (int r = 0; r < 8; r++)
            a2s[(cobase + r) * 64 + p] = fmaxf(acc[r], 0.f);
    }
    __syncthreads();

    // conv3 (4 waves, 4 co per thread)
    {
        const int px = tid & 15, oy = px >> 2, ox = px & 3;
        const int cg = tid >> 4;
        float4 bv = ((const float4*)b3)[cg];
        float acc[4] = {bv.x, bv.y, bv.z, bv.w};
        for (int ci = 0; ci < 32; ci++) {
            float patch[9];
            #pragma unroll
            for (int ky = 0; ky < 3; ky++) {
                const int iy = 2 * oy - 1 + ky;
                #pragma unroll
                for (int kx = 0; kx < 3; kx++) {
                    const int ix = 2 * ox - 1 + kx;
                    bool v = (iy >= 0) && (ix >= 0);
                    patch[ky * 3 + kx] = v ? a2s[ci * 64 + iy * 8 + ix] : 0.f;
                }
            }
            #pragma unroll
            for (int k = 0; k < 9; k++) {
                float4 wv = *(const float4*)(w3t + k * 2048 + ci * 64 + cg * 4);
                acc[0] = fmaf(patch[k], wv.x, acc[0]);
                acc[1] = fmaf(patch[k], wv.y, acc[1]);
                acc[2] = fmaf(patch[k], wv.z, acc[2]);
                acc[3] = fmaf(patch[k], wv.w, acc[3]);
            }
        }
        #pragma unroll
        for (int r = 0; r < 4; r++)
            a3s[(cg * 4 + r) * 16 + px] = fmaxf(acc[r], 0.f);
    }
    __syncthreads();

    // conv4 (round-5 restructured form)
    {
        const int co = tid & 63;
        const int part = __builtin_amdgcn_readfirstlane(tid >> 6);
        float a0 = 0.f, a1 = 0.f, a2 = 0.f, a3 = 0.f;
        for (int ci = part * 16; ci < part * 16 + 16; ci++) {
            const float* wp = w4t + ci * 64 + co;
            const float w0 = wp[0];
            const float w1 = wp[4096];
            const float w2 = wp[8192];
            const float w3 = wp[12288];
            const float w4 = wp[16384];
            const float w5 = wp[20480];
            const float w6 = wp[24576];
            const float w7 = wp[28672];
            const float w8 = wp[32768];
            const float4 r0 = *(const float4*)(a3s + ci * 16);
            const float4 r1 = *(const float4*)(a3s + ci * 16 + 4);
            const float4 r2 = *(const float4*)(a3s + ci * 16 + 8);
            const float4 r3 = *(const float4*)(a3s + ci * 16 + 12);
            a0 = fmaf(r0.x, w4, a0); a0 = fmaf(r0.y, w5, a0);
            a0 = fmaf(r1.x, w7, a0); a0 = fmaf(r1.y, w8, a0);
            a1 = fmaf(r0.y, w3, a1); a1 = fmaf(r0.z, w4, a1); a1 = fmaf(r0.w, w5, a1);
            a1 = fmaf(r1.y, w6, a1); a1 = fmaf(r1.z, w7, a1); a1 = fmaf(r1.w, w8, a1);
            a2 = fmaf(r1.x, w1, a2); a2 = fmaf(r1.y, w2, a2);
            a2 = fmaf(r2.x, w4, a2); a2 = fmaf(r2.y, w5, a2);
            a2 = fmaf(r3.x, w7, a2); a2 = fmaf(r3.y, w8, a2);
            a3 = fmaf(r1.y, w0, a3); a3 = fmaf(r1.z, w1, a3); a3 = fmaf(r1.w, w2, a3);
            a3 = fmaf(r2.y, w3, a3); a3 = fmaf(r2.z, w4, a3); a3 = fmaf(r2.w, w5, a3);
            a3 = fmaf(r3.y, w6, a3); a3 = fmaf(r3.z, w7, a3); a3 = fmaf(r3.w, w8, a3);
        }
        float* reds2 = bse;   // a2s dead after conv3
        reds2[part * 256 +   0 + co] = a0;
        reds2[part * 256 +  64 + co] = a1;
        reds2[part * 256 + 128 + co] = a2;
        reds2[part * 256 + 192 + co] = a3;
        __syncthreads();
        {
            const int co2 = tid & 63;
            const int cls2 = __builtin_amdgcn_readfirstlane(tid >> 6);
            float s = b4[co2]
                    + reds2[      cls2 * 64 + co2] + reds2[256 + cls2 * 64 + co2]
                    + reds2[512 + cls2 * 64 + co2] + reds2[768 + cls2 * 64 + co2];
            a4s[co2 * 4 + cls2] = fmaxf(s, 0.f);
        }
    }
    __syncthreads();

    // conv5
    {
        const int c = tid & 63, part = tid >> 6;
        float s = 0.f;
        for (int ci = part * 16; ci < part * 16 + 16; ci++) {
            const float4 av = *(const float4*)(a4s + ci * 4);
            s = fmaf(av.x, w5t[4 * 4096 + ci * 64 + c], s);
            s = fmaf(av.y, w5t[5 * 4096 + ci * 64 + c], s);
            s = fmaf(av.z, w5t[7 * 4096 + ci * 64 + c], s);
            s = fmaf(av.w, w5t[8 * 4096 + ci * 64 + c], s);
        }
        reds[part * 64 + c] = s;
    }
    __syncthreads();
    if (tid < 64) {
        float v = b5[tid] + reds[tid] + reds[64 + tid] + reds[128 + tid] + reds[192 + tid];
        hout[n * 64 + tid] = fmaxf(v, 0.f);
    }
}

// ============================================================================
// FC heads (unchanged): mu -> d_out; D/B heads -> Pm directly.
// ============================================================================
__global__ __launch_bounds__(256) void fc_enc(
    const float* __restrict__ h,
    const float* __restrict__ wmu, const float* __restrict__ bmu,
    const float* __restrict__ wD,  const float* __restrict__ bD,
    const float* __restrict__ wB,  const float* __restrict__ bB,
    float* __restrict__ mu, float* __restrict__ Pm)
{
    __shared__ float As[32][65];
    __shared__ float Bs[32][65];
    const int tid = threadIdx.x;
    const int m0 = blockIdx.y * 64;
    const int n0 = blockIdx.x * 64;

    const float* wbase; const float* bias; int nloc; int region;
    if (n0 < 256)       { wbase = wmu; bias = bmu; nloc = n0;        region = 0; }
    else if (n0 < 4352) { wbase = wD;  bias = bD;  nloc = n0 - 256;  region = 1; }
    else                { wbase = wB;  bias = bB;  nloc = n0 - 4352; region = 2; }

    const int tx = tid & 15, ty = tid >> 4;
    float acc[4][4] = {};
    for (int k0 = 0; k0 < 1024; k0 += 32) {
        #pragma unroll
        for (int s = 0; s < 8; s++) {
            int l = tid + 256 * s;
            int row = l >> 5, kk = l & 31;
            As[kk][row] = h[(m0 + row) * 1024 + k0 + kk];
            Bs[kk][row] = wbase[(nloc + row) * 1024 + k0 + kk];
        }
        __syncthreads();
        #pragma unroll
        for (int kk = 0; kk < 32; kk++) {
            float av[4], bv[4];
            #pragma unroll
            for (int i = 0; i < 4; i++) av[i] = As[kk][ty * 4 + i];
            #pragma unroll
            for (int j = 0; j < 4; j++) bv[j] = Bs[kk][tx * 4 + j];
            #pragma unroll
            for (int i = 0; i < 4; i++)
                #pragma unroll
                for (int j = 0; j < 4; j++) acc[i][j] = fmaf(av[i], bv[j], acc[i][j]);
        }
        __syncthreads();
    }
    #pragma unroll
    for (int i = 0; i < 4; i++) {
        int m = m0 + ty * 4 + i;
        size_t pbase = (size_t)m * 65536;
        #pragma unroll
        for (int j = 0; j < 4; j++) {
            int nc = nloc + tx * 4 + j;
            float v = acc[i][j] + bias[nc];
            if (region == 0) {
                mu[m * 256 + nc] = v;
            } else {
                int t = nc >> 8, pi = (nc >> 4) & 15, pj = nc & 15;
                if (region == 1) {
                    int row = t * 16 + pi, col = t * 16 + pj;
                    Pm[pbase + row * 256 + col] = v + (pi == pj ? ALPHA : 0.f);
                } else {
                    int row = (t + 1) * 16 + pi, col = t * 16 + pj;
                    Pm[pbase + row * 256 + col] = v;      // sub-diagonal
                    Pm[pbase + col * 256 + row] = v;      // super-diagonal (transposed)
                }
            }
        }
    }
}

// ============================================================================
// Banded Cholesky v2 (unchanged from round 3)
// ============================================================================
__global__ __launch_bounds__(64) void chol_band(
    const float* __restrict__ Pm, float* __restrict__ Lb_g)
{
    __shared__ float Lb[256 * 32 + 32];   // +32 zero pad for row-255 overread
    __shared__ float Ds[4096];
    __shared__ float Bs2[3840];
    const int b = blockIdx.x, lane = threadIdx.x;
    const float* Pb = Pm + (size_t)b * 65536;
    for (int i = lane; i < 8224; i += 64) Lb[i] = 0.f;
    for (int i = lane; i < 4096; i += 64) {
        int t = i >> 8, r = (i >> 4) & 15, c = i & 15;
        Ds[i] = Pb[(t * 16 + r) * 256 + t * 16 + c];
    }
    for (int i = lane; i < 3840; i += 64) {
        int t = i >> 8, r = (i >> 4) & 15, c = i & 15;
        Bs2[i] = Pb[((t + 1) * 16 + r) * 256 + t * 16 + c];
    }
    __syncthreads();

    const int d = lane;
    for (int j = 0; j < 256; j++) {
        const int i = j + d;
        float s = 0.f;
        if (d < 32 && i < 256) {
            int bi = i >> 4, bj = j >> 4, pi = i & 15, pj = j & 15;
            float a;
            if (bi == bj)           a = Ds[bi * 256 + pi * 16 + pj];
            else if (bi == bj + 1)  a = Bs2[bj * 256 + pi * 16 + pj];
            else                    a = 0.f;

            // batched loads: all independent, one wait
            float c[32], p[32];
            const float* cp = Lb + j * 32;
            #pragma unroll
            for (int q = 0; q < 8; q++)
                *(float4*)(c + 4 * q) = *(const float4*)(cp + 4 * q);
            const float* pp = Lb + i * 32 + d;
            #pragma unroll
            for (int m = 1; m < 32; m++) p[m] = pp[m];

            float s0 = 0.f, s1 = 0.f, s2 = 0.f, s3 = 0.f;
            #pragma unroll
            for (int m = 1; m <= 28; m += 4) {
                s0 = fmaf(p[m],     c[m],     s0);
                s1 = fmaf(p[m + 1], c[m + 1], s1);
                s2 = fmaf(p[m + 2], c[m + 2], s2);
                s3 = fmaf(p[m + 3], c[m + 3], s3);
            }
            s0 = fmaf(p[29], c[29], s0);
            s1 = fmaf(p[30], c[30], s1);
            s2 = fmaf(p[31], c[31], s2);
            s = a - ((s0 + s1) + (s2 + s3));
        }
        float diag = __shfl(s, 0);
        float Ljj = sqrtf(diag);
        if (d == 0)                  Lb[j * 32] = Ljj;
        else if (d < 32 && i < 256)  Lb[i * 32 + d] = s / Ljj;
        __syncthreads();
    }
    for (int i = lane; i < 8192; i += 64) Lb_g[b * 8192 + i] = Lb[i];
}

// ============================================================================
// cov = inv(L) v3: Lr broadcast reads vectorized to 8x ds_read_b128
// (was 31 scalar ds_read_b32 per row; inv_band runs at 1 block/CU so per-wave
// issue count is the critical path). Same values, same fma order.
// ============================================================================
__global__ __launch_bounds__(256) void inv_band(
    const float* __restrict__ Lb_g, float* __restrict__ cov)
{
    __shared__ __align__(16) float Ls[8192];
    __shared__ float rs[256];
    const int b = blockIdx.x, j = threadIdx.x;
    float* covb = cov + (size_t)b * 65536;

    // stage band (float4-coalesced)
    {
        const float4* src = (const float4*)(Lb_g + b * 8192);
        float4* dst = (float4*)Ls;
        #pragma unroll
        for (int q = 0; q < 8; q++) dst[j + 256 * q] = src[j + 256 * q];
    }
    __syncthreads();
    rs[j] = 1.f / Ls[j * 32];
    __syncthreads();

    const int w = __builtin_amdgcn_readfirstlane(j >> 6);
    const int istart = w * 64;                 // 32-aligned, <= any j in wave

    // rows above istart are strictly upper-triangular for this wave -> zero
    for (int i = 0; i < istart; i++) covb[i * 256 + j] = 0.f;

    float g[32];
    #pragma unroll
    for (int q = 0; q < 32; q++) g[q] = 0.f;

    for (int c = istart; c < 256; c += 32) {
        #pragma unroll
        for (int u = 0; u < 32; u++) {
            const int i = c + u;                       // wave-uniform
            const float* Lr = Ls + i * 32;             // broadcast LDS reads
            float lrow[32];
            #pragma unroll
            for (int q = 0; q < 8; q++)
                *(float4*)(lrow + 4 * q) = *(const float4*)(Lr + 4 * q);
            float s0 = 0.f, s1 = 0.f, s2 = 0.f, s3 = 0.f;
            #pragma unroll
            for (int d = 1; d < 32; d += 4) {
                s0 = fmaf(lrow[d],     g[(u - d) & 31],     s0);
                if (d + 1 < 32) s1 = fmaf(lrow[d + 1], g[(u - d - 1) & 31], s1);
                if (d + 2 < 32) s2 = fmaf(lrow[d + 2], g[(u - d - 2) & 31], s2);
                if (d + 3 < 32) s3 = fmaf(lrow[d + 3], g[(u - d - 3) & 31], s3);
            }
            float s = (s0 + s1) + (s2 + s3);
            float gi = (((i == j) ? 1.f : 0.f) - s) * rs[i];
            g[u & 31] = gi;
            covb[i * 256 + j] = gi;                    // coalesced
        }
    }
}

// ============================================================================
// z = mu + cov @ eps (unchanged)
// ============================================================================
__global__ __launch_bounds__(256) void zvec_k(
    const float* __restrict__ cov, const float* __restrict__ mu,
    const float* __restrict__ eps, float* __restrict__ z)
{
    __shared__ float es[256];
    const int b = blockIdx.x, i = threadIdx.x;
    es[i] = eps[b * 256 + i];
    __syncthreads();
    const float4* row = (const float4*)(cov + (size_t)b * 65536 + i * 256);
    float s = 0.f;
    #pragma unroll 8
    for (int k = 0; k < 64; k++) {
        float4 v = row[k];
        s = fmaf(v.x, es[4 * k], s);
        s = fmaf(v.y, es[4 * k + 1], s);
        s = fmaf(v.z, es[4 * k + 2], s);
        s = fmaf(v.w, es[4 * k + 3], s);
    }
    z[b * 256 + i] = mu[b * 256 + i] + s;
}

// ============================================================================
// fc_dec + mu_fix fused (independent work; runs after zvec so the mu
// rewrite cannot race zvec's mu read). bid<1024 -> fc_dec; else mu_fix.
// ============================================================================
__global__ __launch_bounds__(256) void fc_dec_mu(
    const float* __restrict__ z, const float* __restrict__ w,
    const float* __restrict__ bias, float* __restrict__ hd0,
    const float* __restrict__ h, const float* __restrict__ wmu,
    const float* __restrict__ bmu, float* __restrict__ mu)
{
    __shared__ float sh[1024];
    const int blk = blockIdx.x;
    if (blk < 1024) {
        // fc_dec
        const int b = blk >> 2;
        const int f = ((blk & 3) << 8) + threadIdx.x;
        sh[threadIdx.x] = z[b * 256 + threadIdx.x];
        __syncthreads();
        const float4* wr = (const float4*)(w + f * 256);
        float s = 0.f;
        #pragma unroll 8
        for (int k = 0; k < 64; k++) {
            float4 v = wr[k];
            s = fmaf(v.x, sh[4 * k], s);
            s = fmaf(v.y, sh[4 * k + 1], s);
            s = fmaf(v.z, sh[4 * k + 2], s);
            s = fmaf(v.w, sh[4 * k + 3], s);
        }
        hd0[b * 1024 + f] = s + bias[f];
    } else {
        // mu_fix
        const int b = blk - 1024, p = threadIdx.x;
        #pragma unroll
        for (int i = 0; i < 4; i++) sh[p + 256 * i] = h[b * 1024 + p + 256 * i];
        __syncthreads();
        const float4* wr = (const float4*)(wmu + p * 1024);
        float s = 0.f;
        #pragma unroll 8
        for (int k = 0; k < 256; k++) {
            float4 v = wr[k];
            s = fmaf(v.x, sh[4 * k], s);
            s = fmaf(v.y, sh[4 * k + 1], s);
            s = fmaf(v.z, sh[4 * k + 2], s);
            s = fmaf(v.w, sh[4 * k + 3], s);
        }
        mu[b * 256 + p] = s + bmu[p];
    }
}

// ============================================================================
// Decoder v5: T1 tap dedup (9 guarded LDS reads -> 4 distinct values per ci,
// reused across 9 fma; fma order per output unchanged -> bitwise identical).
// T5: d0 reads vectorized to 16x ds_read_b128 (same fma order).
// ============================================================================
__device__ __forceinline__ float eluf(float v) { return v > 0.f ? v : expf(v) - 1.f; }

template<int OY>
__device__ __forceinline__ void t4_row(
    const float* __restrict__ wt4t, const float* __restrict__ bt4,
    const float* __restrict__ d1, float* __restrict__ d2, int co)
{
    float a0 = 0.f, a1 = 0.f, a2 = 0.f, a3 = 0.f;
    const float* wb = wt4t + co;
    for (int ci = 0; ci < 64; ci++) {
        const float* base = d1 + ci * 12;
        if (OY % 2 == 0) {
            float4 r = *(const float4*)(base + (OY / 2) * 4);
            float w10 = wb[3 * 4096 + ci * 64];
            float w11 = wb[4 * 4096 + ci * 64];
            float w12 = wb[5 * 4096 + ci * 64];
            a0 = fmaf(r.x, w11, a0);
            a1 = fmaf(r.x, w12, a1); a1 = fmaf(r.y, w10, a1);
            a2 = fmaf(r.y, w11, a2);
            a3 = fmaf(r.y, w12, a3); a3 = fmaf(r.z, w10, a3);
        } else {
            float4 ra = *(const float4*)(base + ((OY - 1) / 2) * 4);
            float4 rb = *(const float4*)(base + ((OY + 1) / 2) * 4);
            float w20 = wb[6 * 4096 + ci * 64], w21 = wb[7 * 4096 + ci * 64], w22 = wb[8 * 4096 + ci * 64];
            float w00 = wb[0 * 4096 + ci * 64], w01 = wb[1 * 4096 + ci * 64], w02 = wb[2 * 4096 + ci * 64];
            a0 = fmaf(ra.x, w21, a0); a0 = fmaf(rb.x, w01, a0);
            a1 = fmaf(ra.x, w22, a1); a1 = fmaf(ra.y, w20, a1);
            a1 = fmaf(rb.x, w02, a1); a1 = fmaf(rb.y, w00, a1);
            a2 = fmaf(ra.y, w21, a2); a2 = fmaf(rb.y, w01, a2);
            a3 = fmaf(ra.y, w22, a3); a3 = fmaf(ra.z, w20, a3);
            a3 = fmaf(rb.y, w02, a3); a3 = fmaf(rb.z, w00, a3);
        }
    }
    float b = bt4[co];
    float4 o = make_float4(eluf(a0 + b), eluf(a1 + b), eluf(a2 + b), eluf(a3 + b));
    *(float4*)(d2 + co * 44 + OY * 8) = o;
}

template<int M>
__device__ __forceinline__ void xrow(float* acc, const float* R, float w0, float w1, float w2)
{
    #pragma unroll
    for (int m = 0; m < M; m++) {
        acc[2 * m]     = fmaf(R[m], w1, acc[2 * m]);
        acc[2 * m + 1] = fmaf(R[m], w2, acc[2 * m + 1]);
        acc[2 * m + 1] = fmaf(R[m + 1], w0, acc[2 * m + 1]);
    }
}

__global__ __launch_bounds__(256, 4) void dec_fused(
    const float* __restrict__ hd0,
    const float* __restrict__ wt5t, const float* __restrict__ bt5,
    const float* __restrict__ wt4t, const float* __restrict__ bt4,
    const float* __restrict__ wt3t, const float* __restrict__ bt3,
    const float* __restrict__ wt2t, const float* __restrict__ bt2,
    const float* __restrict__ wt1,  const float* __restrict__ bt1,
    float* __restrict__ xr)
{
    __shared__ __align__(16) float smem[9664];   // 38656 B -> 4 blocks/CU
    float* d0  = smem;            // 64
    float* d1  = smem + 64;       // [64][3][4] pitch 12
    float* d2  = smem + 832;      // [64][44], rows pitch 8 (5 rows)
    float* scr = smem + 3648;     // [128][20]
    float* d3  = smem + 6208;     // [32][108], rows pitch 12 (9 rows)
    float* d4  = smem;            // [32][260] overlays A+scr+d3 after T2 barrier

    const int n = blockIdx.x, tid = threadIdx.x;

    for (int i = tid; i < 3584; i += 256) smem[64 + i] = 0.f;
    for (int i = tid; i < 3456; i += 256) d3[i] = 0.f;
    if (tid < 64) d0[tid] = hd0[n * 64 + tid];
    __syncthreads();

    // T5 (d0 via float4; same fma order)
    {
        const int co = tid & 63;
        const int wv = __builtin_amdgcn_readfirstlane(tid >> 6);
        const int oy = wv >> 1, ox = wv & 1;
        const int wk = (oy + 1) * 3 + (ox + 1);
        const float* wp = wt5t + wk * 4096 + co;
        float s = bt5[co];
        #pragma unroll
        for (int q = 0; q < 16; q++) {
            float4 dv = *(const float4*)(d0 + 4 * q);
            s = fmaf(dv.x, wp[(4 * q) * 64], s);
            s = fmaf(dv.y, wp[(4 * q + 1) * 64], s);
            s = fmaf(dv.z, wp[(4 * q + 2) * 64], s);
            s = fmaf(dv.w, wp[(4 * q + 3) * 64], s);
        }
        d1[co * 12 + oy * 4 + ox] = eluf(s);
    }
    __syncthreads();

    // T4
    {
        const int co = tid & 63;
        const int oyw = __builtin_amdgcn_readfirstlane(tid >> 6);
        if (oyw == 0)      t4_row<0>(wt4t, bt4, d1, d2, co);
        else if (oyw == 1) t4_row<1>(wt4t, bt4, d1, d2, co);
        else if (oyw == 2) t4_row<2>(wt4t, bt4, d1, d2, co);
        else               t4_row<3>(wt4t, bt4, d1, d2, co);
    }
    __syncthreads();

    // T3
    {
        const int co = tid & 31, pr = (tid >> 5) & 3, cih = tid >> 7;
        const int e = (pr & 1) ? 7 - pr : pr;
        const int o = (pr & 1) ? pr : 7 - pr;
        const int iy_e = e >> 1, iy_o2 = (o - 1) >> 1, iy_o0 = (o + 1) >> 1;
        float acce[8] = {}, acco[8] = {};
        const float* wb = wt3t + co;
        for (int c = 0; c < 32; c++) {
            const int ci = cih * 32 + c;
            const float* base = d2 + ci * 44;
            float re[8], ro2[8], ro0[8];
            *(float4*)(re)      = *(const float4*)(base + iy_e * 8);
            *(float4*)(re + 4)  = *(const float4*)(base + iy_e * 8 + 4);
            *(float4*)(ro2)     = *(const float4*)(base + iy_o2 * 8);
            *(float4*)(ro2 + 4) = *(const float4*)(base + iy_o2 * 8 + 4);
            *(float4*)(ro0)     = *(const float4*)(base + iy_o0 * 8);
            *(float4*)(ro0 + 4) = *(const float4*)(base + iy_o0 * 8 + 4);
            float w10 = wb[3 * 2048 + ci * 32], w11 = wb[4 * 2048 + ci * 32], w12 = wb[5 * 2048 + ci * 32];
            float w20 = wb[6 * 2048 + ci * 32], w21 = wb[7 * 2048 + ci * 32], w22 = wb[8 * 2048 + ci * 32];
            float w00 = wb[0 * 2048 + ci * 32], w01 = wb[1 * 2048 + ci * 32], w02 = wb[2 * 2048 + ci * 32];
            xrow<4>(acce, re, w10, w11, w12);
            xrow<4>(acco, ro2, w20, w21, w22);
            xrow<4>(acco, ro0, w00, w01, w02);
        }
        if (cih == 1) {
            float* s = scr + (tid - 128) * 20;
            #pragma unroll
            for (int k = 0; k < 8; k++) { s[k] = acce[k]; s[8 + k] = acco[k]; }
        }
        __syncthreads();
        if (cih == 0) {
            const float* s = scr + tid * 20;
            const float b = bt3[co];
            float* oe = d3 + co * 108 + e * 12;
            float* oo = d3 + co * 108 + o * 12;
            #pragma unroll
            for (int k = 0; k < 8; k++) {
                oe[k] = eluf(acce[k] + s[k] + b);
                oo[k] = eluf(acco[k] + s[8 + k] + b);
            }
        }
    }
    __syncthreads();

    // T2 — register-staged output: accumulate (reads d3), barrier, store d4.
    {
        const int co = tid & 31, org = tid >> 5;
        float acc0[16] = {}, acc1[16] = {};
        const float* wb = wt2t + co;
        for (int ci = 0; ci < 32; ci++) {
            const float* base = d3 + ci * 108 + org * 12;
            float A[12], B[12];
            #pragma unroll
            for (int q = 0; q < 3; q++) {
                *(float4*)(A + 4 * q) = *(const float4*)(base + 4 * q);
                *(float4*)(B + 4 * q) = *(const float4*)(base + 12 + 4 * q);
            }
            float w10 = wb[3 * 1024 + ci * 32], w11 = wb[4 * 1024 + ci * 32], w12 = wb[5 * 1024 + ci * 32];
            float w20 = wb[6 * 1024 + ci * 32], w21 = wb[7 * 1024 + ci * 32], w22 = wb[8 * 1024 + ci * 32];
            float w00 = wb[0 * 1024 + ci * 32], w01 = wb[1 * 1024 + ci * 32], w02 = wb[2 * 1024 + ci * 32];
            xrow<8>(acc0, A, w10, w11, w12);
            xrow<8>(acc1, A, w20, w21, w22);
            xrow<8>(acc1, B, w00, w01, w02);
        }
        __syncthreads();   // all d3 reads drained -> d4 may overlay d3
        const float b = bt2[co];
        float* o0 = d4 + co * 260 + (2 * org) * 16;
        float* o1 = o0 + 16;
        #pragma unroll
        for (int q = 0; q < 4; q++) {
            float4 v0 = make_float4(eluf(acc0[4 * q] + b), eluf(acc0[4 * q + 1] + b),
                                    eluf(acc0[4 * q + 2] + b), eluf(acc0[4 * q + 3] + b));
            float4 v1 = make_float4(eluf(acc1[4 * q] + b), eluf(acc1[4 * q + 1] + b),
                                    eluf(acc1[4 * q + 2] + b), eluf(acc1[4 * q + 3] + b));
            *(float4*)(o0 + 4 * q) = v0;
            *(float4*)(o1 + 4 * q) = v1;
        }
    }
    __syncthreads();

    // T1 — tap dedup: 4 distinct d4 values per ci, 9 fma in original order.
    {
        const int ey = tid >> 4, ex = tid & 15;
        const bool vx = (ex + 1) < 16, vy = (ey + 1) < 16;
        const float bb = bt1[0];
        float* xi = xr + n * 1024;
        float acc[4] = {};
        for (int ci = 0; ci < 32; ci++) {
            const float* a = d4 + ci * 260;
            const float* w = wt1 + ci * 9;
            const float v00 = a[ey * 16 + ex];
            const float v01 = vx ? a[ey * 16 + ex + 1] : 0.f;
            const float v10 = vy ? a[(ey + 1) * 16 + ex] : 0.f;
            const float v11 = (vx && vy) ? a[(ey + 1) * 16 + ex + 1] : 0.f;
            // quad (0,0): k4@(ey,ex)
            acc[0] = fmaf(v00, w[4], acc[0]);
            // quad (0,1): k5@(ey,ex), k3@(ey,ex+1)
            acc[1] = fmaf(v00, w[5], acc[1]);
            acc[1] = fmaf(v01, w[3], acc[1]);
            // quad (1,0): k7@(ey,ex), k1@(ey+1,ex)
            acc[2] = fmaf(v00, w[7], acc[2]);
            acc[2] = fmaf(v10, w[1], acc[2]);
            // quad (1,1): k8, k6, k2, k0
            acc[3] = fmaf(v00, w[8], acc[3]);
            acc[3] = fmaf(v01, w[6], acc[3]);
            acc[3] = fmaf(v10, w[2], acc[3]);
            acc[3] = fmaf(v11, w[0], acc[3]);
        }
        xi[(2 * ey) * 32 + 2 * ex]         = 1.f / (1.f + expf(-(acc[0] + bb)));
        xi[(2 * ey) * 32 + 2 * ex + 1]     = 1.f / (1.f + expf(-(acc[1] + bb)));
        xi[(2 * ey + 1) * 32 + 2 * ex]     = 1.f / (1.f + expf(-(acc[2] + bb)));
        xi[(2 * ey + 1) * 32 + 2 * ex + 1] = 1.f / (1.f + expf(-(acc[3] + bb)));
    }
}

// ============================================================================
extern "C" void kernel_launch(void* const* d_in, const int* in_sizes, int n_in,
                              void* d_out, int out_size, void* d_ws, size_t ws_size,
                              hipStream_t stream)
{
    (void)in_sizes; (void)n_in; (void)out_size; (void)ws_size;
    const float* x    = (const float*)d_in[0];
    const float* eps  = (const float*)d_in[1];
    const float* w1 = (const float*)d_in[2];  const float* b1 = (const float*)d_in[3];
    const float* w2 = (const float*)d_in[4];  const float* b2 = (const float*)d_in[5];
    const float* w3 = (const float*)d_in[6];  const float* b3 = (const float*)d_in[7];
    const float* w4 = (const float*)d_in[8];  const float* b4 = (const float*)d_in[9];
    const float* w5 = (const float*)d_in[10]; const float* b5 = (const float*)d_in[11];
    const float* fc_mu_w = (const float*)d_in[12]; const float* fc_mu_b = (const float*)d_in[13];
    const float* fc_D_w  = (const float*)d_in[14]; const float* fc_D_b  = (const float*)d_in[15];
    const float* fc_B_w  = (const float*)d_in[16]; const float* fc_B_b  = (const float*)d_in[17];
    const float* fc_dec_w = (const float*)d_in[18]; const float* fc_dec_b = (const float*)d_in[19];
    const float* wt5 = (const float*)d_in[20]; const float* bt5 = (const float*)d_in[21];
    const float* wt4 = (const float*)d_in[22]; const float* bt4 = (const float*)d_in[23];
    const float* wt3 = (const float*)d_in[24]; const float* bt3 = (const float*)d_in[25];
    const float* wt2 = (const float*)d_in[26]; const float* bt2 = (const float*)d_in[27];
    const float* wt1 = (const float*)d_in[28]; const float* bt1 = (const float*)d_in[29];

    // workspace layout (floats): total 2,889,728 (~11.6 MB)
    float* ws   = (float*)d_ws;
    float* h    = ws;                  // 262144  [4096][64]
    float* Lb   = ws + 262144;         // 2097152 [256][256][32]
    float* z    = ws + 2359296;        // 65536
    float* hd0  = ws + 2424832;        // 262144  [4096][64]
    float* wt5t = ws + 2686976;        // 36864   [9][64][64]
    float* wt4t = ws + 2723840;        // 36864   [9][64][64]
    float* wt3t = ws + 2760704;        // 18432   [9][64][32]
    float* wt2t = ws + 2779136;        // 9216    [9][32][32]
    float* w2t  = ws + 2788352;        // 9216    [9][32][32]
    float* w3t  = ws + 2797568;        // 18432   [9][32][64]
    float* w4t  = ws + 2816000;        // 36864   [9][64][64]
    float* w5t  = ws + 2852864;        // 36864   [9][64][64]

    // output layout: xr | mu | cov | Pm
    float* out = (float*)d_out;
    float* xr  = out;                 // 4194304
    float* mu  = out + 4194304;       // 65536
    float* cov = out + 4259840;       // 16777216
    float* Pm  = out + 21037056;      // 16777216

    prep_all<<<17176, 256, 0, stream>>>(wt5, wt4, wt3, wt2, w2, w3, w4, w5,
                                        wt5t, wt4t, wt3t, wt2t, w2t, w3t, w4t, w5t,
                                        (float4*)Pm);
    enc_fused<<<4096, 256, 0, stream>>>(x, w1, b1, w2t, b2, w3t, b3, w4t, b4, w5t, b5, h);
    fc_enc<<<dim3(128, 4), 256, 0, stream>>>(h, fc_mu_w, fc_mu_b, fc_D_w, fc_D_b,
                                             fc_B_w, fc_B_b, mu, Pm);
    chol_band<<<256, 64, 0, stream>>>(Pm, Lb);
    inv_band<<<256, 256, 0, stream>>>(Lb, cov);
    zvec_k<<<256, 256, 0, stream>>>(cov, mu, eps, z);
    fc_dec_mu<<<1280, 256, 0, stream>>>(z, fc_dec_w, fc_dec_b, hd0,
                                        h, fc_mu_w, fc_mu_b, mu);
    dec_fused<<<4096, 256, 0, stream>>>(hd0, wt5t, bt5, wt4t, bt4, wt3t, bt3,
                                        wt2t, bt2, wt1, bt1, xr);
}

// Round 8
// 980.472 us; speedup vs baseline: 1.0124x; 1.0124x over previous
//
#include <hip/hip_runtime.h>
#include <cmath>

#define ALPHA 0.5f

// ============================================================================
// prep_all: pm_zero (16384 blocks) + weight transpose (792 blocks) fused.
// ============================================================================
__global__ __launch_bounds__(256) void prep_all(
    const float* __restrict__ dw5, const float* __restrict__ dw4,
    const float* __restrict__ dw3, const float* __restrict__ dw2,
    const float* __restrict__ ew2, const float* __restrict__ ew3,
    const float* __restrict__ ew4, const float* __restrict__ ew5,
    float* __restrict__ t5, float* __restrict__ t4,
    float* __restrict__ t3, float* __restrict__ t2,
    float* __restrict__ e2, float* __restrict__ e3,
    float* __restrict__ e4, float* __restrict__ e5,
    float4* __restrict__ Pm4)
{
    const int bid = blockIdx.x;
    if (bid < 16384) {
        Pm4[bid * 256 + threadIdx.x] = make_float4(0.f, 0.f, 0.f, 0.f);
        return;
    }
    int idx = (bid - 16384) * 256 + threadIdx.x;   // total 202752
    if (idx >= 202752) return;
    const float* w; float* t; int CIN, COUT, loc; bool enc = false;
    if (idx < 36864)       { w = dw5; t = t5; CIN = 64; COUT = 64; loc = idx; }
    else if (idx < 73728)  { w = dw4; t = t4; CIN = 64; COUT = 64; loc = idx - 36864; }
    else if (idx < 92160)  { w = dw3; t = t3; CIN = 64; COUT = 32; loc = idx - 73728; }
    else if (idx < 101376) { w = dw2; t = t2; CIN = 32; COUT = 32; loc = idx - 92160; }
    else if (idx < 110592) { w = ew2; t = e2; CIN = 32; COUT = 32; loc = idx - 101376; enc = true; }
    else if (idx < 129024) { w = ew3; t = e3; CIN = 32; COUT = 64; loc = idx - 110592; enc = true; }
    else if (idx < 165888) { w = ew4; t = e4; CIN = 64; COUT = 64; loc = idx - 129024; enc = true; }
    else                   { w = ew5; t = e5; CIN = 64; COUT = 64; loc = idx - 165888; enc = true; }
    int wk = loc % 9; int r = loc / 9; int ci, co;
    if (enc) { ci = r % CIN;  co = r / CIN;  }   // src [co][ci][k]
    else     { co = r % COUT; ci = r / COUT; }   // src [ci][co][k]
    t[wk * CIN * COUT + ci * COUT + co] = w[loc];
}

// ============================================================================
// Encoder (unchanged from round 6).
// ============================================================================
__device__ __forceinline__ int a1map(int iy, int col) {
    return (col & 7)
         | ((iy & 2) << 2)                   // iy[1]        -> bit3
         | (((iy ^ (iy >> 2)) & 1) << 4)     // iy[0]^iy[2]  -> bit4
         | ((col & 8) << 2)                  // col[3]       -> bit5
         | ((iy & 4) << 4)                   // iy[2]        -> bit6
         | ((iy & 8) << 4);                  // iy[3]        -> bit7
}

__global__ __launch_bounds__(256, 4) void enc_fused(
    const float* __restrict__ x,
    const float* __restrict__ w1,  const float* __restrict__ b1,
    const float* __restrict__ w2t, const float* __restrict__ b2,
    const float* __restrict__ w3t, const float* __restrict__ b3,
    const float* __restrict__ w4t, const float* __restrict__ b4,
    const float* __restrict__ w5t, const float* __restrict__ b5,
    float* __restrict__ hout)
{
    __shared__ __align__(16) float smem[10240];   // 40960 B -> 4 blocks/CU
    float* a1s  = smem;          // [32][256] permuted conv1 output (8192 fl)
    float* bse  = smem + 8192;   // region B (2048 fl): aliased by phase
    float* imgs = bse;           // phase0: [32][40] = 1280
    float* a2s  = bse;           // phase1+: [32][64] = 2048
    float* a3s  = smem;          // post-conv2 overlay of a1s: [64][16] = 1024
    float* a4s  = smem + 1024;   // [64][4] = 256
    float* reds = smem + 1280;   // [4][64] = 256

    const int n = blockIdx.x;
    const int tid = threadIdx.x;

    const float* xi = x + n * 1024;
    #pragma unroll
    for (int i = 0; i < 4; i++) {
        int idx = tid + 256 * i;
        int iy = idx >> 5, ix = idx & 31;
        int col = (ix & 1) ? 20 + (ix >> 1) : (ix >> 1);
        imgs[iy * 40 + col] = xi[idx];
    }
    __syncthreads();

    // conv1
    {
        const int oy = tid >> 4, ox = tid & 15;
        float patch[9];
        #pragma unroll
        for (int ky = 0; ky < 3; ky++) {
            const int iy = 2 * oy - 1 + ky;
            #pragma unroll
            for (int kx = 0; kx < 3; kx++) {
                const int ix = 2 * ox - 1 + kx;
                bool v = (iy >= 0) && (ix >= 0);
                int col = (ix & 1) ? 20 + (ix >> 1) : (ix >> 1);
                patch[ky * 3 + kx] = v ? imgs[iy * 40 + col] : 0.f;
            }
        }
        const int ocol = (ox & 1) ? 8 + (ox >> 1) : (ox >> 1);
        const int sidx = a1map(oy, ocol);
        for (int c = 0; c < 32; c++) {
            float acc = b1[c];
            #pragma unroll
            for (int k = 0; k < 9; k++) acc = fmaf(patch[k], w1[c * 9 + k], acc);
            a1s[c * 256 + sidx] = fmaxf(acc, 0.f);
        }
    }
    __syncthreads();

    // conv2 (4 waves, 8 co per thread)
    {
        const int p = tid & 63, oy = p >> 3, ox = p & 7;
        const int c0u = __builtin_amdgcn_readfirstlane(tid >> 6);
        const int cobase = c0u * 8;
        float acc[8];
        #pragma unroll
        for (int r = 0; r < 8; r++) acc[r] = b2[cobase + r];
        int offs[9]; bool val[9];
        #pragma unroll
        for (int ky = 0; ky < 3; ky++) {
            const int iy = 2 * oy - 1 + ky;
            #pragma unroll
            for (int kx = 0; kx < 3; kx++) {
                const int ix = 2 * ox - 1 + kx;
                const bool v = (iy >= 0) && (ix >= 0);
                const int col = (ix & 1) ? 8 + (ix >> 1) : (ix >> 1);
                offs[ky * 3 + kx] = v ? a1map(iy, col) : 0;
                val[ky * 3 + kx] = v;
            }
        }
        for (int ci = 0; ci < 32; ci++) {
            float patch[9];
            #pragma unroll
            for (int k = 0; k < 9; k++)
                patch[k] = val[k] ? a1s[ci * 256 + offs[k]] : 0.f;
            const float* wci = w2t + ci * 32 + cobase;
            #pragma unroll
            for (int k = 0; k < 9; k++) {
                #pragma unroll
                for (int r = 0; r < 8; r++)
                    acc[r] = fmaf(patch[k], wci[k * 1024 + r], acc[r]);
            }
        }
        __syncthreads();
        #pragma unroll
        for (int r = 0; r < 8; r++)
            a2s[(cobase + r) * 64 + p] = fmaxf(acc[r], 0.f);
    }
    __syncthreads();

    // conv3 (4 waves, 4 co per thread)
    {
        const int px = tid & 15, oy = px >> 2, ox = px & 3;
        const int cg = tid >> 4;
        float4 bv = ((const float4*)b3)[cg];
        float acc[4] = {bv.x, bv.y, bv.z, bv.w};
        for (int ci = 0; ci < 32; ci++) {
            float patch[9];
            #pragma unroll
            for (int ky = 0; ky < 3; ky++) {
                const int iy = 2 * oy - 1 + ky;
                #pragma unroll
                for (int kx = 0; kx < 3; kx++) {
                    const int ix = 2 * ox - 1 + kx;
                    bool v = (iy >= 0) && (ix >= 0);
                    patch[ky * 3 + kx] = v ? a2s[ci * 64 + iy * 8 + ix] : 0.f;
                }
            }
            #pragma unroll
            for (int k = 0; k < 9; k++) {
                float4 wv = *(const float4*)(w3t + k * 2048 + ci * 64 + cg * 4);
                acc[0] = fmaf(patch[k], wv.x, acc[0]);
                acc[1] = fmaf(patch[k], wv.y, acc[1]);
                acc[2] = fmaf(patch[k], wv.z, acc[2]);
                acc[3] = fmaf(patch[k], wv.w, acc[3]);
            }
        }
        #pragma unroll
        for (int r = 0; r < 4; r++)
            a3s[(cg * 4 + r) * 16 + px] = fmaxf(acc[r], 0.f);
    }
    __syncthreads();

    // conv4 (round-5 restructured form)
    {
        const int co = tid & 63;
        const int part = __builtin_amdgcn_readfirstlane(tid >> 6);
        float a0 = 0.f, a1 = 0.f, a2 = 0.f, a3 = 0.f;
        for (int ci = part * 16; ci < part * 16 + 16; ci++) {
            const float* wp = w4t + ci * 64 + co;
            const float w0 = wp[0];
            const float w1 = wp[4096];
            const float w2 = wp[8192];
            const float w3 = wp[12288];
            const float w4 = wp[16384];
            const float w5 = wp[20480];
            const float w6 = wp[24576];
            const float w7 = wp[28672];
            const float w8 = wp[32768];
            const float4 r0 = *(const float4*)(a3s + ci * 16);
            const float4 r1 = *(const float4*)(a3s + ci * 16 + 4);
            const float4 r2 = *(const float4*)(a3s + ci * 16 + 8);
            const float4 r3 = *(const float4*)(a3s + ci * 16 + 12);
            a0 = fmaf(r0.x, w4, a0); a0 = fmaf(r0.y, w5, a0);
            a0 = fmaf(r1.x, w7, a0); a0 = fmaf(r1.y, w8, a0);
            a1 = fmaf(r0.y, w3, a1); a1 = fmaf(r0.z, w4, a1); a1 = fmaf(r0.w, w5, a1);
            a1 = fmaf(r1.y, w6, a1); a1 = fmaf(r1.z, w7, a1); a1 = fmaf(r1.w, w8, a1);
            a2 = fmaf(r1.x, w1, a2); a2 = fmaf(r1.y, w2, a2);
            a2 = fmaf(r2.x, w4, a2); a2 = fmaf(r2.y, w5, a2);
            a2 = fmaf(r3.x, w7, a2); a2 = fmaf(r3.y, w8, a2);
            a3 = fmaf(r1.y, w0, a3); a3 = fmaf(r1.z, w1, a3); a3 = fmaf(r1.w, w2, a3);
            a3 = fmaf(r2.y, w3, a3); a3 = fmaf(r2.z, w4, a3); a3 = fmaf(r2.w, w5, a3);
            a3 = fmaf(r3.y, w6, a3); a3 = fmaf(r3.z, w7, a3); a3 = fmaf(r3.w, w8, a3);
        }
        float* reds2 = bse;   // a2s dead after conv3
        reds2[part * 256 +   0 + co] = a0;
        reds2[part * 256 +  64 + co] = a1;
        reds2[part * 256 + 128 + co] = a2;
        reds2[part * 256 + 192 + co] = a3;
        __syncthreads();
        {
            const int co2 = tid & 63;
            const int cls2 = __builtin_amdgcn_readfirstlane(tid >> 6);
            float s = b4[co2]
                    + reds2[      cls2 * 64 + co2] + reds2[256 + cls2 * 64 + co2]
                    + reds2[512 + cls2 * 64 + co2] + reds2[768 + cls2 * 64 + co2];
            a4s[co2 * 4 + cls2] = fmaxf(s, 0.f);
        }
    }
    __syncthreads();

    // conv5
    {
        const int c = tid & 63, part = tid >> 6;
        float s = 0.f;
        for (int ci = part * 16; ci < part * 16 + 16; ci++) {
            const float4 av = *(const float4*)(a4s + ci * 4);
            s = fmaf(av.x, w5t[4 * 4096 + ci * 64 + c], s);
            s = fmaf(av.y, w5t[5 * 4096 + ci * 64 + c], s);
            s = fmaf(av.z, w5t[7 * 4096 + ci * 64 + c], s);
            s = fmaf(av.w, w5t[8 * 4096 + ci * 64 + c], s);
        }
        reds[part * 64 + c] = s;
    }
    __syncthreads();
    if (tid < 64) {
        float v = b5[tid] + reds[tid] + reds[64 + tid] + reds[128 + tid] + reds[192 + tid];
        hout[n * 64 + tid] = fmaxf(v, 0.f);
    }
}

// ============================================================================
// FC heads (unchanged): mu -> d_out; D/B heads -> Pm directly.
// ============================================================================
__global__ __launch_bounds__(256) void fc_enc(
    const float* __restrict__ h,
    const float* __restrict__ wmu, const float* __restrict__ bmu,
    const float* __restrict__ wD,  const float* __restrict__ bD,
    const float* __restrict__ wB,  const float* __restrict__ bB,
    float* __restrict__ mu, float* __restrict__ Pm)
{
    __shared__ float As[32][65];
    __shared__ float Bs[32][65];
    const int tid = threadIdx.x;
    const int m0 = blockIdx.y * 64;
    const int n0 = blockIdx.x * 64;

    const float* wbase; const float* bias; int nloc; int region;
    if (n0 < 256)       { wbase = wmu; bias = bmu; nloc = n0;        region = 0; }
    else if (n0 < 4352) { wbase = wD;  bias = bD;  nloc = n0 - 256;  region = 1; }
    else                { wbase = wB;  bias = bB;  nloc = n0 - 4352; region = 2; }

    const int tx = tid & 15, ty = tid >> 4;
    float acc[4][4] = {};
    for (int k0 = 0; k0 < 1024; k0 += 32) {
        #pragma unroll
        for (int s = 0; s < 8; s++) {
            int l = tid + 256 * s;
            int row = l >> 5, kk = l & 31;
            As[kk][row] = h[(m0 + row) * 1024 + k0 + kk];
            Bs[kk][row] = wbase[(nloc + row) * 1024 + k0 + kk];
        }
        __syncthreads();
        #pragma unroll
        for (int kk = 0; kk < 32; kk++) {
            float av[4], bv[4];
            #pragma unroll
            for (int i = 0; i < 4; i++) av[i] = As[kk][ty * 4 + i];
            #pragma unroll
            for (int j = 0; j < 4; j++) bv[j] = Bs[kk][tx * 4 + j];
            #pragma unroll
            for (int i = 0; i < 4; i++)
                #pragma unroll
                for (int j = 0; j < 4; j++) acc[i][j] = fmaf(av[i], bv[j], acc[i][j]);
        }
        __syncthreads();
    }
    #pragma unroll
    for (int i = 0; i < 4; i++) {
        int m = m0 + ty * 4 + i;
        size_t pbase = (size_t)m * 65536;
        #pragma unroll
        for (int j = 0; j < 4; j++) {
            int nc = nloc + tx * 4 + j;
            float v = acc[i][j] + bias[nc];
            if (region == 0) {
                mu[m * 256 + nc] = v;
            } else {
                int t = nc >> 8, pi = (nc >> 4) & 15, pj = nc & 15;
                if (region == 1) {
                    int row = t * 16 + pi, col = t * 16 + pj;
                    Pm[pbase + row * 256 + col] = v + (pi == pj ? ALPHA : 0.f);
                } else {
                    int row = (t + 1) * 16 + pi, col = t * 16 + pj;
                    Pm[pbase + row * 256 + col] = v;      // sub-diagonal
                    Pm[pbase + col * 256 + row] = v;      // super-diagonal (transposed)
                }
            }
        }
    }
}

// ============================================================================
// Banded Cholesky v2 (unchanged from round 3)
// ============================================================================
__global__ __launch_bounds__(64) void chol_band(
    const float* __restrict__ Pm, float* __restrict__ Lb_g)
{
    __shared__ float Lb[256 * 32 + 32];   // +32 zero pad for row-255 overread
    __shared__ float Ds[4096];
    __shared__ float Bs2[3840];
    const int b = blockIdx.x, lane = threadIdx.x;
    const float* Pb = Pm + (size_t)b * 65536;
    for (int i = lane; i < 8224; i += 64) Lb[i] = 0.f;
    for (int i = lane; i < 4096; i += 64) {
        int t = i >> 8, r = (i >> 4) & 15, c = i & 15;
        Ds[i] = Pb[(t * 16 + r) * 256 + t * 16 + c];
    }
    for (int i = lane; i < 3840; i += 64) {
        int t = i >> 8, r = (i >> 4) & 15, c = i & 15;
        Bs2[i] = Pb[((t + 1) * 16 + r) * 256 + t * 16 + c];
    }
    __syncthreads();

    const int d = lane;
    for (int j = 0; j < 256; j++) {
        const int i = j + d;
        float s = 0.f;
        if (d < 32 && i < 256) {
            int bi = i >> 4, bj = j >> 4, pi = i & 15, pj = j & 15;
            float a;
            if (bi == bj)           a = Ds[bi * 256 + pi * 16 + pj];
            else if (bi == bj + 1)  a = Bs2[bj * 256 + pi * 16 + pj];
            else                    a = 0.f;

            // batched loads: all independent, one wait
            float c[32], p[32];
            const float* cp = Lb + j * 32;
            #pragma unroll
            for (int q = 0; q < 8; q++)
                *(float4*)(c + 4 * q) = *(const float4*)(cp + 4 * q);
            const float* pp = Lb + i * 32 + d;
            #pragma unroll
            for (int m = 1; m < 32; m++) p[m] = pp[m];

            float s0 = 0.f, s1 = 0.f, s2 = 0.f, s3 = 0.f;
            #pragma unroll
            for (int m = 1; m <= 28; m += 4) {
                s0 = fmaf(p[m],     c[m],     s0);
                s1 = fmaf(p[m + 1], c[m + 1], s1);
                s2 = fmaf(p[m + 2], c[m + 2], s2);
                s3 = fmaf(p[m + 3], c[m + 3], s3);
            }
            s0 = fmaf(p[29], c[29], s0);
            s1 = fmaf(p[30], c[30], s1);
            s2 = fmaf(p[31], c[31], s2);
            s = a - ((s0 + s1) + (s2 + s3));
        }
        float diag = __shfl(s, 0);
        float Ljj = sqrtf(diag);
        if (d == 0)                  Lb[j * 32] = Ljj;
        else if (d < 32 && i < 256)  Lb[i * 32 + d] = s / Ljj;
        __syncthreads();
    }
    for (int i = lane; i < 8192; i += 64) Lb_g[b * 8192 + i] = Lb[i];
}

// ============================================================================
// cov = inv(L) v3 (unchanged from round 7)
// ============================================================================
__global__ __launch_bounds__(256) void inv_band(
    const float* __restrict__ Lb_g, float* __restrict__ cov)
{
    __shared__ __align__(16) float Ls[8192];
    __shared__ float rs[256];
    const int b = blockIdx.x, j = threadIdx.x;
    float* covb = cov + (size_t)b * 65536;

    // stage band (float4-coalesced)
    {
        const float4* src = (const float4*)(Lb_g + b * 8192);
        float4* dst = (float4*)Ls;
        #pragma unroll
        for (int q = 0; q < 8; q++) dst[j + 256 * q] = src[j + 256 * q];
    }
    __syncthreads();
    rs[j] = 1.f / Ls[j * 32];
    __syncthreads();

    const int w = __builtin_amdgcn_readfirstlane(j >> 6);
    const int istart = w * 64;                 // 32-aligned, <= any j in wave

    // rows above istart are strictly upper-triangular for this wave -> zero
    for (int i = 0; i < istart; i++) covb[i * 256 + j] = 0.f;

    float g[32];
    #pragma unroll
    for (int q = 0; q < 32; q++) g[q] = 0.f;

    for (int c = istart; c < 256; c += 32) {
        #pragma unroll
        for (int u = 0; u < 32; u++) {
            const int i = c + u;                       // wave-uniform
            const float* Lr = Ls + i * 32;             // broadcast LDS reads
            float lrow[32];
            #pragma unroll
            for (int q = 0; q < 8; q++)
                *(float4*)(lrow + 4 * q) = *(const float4*)(Lr + 4 * q);
            float s0 = 0.f, s1 = 0.f, s2 = 0.f, s3 = 0.f;
            #pragma unroll
            for (int d = 1; d < 32; d += 4) {
                s0 = fmaf(lrow[d],     g[(u - d) & 31],     s0);
                if (d + 1 < 32) s1 = fmaf(lrow[d + 1], g[(u - d - 1) & 31], s1);
                if (d + 2 < 32) s2 = fmaf(lrow[d + 2], g[(u - d - 2) & 31], s2);
                if (d + 3 < 32) s3 = fmaf(lrow[d + 3], g[(u - d - 3) & 31], s3);
            }
            float s = (s0 + s1) + (s2 + s3);
            float gi = (((i == j) ? 1.f : 0.f) - s) * rs[i];
            g[u & 31] = gi;
            covb[i * 256 + j] = gi;                    // coalesced
        }
    }
}

// ============================================================================
// z = mu + cov @ eps (unchanged)
// ============================================================================
__global__ __launch_bounds__(256) void zvec_k(
    const float* __restrict__ cov, const float* __restrict__ mu,
    const float* __restrict__ eps, float* __restrict__ z)
{
    __shared__ float es[256];
    const int b = blockIdx.x, i = threadIdx.x;
    es[i] = eps[b * 256 + i];
    __syncthreads();
    const float4* row = (const float4*)(cov + (size_t)b * 65536 + i * 256);
    float s = 0.f;
    #pragma unroll 8
    for (int k = 0; k < 64; k++) {
        float4 v = row[k];
        s = fmaf(v.x, es[4 * k], s);
        s = fmaf(v.y, es[4 * k + 1], s);
        s = fmaf(v.z, es[4 * k + 2], s);
        s = fmaf(v.w, es[4 * k + 3], s);
    }
    z[b * 256 + i] = mu[b * 256 + i] + s;
}

// ============================================================================
// fc_dec + mu_fix fused (unchanged from round 7)
// ============================================================================
__global__ __launch_bounds__(256) void fc_dec_mu(
    const float* __restrict__ z, const float* __restrict__ w,
    const float* __restrict__ bias, float* __restrict__ hd0,
    const float* __restrict__ h, const float* __restrict__ wmu,
    const float* __restrict__ bmu, float* __restrict__ mu)
{
    __shared__ float sh[1024];
    const int blk = blockIdx.x;
    if (blk < 1024) {
        // fc_dec
        const int b = blk >> 2;
        const int f = ((blk & 3) << 8) + threadIdx.x;
        sh[threadIdx.x] = z[b * 256 + threadIdx.x];
        __syncthreads();
        const float4* wr = (const float4*)(w + f * 256);
        float s = 0.f;
        #pragma unroll 8
        for (int k = 0; k < 64; k++) {
            float4 v = wr[k];
            s = fmaf(v.x, sh[4 * k], s);
            s = fmaf(v.y, sh[4 * k + 1], s);
            s = fmaf(v.z, sh[4 * k + 2], s);
            s = fmaf(v.w, sh[4 * k + 3], s);
        }
        hd0[b * 1024 + f] = s + bias[f];
    } else {
        // mu_fix
        const int b = blk - 1024, p = threadIdx.x;
        #pragma unroll
        for (int i = 0; i < 4; i++) sh[p + 256 * i] = h[b * 1024 + p + 256 * i];
        __syncthreads();
        const float4* wr = (const float4*)(wmu + p * 1024);
        float s = 0.f;
        #pragma unroll 8
        for (int k = 0; k < 256; k++) {
            float4 v = wr[k];
            s = fmaf(v.x, sh[4 * k], s);
            s = fmaf(v.y, sh[4 * k + 1], s);
            s = fmaf(v.z, sh[4 * k + 2], s);
            s = fmaf(v.w, sh[4 * k + 3], s);
        }
        mu[b * 256 + p] = s + bmu[p];
    }
}

// ============================================================================
// Decoder: exact round-6 form (235 µs measured) + explicit float2 stores in
// T1 (bit-identical values; protects the full-cache-line store coalescing
// that round 7's T1 rewrite broke — WRITE_SIZE 16.4 -> 24.1 MB regression).
// ============================================================================
__device__ __forceinline__ float eluf(float v) { return v > 0.f ? v : expf(v) - 1.f; }

template<int PY, int PX, int HIN, int WIN, class F>
__device__ __forceinline__ void for_taps(int ey, int ex, F&& f) {
    if (PY == 0) {
        if (PX == 0) { f(4, ey, ex, true); }
        else         { f(5, ey, ex, true); f(3, ey, ex + 1, ex + 1 < WIN); }
    } else {
        if (PX == 0) { f(7, ey, ex, true); f(1, ey + 1, ex, ey + 1 < HIN); }
        else {
            f(8, ey, ex, true);
            f(6, ey, ex + 1, ex + 1 < WIN);
            f(2, ey + 1, ex, ey + 1 < HIN);
            f(0, ey + 1, ex + 1, (ey + 1 < HIN) && (ex + 1 < WIN));
        }
    }
}

template<int OY>
__device__ __forceinline__ void t4_row(
    const float* __restrict__ wt4t, const float* __restrict__ bt4,
    const float* __restrict__ d1, float* __restrict__ d2, int co)
{
    float a0 = 0.f, a1 = 0.f, a2 = 0.f, a3 = 0.f;
    const float* wb = wt4t + co;
    for (int ci = 0; ci < 64; ci++) {
        const float* base = d1 + ci * 12;
        if (OY % 2 == 0) {
            float4 r = *(const float4*)(base + (OY / 2) * 4);
            float w10 = wb[3 * 4096 + ci * 64];
            float w11 = wb[4 * 4096 + ci * 64];
            float w12 = wb[5 * 4096 + ci * 64];
            a0 = fmaf(r.x, w11, a0);
            a1 = fmaf(r.x, w12, a1); a1 = fmaf(r.y, w10, a1);
            a2 = fmaf(r.y, w11, a2);
            a3 = fmaf(r.y, w12, a3); a3 = fmaf(r.z, w10, a3);
        } else {
            float4 ra = *(const float4*)(base + ((OY - 1) / 2) * 4);
            float4 rb = *(const float4*)(base + ((OY + 1) / 2) * 4);
            float w20 = wb[6 * 4096 + ci * 64], w21 = wb[7 * 4096 + ci * 64], w22 = wb[8 * 4096 + ci * 64];
            float w00 = wb[0 * 4096 + ci * 64], w01 = wb[1 * 4096 + ci * 64], w02 = wb[2 * 4096 + ci * 64];
            a0 = fmaf(ra.x, w21, a0); a0 = fmaf(rb.x, w01, a0);
            a1 = fmaf(ra.x, w22, a1); a1 = fmaf(ra.y, w20, a1);
            a1 = fmaf(rb.x, w02, a1); a1 = fmaf(rb.y, w00, a1);
            a2 = fmaf(ra.y, w21, a2); a2 = fmaf(rb.y, w01, a2);
            a3 = fmaf(ra.y, w22, a3); a3 = fmaf(ra.z, w20, a3);
            a3 = fmaf(rb.y, w02, a3); a3 = fmaf(rb.z, w00, a3);
        }
    }
    float b = bt4[co];
    float4 o = make_float4(eluf(a0 + b), eluf(a1 + b), eluf(a2 + b), eluf(a3 + b));
    *(float4*)(d2 + co * 44 + OY * 8) = o;
}

template<int M>
__device__ __forceinline__ void xrow(float* acc, const float* R, float w0, float w1, float w2)
{
    #pragma unroll
    for (int m = 0; m < M; m++) {
        acc[2 * m]     = fmaf(R[m], w1, acc[2 * m]);
        acc[2 * m + 1] = fmaf(R[m], w2, acc[2 * m + 1]);
        acc[2 * m + 1] = fmaf(R[m + 1], w0, acc[2 * m + 1]);
    }
}

__global__ __launch_bounds__(256, 4) void dec_fused(
    const float* __restrict__ hd0,
    const float* __restrict__ wt5t, const float* __restrict__ bt5,
    const float* __restrict__ wt4t, const float* __restrict__ bt4,
    const float* __restrict__ wt3t, const float* __restrict__ bt3,
    const float* __restrict__ wt2t, const float* __restrict__ bt2,
    const float* __restrict__ wt1,  const float* __restrict__ bt1,
    float* __restrict__ xr)
{
    __shared__ __align__(16) float smem[9664];   // 38656 B -> 4 blocks/CU
    float* d0  = smem;            // 64
    float* d1  = smem + 64;       // [64][3][4] pitch 12
    float* d2  = smem + 832;      // [64][44], rows pitch 8 (5 rows)
    float* scr = smem + 3648;     // [128][20]
    float* d3  = smem + 6208;     // [32][108], rows pitch 12 (9 rows)
    float* d4  = smem;            // [32][260] overlays A+scr+d3 after T2 barrier

    const int n = blockIdx.x, tid = threadIdx.x;

    for (int i = tid; i < 3584; i += 256) smem[64 + i] = 0.f;
    for (int i = tid; i < 3456; i += 256) d3[i] = 0.f;
    if (tid < 64) d0[tid] = hd0[n * 64 + tid];
    __syncthreads();

    // T5
    {
        const int co = tid & 63;
        const int wv = __builtin_amdgcn_readfirstlane(tid >> 6);
        const int oy = wv >> 1, ox = wv & 1;
        const int wk = (oy + 1) * 3 + (ox + 1);
        const float* wp = wt5t + wk * 4096 + co;
        float s = bt5[co];
        for (int ci = 0; ci < 64; ci++)
            s = fmaf(d0[ci], wp[ci * 64], s);
        d1[co * 12 + oy * 4 + ox] = eluf(s);
    }
    __syncthreads();

    // T4
    {
        const int co = tid & 63;
        const int oyw = __builtin_amdgcn_readfirstlane(tid >> 6);
        if (oyw == 0)      t4_row<0>(wt4t, bt4, d1, d2, co);
        else if (oyw == 1) t4_row<1>(wt4t, bt4, d1, d2, co);
        else if (oyw == 2) t4_row<2>(wt4t, bt4, d1, d2, co);
        else               t4_row<3>(wt4t, bt4, d1, d2, co);
    }
    __syncthreads();

    // T3
    {
        const int co = tid & 31, pr = (tid >> 5) & 3, cih = tid >> 7;
        const int e = (pr & 1) ? 7 - pr : pr;
        const int o = (pr & 1) ? pr : 7 - pr;
        const int iy_e = e >> 1, iy_o2 = (o - 1) >> 1, iy_o0 = (o + 1) >> 1;
        float acce[8] = {}, acco[8] = {};
        const float* wb = wt3t + co;
        for (int c = 0; c < 32; c++) {
            const int ci = cih * 32 + c;
            const float* base = d2 + ci * 44;
            float re[8], ro2[8], ro0[8];
            *(float4*)(re)      = *(const float4*)(base + iy_e * 8);
            *(float4*)(re + 4)  = *(const float4*)(base + iy_e * 8 + 4);
            *(float4*)(ro2)     = *(const float4*)(base + iy_o2 * 8);
            *(float4*)(ro2 + 4) = *(const float4*)(base + iy_o2 * 8 + 4);
            *(float4*)(ro0)     = *(const float4*)(base + iy_o0 * 8);
            *(float4*)(ro0 + 4) = *(const float4*)(base + iy_o0 * 8 + 4);
            float w10 = wb[3 * 2048 + ci * 32], w11 = wb[4 * 2048 + ci * 32], w12 = wb[5 * 2048 + ci * 32];
            float w20 = wb[6 * 2048 + ci * 32], w21 = wb[7 * 2048 + ci * 32], w22 = wb[8 * 2048 + ci * 32];
            float w00 = wb[0 * 2048 + ci * 32], w01 = wb[1 * 2048 + ci * 32], w02 = wb[2 * 2048 + ci * 32];
            xrow<4>(acce, re, w10, w11, w12);
            xrow<4>(acco, ro2, w20, w21, w22);
            xrow<4>(acco, ro0, w00, w01, w02);
        }
        if (cih == 1) {
            float* s = scr + (tid - 128) * 20;
            #pragma unroll
            for (int k = 0; k < 8; k++) { s[k] = acce[k]; s[8 + k] = acco[k]; }
        }
        __syncthreads();
        if (cih == 0) {
            const float* s = scr + tid * 20;
            const float b = bt3[co];
            float* oe = d3 + co * 108 + e * 12;
            float* oo = d3 + co * 108 + o * 12;
            #pragma unroll
            for (int k = 0; k < 8; k++) {
                oe[k] = eluf(acce[k] + s[k] + b);
                oo[k] = eluf(acco[k] + s[8 + k] + b);
            }
        }
    }
    __syncthreads();

    // T2 — register-staged output: accumulate (reads d3), barrier, store d4.
    {
        const int co = tid & 31, org = tid >> 5;
        float acc0[16] = {}, acc1[16] = {};
        const float* wb = wt2t + co;
        for (int ci = 0; ci < 32; ci++) {
            const float* base = d3 + ci * 108 + org * 12;
            float A[12], B[12];
            #pragma unroll
            for (int q = 0; q < 3; q++) {
                *(float4*)(A + 4 * q) = *(const float4*)(base + 4 * q);
                *(float4*)(B + 4 * q) = *(const float4*)(base + 12 + 4 * q);
            }
            float w10 = wb[3 * 1024 + ci * 32], w11 = wb[4 * 1024 + ci * 32], w12 = wb[5 * 1024 + ci * 32];
            float w20 = wb[6 * 1024 + ci * 32], w21 = wb[7 * 1024 + ci * 32], w22 = wb[8 * 1024 + ci * 32];
            float w00 = wb[0 * 1024 + ci * 32], w01 = wb[1 * 1024 + ci * 32], w02 = wb[2 * 1024 + ci * 32];
            xrow<8>(acc0, A, w10, w11, w12);
            xrow<8>(acc1, A, w20, w21, w22);
            xrow<8>(acc1, B, w00, w01, w02);
        }
        __syncthreads();   // all d3 reads drained -> d4 may overlay d3
        const float b = bt2[co];
        float* o0 = d4 + co * 260 + (2 * org) * 16;
        float* o1 = o0 + 16;
        #pragma unroll
        for (int q = 0; q < 4; q++) {
            float4 v0 = make_float4(eluf(acc0[4 * q] + b), eluf(acc0[4 * q + 1] + b),
                                    eluf(acc0[4 * q + 2] + b), eluf(acc0[4 * q + 3] + b));
            float4 v1 = make_float4(eluf(acc1[4 * q] + b), eluf(acc1[4 * q + 1] + b),
                                    eluf(acc1[4 * q + 2] + b), eluf(acc1[4 * q + 3] + b));
            *(float4*)(o0 + 4 * q) = v0;
            *(float4*)(o1 + 4 * q) = v1;
        }
    }
    __syncthreads();

    // T1 (round-6 form; explicit float2 stores)
    {
        const int ey = tid >> 4, ex = tid & 15;
        const float bb = bt1[0];
        float* xi = xr + n * 1024;
        float acc[4] = {};
        for (int ci = 0; ci < 32; ci++) {
            const float* a = d4 + ci * 260;
            const float* w = wt1 + ci * 9;
            for_taps<0, 0, 16, 16>(ey, ex, [&](int wk, int iy, int ix, bool v) {
                acc[0] = fmaf(v ? a[iy * 16 + ix] : 0.f, w[wk], acc[0]); });
            for_taps<0, 1, 16, 16>(ey, ex, [&](int wk, int iy, int ix, bool v) {
                acc[1] = fmaf(v ? a[iy * 16 + ix] : 0.f, w[wk], acc[1]); });
            for_taps<1, 0, 16, 16>(ey, ex, [&](int wk, int iy, int ix, bool v) {
                acc[2] = fmaf(v ? a[iy * 16 + ix] : 0.f, w[wk], acc[2]); });
            for_taps<1, 1, 16, 16>(ey, ex, [&](int wk, int iy, int ix, bool v) {
                acc[3] = fmaf(v ? a[iy * 16 + ix] : 0.f, w[wk], acc[3]); });
        }
        const float s0 = 1.f / (1.f + expf(-(acc[0] + bb)));
        const float s1 = 1.f / (1.f + expf(-(acc[1] + bb)));
        const float s2 = 1.f / (1.f + expf(-(acc[2] + bb)));
        const float s3 = 1.f / (1.f + expf(-(acc[3] + bb)));
        *(float2*)(xi + (2 * ey) * 32 + 2 * ex)     = make_float2(s0, s1);
        *(float2*)(xi + (2 * ey + 1) * 32 + 2 * ex) = make_float2(s2, s3);
    }
}

// ============================================================================
extern "C" void kernel_launch(void* const* d_in, const int* in_sizes, int n_in,
                              void* d_out, int out_size, void* d_ws, size_t ws_size,
                              hipStream_t stream)
{
    (void)in_sizes; (void)n_in; (void)out_size; (void)ws_size;
    const float* x    = (const float*)d_in[0];
    const float* eps  = (const float*)d_in[1];
    const float* w1 = (const float*)d_in[2];  const float* b1 = (const float*)d_in[3];
    const float* w2 = (const float*)d_in[4];  const float* b2 = (const float*)d_in[5];
    const float* w3 = (const float*)d_in[6];  const float* b3 = (const float*)d_in[7];
    const float* w4 = (const float*)d_in[8];  const float* b4 = (const float*)d_in[9];
    const float* w5 = (const float*)d_in[10]; const float* b5 = (const float*)d_in[11];
    const float* fc_mu_w = (const float*)d_in[12]; const float* fc_mu_b = (const float*)d_in[13];
    const float* fc_D_w  = (const float*)d_in[14]; const float* fc_D_b  = (const float*)d_in[15];
    const float* fc_B_w  = (const float*)d_in[16]; const float* fc_B_b  = (const float*)d_in[17];
    const float* fc_dec_w = (const float*)d_in[18]; const float* fc_dec_b = (const float*)d_in[19];
    const float* wt5 = (const float*)d_in[20]; const float* bt5 = (const float*)d_in[21];
    const float* wt4 = (const float*)d_in[22]; const float* bt4 = (const float*)d_in[23];
    const float* wt3 = (const float*)d_in[24]; const float* bt3 = (const float*)d_in[25];
    const float* wt2 = (const float*)d_in[26]; const float* bt2 = (const float*)d_in[27];
    const float* wt1 = (const float*)d_in[28]; const float* bt1 = (const float*)d_in[29];

    // workspace layout (floats): total 2,889,728 (~11.6 MB)
    float* ws   = (float*)d_ws;
    float* h    = ws;                  // 262144  [4096][64]
    float* Lb   = ws + 262144;         // 2097152 [256][256][32]
    float* z    = ws + 2359296;        // 65536
    float* hd0  = ws + 2424832;        // 262144  [4096][64]
    float* wt5t = ws + 2686976;        // 36864   [9][64][64]
    float* wt4t = ws + 2723840;        // 36864   [9][64][64]
    float* wt3t = ws + 2760704;        // 18432   [9][64][32]
    float* wt2t = ws + 2779136;        // 9216    [9][32][32]
    float* w2t  = ws + 2788352;        // 9216    [9][32][32]
    float* w3t  = ws + 2797568;        // 18432   [9][32][64]
    float* w4t  = ws + 2816000;        // 36864   [9][64][64]
    float* w5t  = ws + 2852864;        // 36864   [9][64][64]

    // output layout: xr | mu | cov | Pm
    float* out = (float*)d_out;
    float* xr  = out;                 // 4194304
    float* mu  = out + 4194304;       // 65536
    float* cov = out + 4259840;       // 16777216
    float* Pm  = out + 21037056;      // 16777216

    prep_all<<<17176, 256, 0, stream>>>(wt5, wt4, wt3, wt2, w2, w3, w4, w5,
                                        wt5t, wt4t, wt3t, wt2t, w2t, w3t, w4t, w5t,
                                        (float4*)Pm);
    enc_fused<<<4096, 256, 0, stream>>>(x, w1, b1, w2t, b2, w3t, b3, w4t, b4, w5t, b5, h);
    fc_enc<<<dim3(128, 4), 256, 0, stream>>>(h, fc_mu_w, fc_mu_b, fc_D_w, fc_D_b,
                                             fc_B_w, fc_B_b, mu, Pm);
    chol_band<<<256, 64, 0, stream>>>(Pm, Lb);
    inv_band<<<256, 256, 0, stream>>>(Lb, cov);
    zvec_k<<<256, 256, 0, stream>>>(cov, mu, eps, z);
    fc_dec_mu<<<1280, 256, 0, stream>>>(z, fc_dec_w, fc_dec_b, hd0,
                                        h, fc_mu_w, fc_mu_b, mu);
    dec_fused<<<4096, 256, 0, stream>>>(hd0, wt5t, bt5, wt4t, bt4, wt3t, bt3,
                                        wt2t, bt2, wt1, bt1, xr);
}

// Round 9
// 954.968 us; speedup vs baseline: 1.0395x; 1.0267x over previous
//
#include <hip/hip_runtime.h>
#include <cmath>

#define ALPHA 0.5f

// ============================================================================
// prep_all: pm_zero (16384 blocks) + weight transpose (792 blocks) fused.
// ============================================================================
__global__ __launch_bounds__(256) void prep_all(
    const float* __restrict__ dw5, const float* __restrict__ dw4,
    const float* __restrict__ dw3, const float* __restrict__ dw2,
    const float* __restrict__ ew2, const float* __restrict__ ew3,
    const float* __restrict__ ew4, const float* __restrict__ ew5,
    float* __restrict__ t5, float* __restrict__ t4,
    float* __restrict__ t3, float* __restrict__ t2,
    float* __restrict__ e2, float* __restrict__ e3,
    float* __restrict__ e4, float* __restrict__ e5,
    float4* __restrict__ Pm4)
{
    const int bid = blockIdx.x;
    if (bid < 16384) {
        Pm4[bid * 256 + threadIdx.x] = make_float4(0.f, 0.f, 0.f, 0.f);
        return;
    }
    int idx = (bid - 16384) * 256 + threadIdx.x;   // total 202752
    if (idx >= 202752) return;
    const float* w; float* t; int CIN, COUT, loc; bool enc = false;
    if (idx < 36864)       { w = dw5; t = t5; CIN = 64; COUT = 64; loc = idx; }
    else if (idx < 73728)  { w = dw4; t = t4; CIN = 64; COUT = 64; loc = idx - 36864; }
    else if (idx < 92160)  { w = dw3; t = t3; CIN = 64; COUT = 32; loc = idx - 73728; }
    else if (idx < 101376) { w = dw2; t = t2; CIN = 32; COUT = 32; loc = idx - 92160; }
    else if (idx < 110592) { w = ew2; t = e2; CIN = 32; COUT = 32; loc = idx - 101376; enc = true; }
    else if (idx < 129024) { w = ew3; t = e3; CIN = 32; COUT = 64; loc = idx - 110592; enc = true; }
    else if (idx < 165888) { w = ew4; t = e4; CIN = 64; COUT = 64; loc = idx - 129024; enc = true; }
    else                   { w = ew5; t = e5; CIN = 64; COUT = 64; loc = idx - 165888; enc = true; }
    int wk = loc % 9; int r = loc / 9; int ci, co;
    if (enc) { ci = r % CIN;  co = r / CIN;  }   // src [co][ci][k]
    else     { co = r % COUT; ci = r / COUT; }   // src [ci][co][k]
    t[wk * CIN * COUT + ci * COUT + co] = w[loc];
}

// ============================================================================
// Encoder (unchanged).
// ============================================================================
__device__ __forceinline__ int a1map(int iy, int col) {
    return (col & 7)
         | ((iy & 2) << 2)                   // iy[1]        -> bit3
         | (((iy ^ (iy >> 2)) & 1) << 4)     // iy[0]^iy[2]  -> bit4
         | ((col & 8) << 2)                  // col[3]       -> bit5
         | ((iy & 4) << 4)                   // iy[2]        -> bit6
         | ((iy & 8) << 4);                  // iy[3]        -> bit7
}

__global__ __launch_bounds__(256, 4) void enc_fused(
    const float* __restrict__ x,
    const float* __restrict__ w1,  const float* __restrict__ b1,
    const float* __restrict__ w2t, const float* __restrict__ b2,
    const float* __restrict__ w3t, const float* __restrict__ b3,
    const float* __restrict__ w4t, const float* __restrict__ b4,
    const float* __restrict__ w5t, const float* __restrict__ b5,
    float* __restrict__ hout)
{
    __shared__ __align__(16) float smem[10240];   // 40960 B -> 4 blocks/CU
    float* a1s  = smem;          // [32][256] permuted conv1 output (8192 fl)
    float* bse  = smem + 8192;   // region B (2048 fl): aliased by phase
    float* imgs = bse;           // phase0: [32][40] = 1280
    float* a2s  = bse;           // phase1+: [32][64] = 2048
    float* a3s  = smem;          // post-conv2 overlay of a1s: [64][16] = 1024
    float* a4s  = smem + 1024;   // [64][4] = 256
    float* reds = smem + 1280;   // [4][64] = 256

    const int n = blockIdx.x;
    const int tid = threadIdx.x;

    const float* xi = x + n * 1024;
    #pragma unroll
    for (int i = 0; i < 4; i++) {
        int idx = tid + 256 * i;
        int iy = idx >> 5, ix = idx & 31;
        int col = (ix & 1) ? 20 + (ix >> 1) : (ix >> 1);
        imgs[iy * 40 + col] = xi[idx];
    }
    __syncthreads();

    // conv1
    {
        const int oy = tid >> 4, ox = tid & 15;
        float patch[9];
        #pragma unroll
        for (int ky = 0; ky < 3; ky++) {
            const int iy = 2 * oy - 1 + ky;
            #pragma unroll
            for (int kx = 0; kx < 3; kx++) {
                const int ix = 2 * ox - 1 + kx;
                bool v = (iy >= 0) && (ix >= 0);
                int col = (ix & 1) ? 20 + (ix >> 1) : (ix >> 1);
                patch[ky * 3 + kx] = v ? imgs[iy * 40 + col] : 0.f;
            }
        }
        const int ocol = (ox & 1) ? 8 + (ox >> 1) : (ox >> 1);
        const int sidx = a1map(oy, ocol);
        for (int c = 0; c < 32; c++) {
            float acc = b1[c];
            #pragma unroll
            for (int k = 0; k < 9; k++) acc = fmaf(patch[k], w1[c * 9 + k], acc);
            a1s[c * 256 + sidx] = fmaxf(acc, 0.f);
        }
    }
    __syncthreads();

    // conv2 (4 waves, 8 co per thread)
    {
        const int p = tid & 63, oy = p >> 3, ox = p & 7;
        const int c0u = __builtin_amdgcn_readfirstlane(tid >> 6);
        const int cobase = c0u * 8;
        float acc[8];
        #pragma unroll
        for (int r = 0; r < 8; r++) acc[r] = b2[cobase + r];
        int offs[9]; bool val[9];
        #pragma unroll
        for (int ky = 0; ky < 3; ky++) {
            const int iy = 2 * oy - 1 + ky;
            #pragma unroll
            for (int kx = 0; kx < 3; kx++) {
                const int ix = 2 * ox - 1 + kx;
                const bool v = (iy >= 0) && (ix >= 0);
                const int col = (ix & 1) ? 8 + (ix >> 1) : (ix >> 1);
                offs[ky * 3 + kx] = v ? a1map(iy, col) : 0;
                val[ky * 3 + kx] = v;
            }
        }
        for (int ci = 0; ci < 32; ci++) {
            float patch[9];
            #pragma unroll
            for (int k = 0; k < 9; k++)
                patch[k] = val[k] ? a1s[ci * 256 + offs[k]] : 0.f;
            const float* wci = w2t + ci * 32 + cobase;
            #pragma unroll
            for (int k = 0; k < 9; k++) {
                #pragma unroll
                for (int r = 0; r < 8; r++)
                    acc[r] = fmaf(patch[k], wci[k * 1024 + r], acc[r]);
            }
        }
        __syncthreads();
        #pragma unroll
        for (int r = 0; r < 8; r++)
            a2s[(cobase + r) * 64 + p] = fmaxf(acc[r], 0.f);
    }
    __syncthreads();

    // conv3 (4 waves, 4 co per thread)
    {
        const int px = tid & 15, oy = px >> 2, ox = px & 3;
        const int cg = tid >> 4;
        float4 bv = ((const float4*)b3)[cg];
        float acc[4] = {bv.x, bv.y, bv.z, bv.w};
        for (int ci = 0; ci < 32; ci++) {
            float patch[9];
            #pragma unroll
            for (int ky = 0; ky < 3; ky++) {
                const int iy = 2 * oy - 1 + ky;
                #pragma unroll
                for (int kx = 0; kx < 3; kx++) {
                    const int ix = 2 * ox - 1 + kx;
                    bool v = (iy >= 0) && (ix >= 0);
                    patch[ky * 3 + kx] = v ? a2s[ci * 64 + iy * 8 + ix] : 0.f;
                }
            }
            #pragma unroll
            for (int k = 0; k < 9; k++) {
                float4 wv = *(const float4*)(w3t + k * 2048 + ci * 64 + cg * 4);
                acc[0] = fmaf(patch[k], wv.x, acc[0]);
                acc[1] = fmaf(patch[k], wv.y, acc[1]);
                acc[2] = fmaf(patch[k], wv.z, acc[2]);
                acc[3] = fmaf(patch[k], wv.w, acc[3]);
            }
        }
        #pragma unroll
        for (int r = 0; r < 4; r++)
            a3s[(cg * 4 + r) * 16 + px] = fmaxf(acc[r], 0.f);
    }
    __syncthreads();

    // conv4 (round-5 restructured form)
    {
        const int co = tid & 63;
        const int part = __builtin_amdgcn_readfirstlane(tid >> 6);
        float a0 = 0.f, a1 = 0.f, a2 = 0.f, a3 = 0.f;
        for (int ci = part * 16; ci < part * 16 + 16; ci++) {
            const float* wp = w4t + ci * 64 + co;
            const float w0 = wp[0];
            const float w1 = wp[4096];
            const float w2 = wp[8192];
            const float w3 = wp[12288];
            const float w4 = wp[16384];
            const float w5 = wp[20480];
            const float w6 = wp[24576];
            const float w7 = wp[28672];
            const float w8 = wp[32768];
            const float4 r0 = *(const float4*)(a3s + ci * 16);
            const float4 r1 = *(const float4*)(a3s + ci * 16 + 4);
            const float4 r2 = *(const float4*)(a3s + ci * 16 + 8);
            const float4 r3 = *(const float4*)(a3s + ci * 16 + 12);
            a0 = fmaf(r0.x, w4, a0); a0 = fmaf(r0.y, w5, a0);
            a0 = fmaf(r1.x, w7, a0); a0 = fmaf(r1.y, w8, a0);
            a1 = fmaf(r0.y, w3, a1); a1 = fmaf(r0.z, w4, a1); a1 = fmaf(r0.w, w5, a1);
            a1 = fmaf(r1.y, w6, a1); a1 = fmaf(r1.z, w7, a1); a1 = fmaf(r1.w, w8, a1);
            a2 = fmaf(r1.x, w1, a2); a2 = fmaf(r1.y, w2, a2);
            a2 = fmaf(r2.x, w4, a2); a2 = fmaf(r2.y, w5, a2);
            a2 = fmaf(r3.x, w7, a2); a2 = fmaf(r3.y, w8, a2);
            a3 = fmaf(r1.y, w0, a3); a3 = fmaf(r1.z, w1, a3); a3 = fmaf(r1.w, w2, a3);
            a3 = fmaf(r2.y, w3, a3); a3 = fmaf(r2.z, w4, a3); a3 = fmaf(r2.w, w5, a3);
            a3 = fmaf(r3.y, w6, a3); a3 = fmaf(r3.z, w7, a3); a3 = fmaf(r3.w, w8, a3);
        }
        float* reds2 = bse;   // a2s dead after conv3
        reds2[part * 256 +   0 + co] = a0;
        reds2[part * 256 +  64 + co] = a1;
        reds2[part * 256 + 128 + co] = a2;
        reds2[part * 256 + 192 + co] = a3;
        __syncthreads();
        {
            const int co2 = tid & 63;
            const int cls2 = __builtin_amdgcn_readfirstlane(tid >> 6);
            float s = b4[co2]
                    + reds2[      cls2 * 64 + co2] + reds2[256 + cls2 * 64 + co2]
                    + reds2[512 + cls2 * 64 + co2] + reds2[768 + cls2 * 64 + co2];
            a4s[co2 * 4 + cls2] = fmaxf(s, 0.f);
        }
    }
    __syncthreads();

    // conv5
    {
        const int c = tid & 63, part = tid >> 6;
        float s = 0.f;
        for (int ci = part * 16; ci < part * 16 + 16; ci++) {
            const float4 av = *(const float4*)(a4s + ci * 4);
            s = fmaf(av.x, w5t[4 * 4096 + ci * 64 + c], s);
            s = fmaf(av.y, w5t[5 * 4096 + ci * 64 + c], s);
            s = fmaf(av.z, w5t[7 * 4096 + ci * 64 + c], s);
            s = fmaf(av.w, w5t[8 * 4096 + ci * 64 + c], s);
        }
        reds[part * 64 + c] = s;
    }
    __syncthreads();
    if (tid < 64) {
        float v = b5[tid] + reds[tid] + reds[64 + tid] + reds[128 + tid] + reds[192 + tid];
        hout[n * 64 + tid] = fmaxf(v, 0.f);
    }
}

// ============================================================================
// FC heads (unchanged): mu -> d_out; D/B heads -> Pm directly.
// ============================================================================
__global__ __launch_bounds__(256) void fc_enc(
    const float* __restrict__ h,
    const float* __restrict__ wmu, const float* __restrict__ bmu,
    const float* __restrict__ wD,  const float* __restrict__ bD,
    const float* __restrict__ wB,  const float* __restrict__ bB,
    float* __restrict__ mu, float* __restrict__ Pm)
{
    __shared__ float As[32][65];
    __shared__ float Bs[32][65];
    const int tid = threadIdx.x;
    const int m0 = blockIdx.y * 64;
    const int n0 = blockIdx.x * 64;

    const float* wbase; const float* bias; int nloc; int region;
    if (n0 < 256)       { wbase = wmu; bias = bmu; nloc = n0;        region = 0; }
    else if (n0 < 4352) { wbase = wD;  bias = bD;  nloc = n0 - 256;  region = 1; }
    else                { wbase = wB;  bias = bB;  nloc = n0 - 4352; region = 2; }

    const int tx = tid & 15, ty = tid >> 4;
    float acc[4][4] = {};
    for (int k0 = 0; k0 < 1024; k0 += 32) {
        #pragma unroll
        for (int s = 0; s < 8; s++) {
            int l = tid + 256 * s;
            int row = l >> 5, kk = l & 31;
            As[kk][row] = h[(m0 + row) * 1024 + k0 + kk];
            Bs[kk][row] = wbase[(nloc + row) * 1024 + k0 + kk];
        }
        __syncthreads();
        #pragma unroll
        for (int kk = 0; kk < 32; kk++) {
            float av[4], bv[4];
            #pragma unroll
            for (int i = 0; i < 4; i++) av[i] = As[kk][ty * 4 + i];
            #pragma unroll
            for (int j = 0; j < 4; j++) bv[j] = Bs[kk][tx * 4 + j];
            #pragma unroll
            for (int i = 0; i < 4; i++)
                #pragma unroll
                for (int j = 0; j < 4; j++) acc[i][j] = fmaf(av[i], bv[j], acc[i][j]);
        }
        __syncthreads();
    }
    #pragma unroll
    for (int i = 0; i < 4; i++) {
        int m = m0 + ty * 4 + i;
        size_t pbase = (size_t)m * 65536;
        #pragma unroll
        for (int j = 0; j < 4; j++) {
            int nc = nloc + tx * 4 + j;
            float v = acc[i][j] + bias[nc];
            if (region == 0) {
                mu[m * 256 + nc] = v;
            } else {
                int t = nc >> 8, pi = (nc >> 4) & 15, pj = nc & 15;
                if (region == 1) {
                    int row = t * 16 + pi, col = t * 16 + pj;
                    Pm[pbase + row * 256 + col] = v + (pi == pj ? ALPHA : 0.f);
                } else {
                    int row = (t + 1) * 16 + pi, col = t * 16 + pj;
                    Pm[pbase + row * 256 + col] = v;      // sub-diagonal
                    Pm[pbase + col * 256 + row] = v;      // super-diagonal (transposed)
                }
            }
        }
    }
}

// ============================================================================
// chol_inv: banded Cholesky + cov=inv(L) fused in one kernel. The band stays
// resident in LDS between the phases (identical Lb[i*32+d] layout) — saves a
// launch gap, the 16 MB Lb_g round trip, chol's 128-store writeback and inv's
// 8-load restage. 256 threads: chol phase is wave-0-only (guards d<32 etc.;
// __shfl is per-wave so wave-0 semantics match the old 64-thread kernel; all
// threads reach every barrier). rs aliases the dead Ds region (LDS cap 64KB).
// Arithmetic order identical in both phases -> absmax unchanged.
// ============================================================================
__global__ __launch_bounds__(256) void chol_inv(
    const float* __restrict__ Pm, float* __restrict__ cov)
{
    __shared__ __align__(16) float Lb[256 * 32 + 32];   // 8224 fl (+pad)
    __shared__ float Ds[4096];
    __shared__ float Bs2[3840];                          // total 64640 B
    const int b = blockIdx.x, tid = threadIdx.x;
    const float* Pb = Pm + (size_t)b * 65536;

    // stage (256-thread wide)
    for (int i = tid; i < 8224; i += 256) Lb[i] = 0.f;
    for (int i = tid; i < 4096; i += 256) {
        int t = i >> 8, r = (i >> 4) & 15, c = i & 15;
        Ds[i] = Pb[(t * 16 + r) * 256 + t * 16 + c];
    }
    for (int i = tid; i < 3840; i += 256) {
        int t = i >> 8, r = (i >> 4) & 15, c = i & 15;
        Bs2[i] = Pb[((t + 1) * 16 + r) * 256 + t * 16 + c];
    }
    __syncthreads();

    // ---- chol phase (wave 0 computes; others idle at barriers) ----
    const int d = tid;
    for (int j = 0; j < 256; j++) {
        const int i = j + d;
        float s = 0.f;
        if (d < 32 && i < 256) {
            int bi = i >> 4, bj = j >> 4, pi = i & 15, pj = j & 15;
            float a;
            if (bi == bj)           a = Ds[bi * 256 + pi * 16 + pj];
            else if (bi == bj + 1)  a = Bs2[bj * 256 + pi * 16 + pj];
            else                    a = 0.f;

            float c[32], p[32];
            const float* cp = Lb + j * 32;
            #pragma unroll
            for (int q = 0; q < 8; q++)
                *(float4*)(c + 4 * q) = *(const float4*)(cp + 4 * q);
            const float* pp = Lb + i * 32 + d;
            #pragma unroll
            for (int m = 1; m < 32; m++) p[m] = pp[m];

            float s0 = 0.f, s1 = 0.f, s2 = 0.f, s3 = 0.f;
            #pragma unroll
            for (int m = 1; m <= 28; m += 4) {
                s0 = fmaf(p[m],     c[m],     s0);
                s1 = fmaf(p[m + 1], c[m + 1], s1);
                s2 = fmaf(p[m + 2], c[m + 2], s2);
                s3 = fmaf(p[m + 3], c[m + 3], s3);
            }
            s0 = fmaf(p[29], c[29], s0);
            s1 = fmaf(p[30], c[30], s1);
            s2 = fmaf(p[31], c[31], s2);
            s = a - ((s0 + s1) + (s2 + s3));
        }
        float diag = __shfl(s, 0);
        float Ljj = sqrtf(diag);
        if (d == 0)                  Lb[j * 32] = Ljj;
        else if (d < 32 && i < 256)  Lb[i * 32 + d] = s / Ljj;
        __syncthreads();
    }

    // ---- inv phase (Lb in place; rs aliases dead Ds) ----
    float* rs = Ds;
    const int j = tid;
    rs[j] = 1.f / Lb[j * 32];
    __syncthreads();

    float* covb = cov + (size_t)b * 65536;
    const int w = __builtin_amdgcn_readfirstlane(j >> 6);
    const int istart = w * 64;                 // 32-aligned, <= any j in wave

    for (int i = 0; i < istart; i++) covb[i * 256 + j] = 0.f;

    float g[32];
    #pragma unroll
    for (int q = 0; q < 32; q++) g[q] = 0.f;

    for (int c = istart; c < 256; c += 32) {
        #pragma unroll
        for (int u = 0; u < 32; u++) {
            const int i = c + u;                       // wave-uniform
            const float* Lr = Lb + i * 32;             // broadcast LDS reads
            float lrow[32];
            #pragma unroll
            for (int q = 0; q < 8; q++)
                *(float4*)(lrow + 4 * q) = *(const float4*)(Lr + 4 * q);
            float s0 = 0.f, s1 = 0.f, s2 = 0.f, s3 = 0.f;
            #pragma unroll
            for (int dd = 1; dd < 32; dd += 4) {
                s0 = fmaf(lrow[dd],     g[(u - dd) & 31],     s0);
                if (dd + 1 < 32) s1 = fmaf(lrow[dd + 1], g[(u - dd - 1) & 31], s1);
                if (dd + 2 < 32) s2 = fmaf(lrow[dd + 2], g[(u - dd - 2) & 31], s2);
                if (dd + 3 < 32) s3 = fmaf(lrow[dd + 3], g[(u - dd - 3) & 31], s3);
            }
            float s = (s0 + s1) + (s2 + s3);
            float gi = (((i == j) ? 1.f : 0.f) - s) * rs[i];
            g[u & 31] = gi;
            covb[i * 256 + j] = gi;                    // coalesced
        }
    }
}

// ============================================================================
// z = mu + cov @ eps (unchanged)
// ============================================================================
__global__ __launch_bounds__(256) void zvec_k(
    const float* __restrict__ cov, const float* __restrict__ mu,
    const float* __restrict__ eps, float* __restrict__ z)
{
    __shared__ float es[256];
    const int b = blockIdx.x, i = threadIdx.x;
    es[i] = eps[b * 256 + i];
    __syncthreads();
    const float4* row = (const float4*)(cov + (size_t)b * 65536 + i * 256);
    float s = 0.f;
    #pragma unroll 8
    for (int k = 0; k < 64; k++) {
        float4 v = row[k];
        s = fmaf(v.x, es[4 * k], s);
        s = fmaf(v.y, es[4 * k + 1], s);
        s = fmaf(v.z, es[4 * k + 2], s);
        s = fmaf(v.w, es[4 * k + 3], s);
    }
    z[b * 256 + i] = mu[b * 256 + i] + s;
}

// ============================================================================
// fc_dec + mu_fix fused (unchanged)
// ============================================================================
__global__ __launch_bounds__(256) void fc_dec_mu(
    const float* __restrict__ z, const float* __restrict__ w,
    const float* __restrict__ bias, float* __restrict__ hd0,
    const float* __restrict__ h, const float* __restrict__ wmu,
    const float* __restrict__ bmu, float* __restrict__ mu)
{
    __shared__ float sh[1024];
    const int blk = blockIdx.x;
    if (blk < 1024) {
        // fc_dec
        const int b = blk >> 2;
        const int f = ((blk & 3) << 8) + threadIdx.x;
        sh[threadIdx.x] = z[b * 256 + threadIdx.x];
        __syncthreads();
        const float4* wr = (const float4*)(w + f * 256);
        float s = 0.f;
        #pragma unroll 8
        for (int k = 0; k < 64; k++) {
            float4 v = wr[k];
            s = fmaf(v.x, sh[4 * k], s);
            s = fmaf(v.y, sh[4 * k + 1], s);
            s = fmaf(v.z, sh[4 * k + 2], s);
            s = fmaf(v.w, sh[4 * k + 3], s);
        }
        hd0[b * 1024 + f] = s + bias[f];
    } else {
        // mu_fix
        const int b = blk - 1024, p = threadIdx.x;
        #pragma unroll
        for (int i = 0; i < 4; i++) sh[p + 256 * i] = h[b * 1024 + p + 256 * i];
        __syncthreads();
        const float4* wr = (const float4*)(wmu + p * 1024);
        float s = 0.f;
        #pragma unroll 8
        for (int k = 0; k < 256; k++) {
            float4 v = wr[k];
            s = fmaf(v.x, sh[4 * k], s);
            s = fmaf(v.y, sh[4 * k + 1], s);
            s = fmaf(v.z, sh[4 * k + 2], s);
            s = fmaf(v.w, sh[4 * k + 3], s);
        }
        mu[b * 256 + p] = s + bmu[p];
    }
}

// ============================================================================
// Decoder: EXACT round-6 form (235 µs measured). Round 7's T1 rewrite broke
// store coalescing (WRITE_SIZE +8MB); round 8's float2 packing cost ~10 µs.
// Scalar stores in original order are the measured-best codegen.
// ============================================================================
__device__ __forceinline__ float eluf(float v) { return v > 0.f ? v : expf(v) - 1.f; }

template<int PY, int PX, int HIN, int WIN, class F>
__device__ __forceinline__ void for_taps(int ey, int ex, F&& f) {
    if (PY == 0) {
        if (PX == 0) { f(4, ey, ex, true); }
        else         { f(5, ey, ex, true); f(3, ey, ex + 1, ex + 1 < WIN); }
    } else {
        if (PX == 0) { f(7, ey, ex, true); f(1, ey + 1, ex, ey + 1 < HIN); }
        else {
            f(8, ey, ex, true);
            f(6, ey, ex + 1, ex + 1 < WIN);
            f(2, ey + 1, ex, ey + 1 < HIN);
            f(0, ey + 1, ex + 1, (ey + 1 < HIN) && (ex + 1 < WIN));
        }
    }
}

template<int OY>
__device__ __forceinline__ void t4_row(
    const float* __restrict__ wt4t, const float* __restrict__ bt4,
    const float* __restrict__ d1, float* __restrict__ d2, int co)
{
    float a0 = 0.f, a1 = 0.f, a2 = 0.f, a3 = 0.f;
    const float* wb = wt4t + co;
    for (int ci = 0; ci < 64; ci++) {
        const float* base = d1 + ci * 12;
        if (OY % 2 == 0) {
            float4 r = *(const float4*)(base + (OY / 2) * 4);
            float w10 = wb[3 * 4096 + ci * 64];
            float w11 = wb[4 * 4096 + ci * 64];
            float w12 = wb[5 * 4096 + ci * 64];
            a0 = fmaf(r.x, w11, a0);
            a1 = fmaf(r.x, w12, a1); a1 = fmaf(r.y, w10, a1);
            a2 = fmaf(r.y, w11, a2);
            a3 = fmaf(r.y, w12, a3); a3 = fmaf(r.z, w10, a3);
        } else {
            float4 ra = *(const float4*)(base + ((OY - 1) / 2) * 4);
            float4 rb = *(const float4*)(base + ((OY + 1) / 2) * 4);
            float w20 = wb[6 * 4096 + ci * 64], w21 = wb[7 * 4096 + ci * 64], w22 = wb[8 * 4096 + ci * 64];
            float w00 = wb[0 * 4096 + ci * 64], w01 = wb[1 * 4096 + ci * 64], w02 = wb[2 * 4096 + ci * 64];
            a0 = fmaf(ra.x, w21, a0); a0 = fmaf(rb.x, w01, a0);
            a1 = fmaf(ra.x, w22, a1); a1 = fmaf(ra.y, w20, a1);
            a1 = fmaf(rb.x, w02, a1); a1 = fmaf(rb.y, w00, a1);
            a2 = fmaf(ra.y, w21, a2); a2 = fmaf(rb.y, w01, a2);
            a3 = fmaf(ra.y, w22, a3); a3 = fmaf(ra.z, w20, a3);
            a3 = fmaf(rb.y, w02, a3); a3 = fmaf(rb.z, w00, a3);
        }
    }
    float b = bt4[co];
    float4 o = make_float4(eluf(a0 + b), eluf(a1 + b), eluf(a2 + b), eluf(a3 + b));
    *(float4*)(d2 + co * 44 + OY * 8) = o;
}

template<int M>
__device__ __forceinline__ void xrow(float* acc, const float* R, float w0, float w1, float w2)
{
    #pragma unroll
    for (int m = 0; m < M; m++) {
        acc[2 * m]     = fmaf(R[m], w1, acc[2 * m]);
        acc[2 * m + 1] = fmaf(R[m], w2, acc[2 * m + 1]);
        acc[2 * m + 1] = fmaf(R[m + 1], w0, acc[2 * m + 1]);
    }
}

__global__ __launch_bounds__(256, 4) void dec_fused(
    const float* __restrict__ hd0,
    const float* __restrict__ wt5t, const float* __restrict__ bt5,
    const float* __restrict__ wt4t, const float* __restrict__ bt4,
    const float* __restrict__ wt3t, const float* __restrict__ bt3,
    const float* __restrict__ wt2t, const float* __restrict__ bt2,
    const float* __restrict__ wt1,  const float* __restrict__ bt1,
    float* __restrict__ xr)
{
    __shared__ __align__(16) float smem[9664];   // 38656 B -> 4 blocks/CU
    float* d0  = smem;            // 64
    float* d1  = smem + 64;       // [64][3][4] pitch 12
    float* d2  = smem + 832;      // [64][44], rows pitch 8 (5 rows)
    float* scr = smem + 3648;     // [128][20]
    float* d3  = smem + 6208;     // [32][108], rows pitch 12 (9 rows)
    float* d4  = smem;            // [32][260] overlays A+scr+d3 after T2 barrier

    const int n = blockIdx.x, tid = threadIdx.x;

    for (int i = tid; i < 3584; i += 256) smem[64 + i] = 0.f;
    for (int i = tid; i < 3456; i += 256) d3[i] = 0.f;
    if (tid < 64) d0[tid] = hd0[n * 64 + tid];
    __syncthreads();

    // T5
    {
        const int co = tid & 63;
        const int wv = __builtin_amdgcn_readfirstlane(tid >> 6);
        const int oy = wv >> 1, ox = wv & 1;
        const int wk = (oy + 1) * 3 + (ox + 1);
        const float* wp = wt5t + wk * 4096 + co;
        float s = bt5[co];
        for (int ci = 0; ci < 64; ci++)
            s = fmaf(d0[ci], wp[ci * 64], s);
        d1[co * 12 + oy * 4 + ox] = eluf(s);
    }
    __syncthreads();

    // T4
    {
        const int co = tid & 63;
        const int oyw = __builtin_amdgcn_readfirstlane(tid >> 6);
        if (oyw == 0)      t4_row<0>(wt4t, bt4, d1, d2, co);
        else if (oyw == 1) t4_row<1>(wt4t, bt4, d1, d2, co);
        else if (oyw == 2) t4_row<2>(wt4t, bt4, d1, d2, co);
        else               t4_row<3>(wt4t, bt4, d1, d2, co);
    }
    __syncthreads();

    // T3
    {
        const int co = tid & 31, pr = (tid >> 5) & 3, cih = tid >> 7;
        const int e = (pr & 1) ? 7 - pr : pr;
        const int o = (pr & 1) ? pr : 7 - pr;
        const int iy_e = e >> 1, iy_o2 = (o - 1) >> 1, iy_o0 = (o + 1) >> 1;
        float acce[8] = {}, acco[8] = {};
        const float* wb = wt3t + co;
        for (int c = 0; c < 32; c++) {
            const int ci = cih * 32 + c;
            const float* base = d2 + ci * 44;
            float re[8], ro2[8], ro0[8];
            *(float4*)(re)      = *(const float4*)(base + iy_e * 8);
            *(float4*)(re + 4)  = *(const float4*)(base + iy_e * 8 + 4);
            *(float4*)(ro2)     = *(const float4*)(base + iy_o2 * 8);
            *(float4*)(ro2 + 4) = *(const float4*)(base + iy_o2 * 8 + 4);
            *(float4*)(ro0)     = *(const float4*)(base + iy_o0 * 8);
            *(float4*)(ro0 + 4) = *(const float4*)(base + iy_o0 * 8 + 4);
            float w10 = wb[3 * 2048 + ci * 32], w11 = wb[4 * 2048 + ci * 32], w12 = wb[5 * 2048 + ci * 32];
            float w20 = wb[6 * 2048 + ci * 32], w21 = wb[7 * 2048 + ci * 32], w22 = wb[8 * 2048 + ci * 32];
            float w00 = wb[0 * 2048 + ci * 32], w01 = wb[1 * 2048 + ci * 32], w02 = wb[2 * 2048 + ci * 32];
            xrow<4>(acce, re, w10, w11, w12);
            xrow<4>(acco, ro2, w20, w21, w22);
            xrow<4>(acco, ro0, w00, w01, w02);
        }
        if (cih == 1) {
            float* s = scr + (tid - 128) * 20;
            #pragma unroll
            for (int k = 0; k < 8; k++) { s[k] = acce[k]; s[8 + k] = acco[k]; }
        }
        __syncthreads();
        if (cih == 0) {
            const float* s = scr + tid * 20;
            const float b = bt3[co];
            float* oe = d3 + co * 108 + e * 12;
            float* oo = d3 + co * 108 + o * 12;
            #pragma unroll
            for (int k = 0; k < 8; k++) {
                oe[k] = eluf(acce[k] + s[k] + b);
                oo[k] = eluf(acco[k] + s[8 + k] + b);
            }
        }
    }
    __syncthreads();

    // T2 — register-staged output: accumulate (reads d3), barrier, store d4.
    {
        const int co = tid & 31, org = tid >> 5;
        float acc0[16] = {}, acc1[16] = {};
        const float* wb = wt2t + co;
        for (int ci = 0; ci < 32; ci++) {
            const float* base = d3 + ci * 108 + org * 12;
            float A[12], B[12];
            #pragma unroll
            for (int q = 0; q < 3; q++) {
                *(float4*)(A + 4 * q) = *(const float4*)(base + 4 * q);
                *(float4*)(B + 4 * q) = *(const float4*)(base + 12 + 4 * q);
            }
            float w10 = wb[3 * 1024 + ci * 32], w11 = wb[4 * 1024 + ci * 32], w12 = wb[5 * 1024 + ci * 32];
            float w20 = wb[6 * 1024 + ci * 32], w21 = wb[7 * 1024 + ci * 32], w22 = wb[8 * 1024 + ci * 32];
            float w00 = wb[0 * 1024 + ci * 32], w01 = wb[1 * 1024 + ci * 32], w02 = wb[2 * 1024 + ci * 32];
            xrow<8>(acc0, A, w10, w11, w12);
            xrow<8>(acc1, A, w20, w21, w22);
            xrow<8>(acc1, B, w00, w01, w02);
        }
        __syncthreads();   // all d3 reads drained -> d4 may overlay d3
        const float b = bt2[co];
        float* o0 = d4 + co * 260 + (2 * org) * 16;
        float* o1 = o0 + 16;
        #pragma unroll
        for (int q = 0; q < 4; q++) {
            float4 v0 = make_float4(eluf(acc0[4 * q] + b), eluf(acc0[4 * q + 1] + b),
                                    eluf(acc0[4 * q + 2] + b), eluf(acc0[4 * q + 3] + b));
            float4 v1 = make_float4(eluf(acc1[4 * q] + b), eluf(acc1[4 * q + 1] + b),
                                    eluf(acc1[4 * q + 2] + b), eluf(acc1[4 * q + 3] + b));
            *(float4*)(o0 + 4 * q) = v0;
            *(float4*)(o1 + 4 * q) = v1;
        }
    }
    __syncthreads();

    // T1 (exact round-6 form)
    {
        const int ey = tid >> 4, ex = tid & 15;
        const float bb = bt1[0];
        float* xi = xr + n * 1024;
        float acc[4] = {};
        for (int ci = 0; ci < 32; ci++) {
            const float* a = d4 + ci * 260;
            const float* w = wt1 + ci * 9;
            for_taps<0, 0, 16, 16>(ey, ex, [&](int wk, int iy, int ix, bool v) {
                acc[0] = fmaf(v ? a[iy * 16 + ix] : 0.f, w[wk], acc[0]); });
            for_taps<0, 1, 16, 16>(ey, ex, [&](int wk, int iy, int ix, bool v) {
                acc[1] = fmaf(v ? a[iy * 16 + ix] : 0.f, w[wk], acc[1]); });
            for_taps<1, 0, 16, 16>(ey, ex, [&](int wk, int iy, int ix, bool v) {
                acc[2] = fmaf(v ? a[iy * 16 + ix] : 0.f, w[wk], acc[2]); });
            for_taps<1, 1, 16, 16>(ey, ex, [&](int wk, int iy, int ix, bool v) {
                acc[3] = fmaf(v ? a[iy * 16 + ix] : 0.f, w[wk], acc[3]); });
        }
        xi[(2 * ey) * 32 + 2 * ex]         = 1.f / (1.f + expf(-(acc[0] + bb)));
        xi[(2 * ey) * 32 + 2 * ex + 1]     = 1.f / (1.f + expf(-(acc[1] + bb)));
        xi[(2 * ey + 1) * 32 + 2 * ex]     = 1.f / (1.f + expf(-(acc[2] + bb)));
        xi[(2 * ey + 1) * 32 + 2 * ex + 1] = 1.f / (1.f + expf(-(acc[3] + bb)));
    }
}

// ============================================================================
extern "C" void kernel_launch(void* const* d_in, const int* in_sizes, int n_in,
                              void* d_out, int out_size, void* d_ws, size_t ws_size,
                              hipStream_t stream)
{
    (void)in_sizes; (void)n_in; (void)out_size; (void)ws_size;
    const float* x    = (const float*)d_in[0];
    const float* eps  = (const float*)d_in[1];
    const float* w1 = (const float*)d_in[2];  const float* b1 = (const float*)d_in[3];
    const float* w2 = (const float*)d_in[4];  const float* b2 = (const float*)d_in[5];
    const float* w3 = (const float*)d_in[6];  const float* b3 = (const float*)d_in[7];
    const float* w4 = (const float*)d_in[8];  const float* b4 = (const float*)d_in[9];
    const float* w5 = (const float*)d_in[10]; const float* b5 = (const float*)d_in[11];
    const float* fc_mu_w = (const float*)d_in[12]; const float* fc_mu_b = (const float*)d_in[13];
    const float* fc_D_w  = (const float*)d_in[14]; const float* fc_D_b  = (const float*)d_in[15];
    const float* fc_B_w  = (const float*)d_in[16]; const float* fc_B_b  = (const float*)d_in[17];
    const float* fc_dec_w = (const float*)d_in[18]; const float* fc_dec_b = (const float*)d_in[19];
    const float* wt5 = (const float*)d_in[20]; const float* bt5 = (const float*)d_in[21];
    const float* wt4 = (const float*)d_in[22]; const float* bt4 = (const float*)d_in[23];
    const float* wt3 = (const float*)d_in[24]; const float* bt3 = (const float*)d_in[25];
    const float* wt2 = (const float*)d_in[26]; const float* bt2 = (const float*)d_in[27];
    const float* wt1 = (const float*)d_in[28]; const float* bt1 = (const float*)d_in[29];

    // workspace layout (floats)
    float* ws   = (float*)d_ws;
    float* h    = ws;                  // 262144  [4096][64]
    float* z    = ws + 2359296;        // 65536
    float* hd0  = ws + 2424832;        // 262144  [4096][64]
    float* wt5t = ws + 2686976;        // 36864   [9][64][64]
    float* wt4t = ws + 2723840;        // 36864   [9][64][64]
    float* wt3t = ws + 2760704;        // 18432   [9][64][32]
    float* wt2t = ws + 2779136;        // 9216    [9][32][32]
    float* w2t  = ws + 2788352;        // 9216    [9][32][32]
    float* w3t  = ws + 2797568;        // 18432   [9][32][64]
    float* w4t  = ws + 2816000;        // 36864   [9][64][64]
    float* w5t  = ws + 2852864;        // 36864   [9][64][64]

    // output layout: xr | mu | cov | Pm
    float* out = (float*)d_out;
    float* xr  = out;                 // 4194304
    float* mu  = out + 4194304;       // 65536
    float* cov = out + 4259840;       // 16777216
    float* Pm  = out + 21037056;      // 16777216

    prep_all<<<17176, 256, 0, stream>>>(wt5, wt4, wt3, wt2, w2, w3, w4, w5,
                                        wt5t, wt4t, wt3t, wt2t, w2t, w3t, w4t, w5t,
                                        (float4*)Pm);
    enc_fused<<<4096, 256, 0, stream>>>(x, w1, b1, w2t, b2, w3t, b3, w4t, b4, w5t, b5, h);
    fc_enc<<<dim3(128, 4), 256, 0, stream>>>(h, fc_mu_w, fc_mu_b, fc_D_w, fc_D_b,
                                             fc_B_w, fc_B_b, mu, Pm);
    chol_inv<<<256, 256, 0, stream>>>(Pm, cov);
    zvec_k<<<256, 256, 0, stream>>>(cov, mu, eps, z);
    fc_dec_mu<<<1280, 256, 0, stream>>>(z, fc_dec_w, fc_dec_b, hd0,
                                        h, fc_mu_w, fc_mu_b, mu);
    dec_fused<<<4096, 256, 0, stream>>>(hd0, wt5t, bt5, wt4t, bt4, wt3t, bt3,
                                        wt2t, bt2, wt1, bt1, xr);
}

// Round 10
// 954.472 us; speedup vs baseline: 1.0400x; 1.0005x over previous
//
#include <hip/hip_runtime.h>
#include <cmath>

#define ALPHA 0.5f

// ============================================================================
// prep_all: pm_zero (16384 blocks) + weight transpose (792 blocks) fused.
// ============================================================================
__global__ __launch_bounds__(256) void prep_all(
    const float* __restrict__ dw5, const float* __restrict__ dw4,
    const float* __restrict__ dw3, const float* __restrict__ dw2,
    const float* __restrict__ ew2, const float* __restrict__ ew3,
    const float* __restrict__ ew4, const float* __restrict__ ew5,
    float* __restrict__ t5, float* __restrict__ t4,
    float* __restrict__ t3, float* __restrict__ t2,
    float* __restrict__ e2, float* __restrict__ e3,
    float* __restrict__ e4, float* __restrict__ e5,
    float4* __restrict__ Pm4)
{
    const int bid = blockIdx.x;
    if (bid < 16384) {
        Pm4[bid * 256 + threadIdx.x] = make_float4(0.f, 0.f, 0.f, 0.f);
        return;
    }
    int idx = (bid - 16384) * 256 + threadIdx.x;   // total 202752
    if (idx >= 202752) return;
    const float* w; float* t; int CIN, COUT, loc; bool enc = false;
    if (idx < 36864)       { w = dw5; t = t5; CIN = 64; COUT = 64; loc = idx; }
    else if (idx < 73728)  { w = dw4; t = t4; CIN = 64; COUT = 64; loc = idx - 36864; }
    else if (idx < 92160)  { w = dw3; t = t3; CIN = 64; COUT = 32; loc = idx - 73728; }
    else if (idx < 101376) { w = dw2; t = t2; CIN = 32; COUT = 32; loc = idx - 92160; }
    else if (idx < 110592) { w = ew2; t = e2; CIN = 32; COUT = 32; loc = idx - 101376; enc = true; }
    else if (idx < 129024) { w = ew3; t = e3; CIN = 32; COUT = 64; loc = idx - 110592; enc = true; }
    else if (idx < 165888) { w = ew4; t = e4; CIN = 64; COUT = 64; loc = idx - 129024; enc = true; }
    else                   { w = ew5; t = e5; CIN = 64; COUT = 64; loc = idx - 165888; enc = true; }
    int wk = loc % 9; int r = loc / 9; int ci, co;
    if (enc) { ci = r % CIN;  co = r / CIN;  }   // src [co][ci][k]
    else     { co = r % COUT; ci = r / COUT; }   // src [ci][co][k]
    t[wk * CIN * COUT + ci * COUT + co] = w[loc];
}

// ============================================================================
// Encoder v6: LDS cut 40960 -> 32768 B (5 blocks/CU, exactly fills 160 KiB).
//   - imgs overlays a1s: conv1 stages its 9-tap patch into REGISTERS, one
//     added barrier, then writes a1s over the dead imgs region.
//   - a2s overlays a1s[0..2048): conv2 keeps acc in regs and stores only
//     after its internal __syncthreads (all a1s reads drained).
//   - a3s[2048..3072), a4s[3072..3328), reds[3328..3584), reds2[3584..4608):
//     disjoint from every concurrent reader (checked phase by phase).
// Same FMA order everywhere -> bitwise identical results.
// ============================================================================
__device__ __forceinline__ int a1map(int iy, int col) {
    return (col & 7)
         | ((iy & 2) << 2)                   // iy[1]        -> bit3
         | (((iy ^ (iy >> 2)) & 1) << 4)     // iy[0]^iy[2]  -> bit4
         | ((col & 8) << 2)                  // col[3]       -> bit5
         | ((iy & 4) << 4)                   // iy[2]        -> bit6
         | ((iy & 8) << 4);                  // iy[3]        -> bit7
}

__global__ __launch_bounds__(256, 5) void enc_fused(
    const float* __restrict__ x,
    const float* __restrict__ w1,  const float* __restrict__ b1,
    const float* __restrict__ w2t, const float* __restrict__ b2,
    const float* __restrict__ w3t, const float* __restrict__ b3,
    const float* __restrict__ w4t, const float* __restrict__ b4,
    const float* __restrict__ w5t, const float* __restrict__ b5,
    float* __restrict__ hout)
{
    __shared__ __align__(16) float smem[8192];   // 32768 B -> 5 blocks/CU
    float* a1s   = smem;           // [32][256] permuted conv1 output (8192 fl)
    float* imgs  = smem;           // phase0/conv1-read: [32][40] (overlaid)
    float* a2s   = smem;           // conv2 out: [32][64] = 2048 (overlays a1s)
    float* a3s   = smem + 2048;    // [64][16] = 1024
    float* a4s   = smem + 3072;    // [64][4] = 256
    float* reds  = smem + 3328;    // [4][64] = 256
    float* reds2 = smem + 3584;    // [4][4][64] = 1024

    const int n = blockIdx.x;
    const int tid = threadIdx.x;

    const float* xi = x + n * 1024;
    #pragma unroll
    for (int i = 0; i < 4; i++) {
        int idx = tid + 256 * i;
        int iy = idx >> 5, ix = idx & 31;
        int col = (ix & 1) ? 20 + (ix >> 1) : (ix >> 1);
        imgs[iy * 40 + col] = xi[idx];
    }
    __syncthreads();

    // conv1 — patch staged to regs, barrier, then a1s overlays imgs
    {
        const int oy = tid >> 4, ox = tid & 15;
        float patch[9];
        #pragma unroll
        for (int ky = 0; ky < 3; ky++) {
            const int iy = 2 * oy - 1 + ky;
            #pragma unroll
            for (int kx = 0; kx < 3; kx++) {
                const int ix = 2 * ox - 1 + kx;
                bool v = (iy >= 0) && (ix >= 0);
                int col = (ix & 1) ? 20 + (ix >> 1) : (ix >> 1);
                patch[ky * 3 + kx] = v ? imgs[iy * 40 + col] : 0.f;
            }
        }
        __syncthreads();   // all imgs reads done -> a1s may overlay imgs
        const int ocol = (ox & 1) ? 8 + (ox >> 1) : (ox >> 1);
        const int sidx = a1map(oy, ocol);
        for (int c = 0; c < 32; c++) {
            float acc = b1[c];
            #pragma unroll
            for (int k = 0; k < 9; k++) acc = fmaf(patch[k], w1[c * 9 + k], acc);
            a1s[c * 256 + sidx] = fmaxf(acc, 0.f);
        }
    }
    __syncthreads();

    // conv2 (4 waves, 8 co per thread); a2s overlays a1s post-barrier
    {
        const int p = tid & 63, oy = p >> 3, ox = p & 7;
        const int c0u = __builtin_amdgcn_readfirstlane(tid >> 6);
        const int cobase = c0u * 8;
        float acc[8];
        #pragma unroll
        for (int r = 0; r < 8; r++) acc[r] = b2[cobase + r];
        int offs[9]; bool val[9];
        #pragma unroll
        for (int ky = 0; ky < 3; ky++) {
            const int iy = 2 * oy - 1 + ky;
            #pragma unroll
            for (int kx = 0; kx < 3; kx++) {
                const int ix = 2 * ox - 1 + kx;
                const bool v = (iy >= 0) && (ix >= 0);
                const int col = (ix & 1) ? 8 + (ix >> 1) : (ix >> 1);
                offs[ky * 3 + kx] = v ? a1map(iy, col) : 0;
                val[ky * 3 + kx] = v;
            }
        }
        for (int ci = 0; ci < 32; ci++) {
            float patch[9];
            #pragma unroll
            for (int k = 0; k < 9; k++)
                patch[k] = val[k] ? a1s[ci * 256 + offs[k]] : 0.f;
            const float* wci = w2t + ci * 32 + cobase;
            #pragma unroll
            for (int k = 0; k < 9; k++) {
                #pragma unroll
                for (int r = 0; r < 8; r++)
                    acc[r] = fmaf(patch[k], wci[k * 1024 + r], acc[r]);
            }
        }
        __syncthreads();   // all a1s reads done -> a2s may overlay a1s
        #pragma unroll
        for (int r = 0; r < 8; r++)
            a2s[(cobase + r) * 64 + p] = fmaxf(acc[r], 0.f);
    }
    __syncthreads();

    // conv3 (4 waves, 4 co per thread): reads a2s [0,2048), writes a3s [2048,3072)
    {
        const int px = tid & 15, oy = px >> 2, ox = px & 3;
        const int cg = tid >> 4;
        float4 bv = ((const float4*)b3)[cg];
        float acc[4] = {bv.x, bv.y, bv.z, bv.w};
        for (int ci = 0; ci < 32; ci++) {
            float patch[9];
            #pragma unroll
            for (int ky = 0; ky < 3; ky++) {
                const int iy = 2 * oy - 1 + ky;
                #pragma unroll
                for (int kx = 0; kx < 3; kx++) {
                    const int ix = 2 * ox - 1 + kx;
                    bool v = (iy >= 0) && (ix >= 0);
                    patch[ky * 3 + kx] = v ? a2s[ci * 64 + iy * 8 + ix] : 0.f;
                }
            }
            #pragma unroll
            for (int k = 0; k < 9; k++) {
                float4 wv = *(const float4*)(w3t + k * 2048 + ci * 64 + cg * 4);
                acc[0] = fmaf(patch[k], wv.x, acc[0]);
                acc[1] = fmaf(patch[k], wv.y, acc[1]);
                acc[2] = fmaf(patch[k], wv.z, acc[2]);
                acc[3] = fmaf(patch[k], wv.w, acc[3]);
            }
        }
        #pragma unroll
        for (int r = 0; r < 4; r++)
            a3s[(cg * 4 + r) * 16 + px] = fmaxf(acc[r], 0.f);
    }
    __syncthreads();

    // conv4: reads a3s [2048,3072), writes reds2 [3584,4608), then a4s [3072,3328)
    {
        const int co = tid & 63;
        const int part = __builtin_amdgcn_readfirstlane(tid >> 6);
        float a0 = 0.f, a1 = 0.f, a2 = 0.f, a3 = 0.f;
        for (int ci = part * 16; ci < part * 16 + 16; ci++) {
            const float* wp = w4t + ci * 64 + co;
            const float w0 = wp[0];
            const float w1 = wp[4096];
            const float w2 = wp[8192];
            const float w3 = wp[12288];
            const float w4 = wp[16384];
            const float w5 = wp[20480];
            const float w6 = wp[24576];
            const float w7 = wp[28672];
            const float w8 = wp[32768];
            const float4 r0 = *(const float4*)(a3s + ci * 16);
            const float4 r1 = *(const float4*)(a3s + ci * 16 + 4);
            const float4 r2 = *(const float4*)(a3s + ci * 16 + 8);
            const float4 r3 = *(const float4*)(a3s + ci * 16 + 12);
            a0 = fmaf(r0.x, w4, a0); a0 = fmaf(r0.y, w5, a0);
            a0 = fmaf(r1.x, w7, a0); a0 = fmaf(r1.y, w8, a0);
            a1 = fmaf(r0.y, w3, a1); a1 = fmaf(r0.z, w4, a1); a1 = fmaf(r0.w, w5, a1);
            a1 = fmaf(r1.y, w6, a1); a1 = fmaf(r1.z, w7, a1); a1 = fmaf(r1.w, w8, a1);
            a2 = fmaf(r1.x, w1, a2); a2 = fmaf(r1.y, w2, a2);
            a2 = fmaf(r2.x, w4, a2); a2 = fmaf(r2.y, w5, a2);
            a2 = fmaf(r3.x, w7, a2); a2 = fmaf(r3.y, w8, a2);
            a3 = fmaf(r1.y, w0, a3); a3 = fmaf(r1.z, w1, a3); a3 = fmaf(r1.w, w2, a3);
            a3 = fmaf(r2.y, w3, a3); a3 = fmaf(r2.z, w4, a3); a3 = fmaf(r2.w, w5, a3);
            a3 = fmaf(r3.y, w6, a3); a3 = fmaf(r3.z, w7, a3); a3 = fmaf(r3.w, w8, a3);
        }
        reds2[part * 256 +   0 + co] = a0;
        reds2[part * 256 +  64 + co] = a1;
        reds2[part * 256 + 128 + co] = a2;
        reds2[part * 256 + 192 + co] = a3;
        __syncthreads();
        {
            const int co2 = tid & 63;
            const int cls2 = __builtin_amdgcn_readfirstlane(tid >> 6);
            float s = b4[co2]
                    + reds2[      cls2 * 64 + co2] + reds2[256 + cls2 * 64 + co2]
                    + reds2[512 + cls2 * 64 + co2] + reds2[768 + cls2 * 64 + co2];
            a4s[co2 * 4 + cls2] = fmaxf(s, 0.f);
        }
    }
    __syncthreads();

    // conv5: reads a4s [3072,3328), writes reds [3328,3584)
    {
        const int c = tid & 63, part = tid >> 6;
        float s = 0.f;
        for (int ci = part * 16; ci < part * 16 + 16; ci++) {
            const float4 av = *(const float4*)(a4s + ci * 4);
            s = fmaf(av.x, w5t[4 * 4096 + ci * 64 + c], s);
            s = fmaf(av.y, w5t[5 * 4096 + ci * 64 + c], s);
            s = fmaf(av.z, w5t[7 * 4096 + ci * 64 + c], s);
            s = fmaf(av.w, w5t[8 * 4096 + ci * 64 + c], s);
        }
        reds[part * 64 + c] = s;
    }
    __syncthreads();
    if (tid < 64) {
        float v = b5[tid] + reds[tid] + reds[64 + tid] + reds[128 + tid] + reds[192 + tid];
        hout[n * 64 + tid] = fmaxf(v, 0.f);
    }
}

// ============================================================================
// FC heads: staging vectorized (16 scalar global loads -> 4 float4 per k-step;
// same elements to same LDS slots, compute loop untouched -> values identical).
// ============================================================================
__global__ __launch_bounds__(256) void fc_enc(
    const float* __restrict__ h,
    const float* __restrict__ wmu, const float* __restrict__ bmu,
    const float* __restrict__ wD,  const float* __restrict__ bD,
    const float* __restrict__ wB,  const float* __restrict__ bB,
    float* __restrict__ mu, float* __restrict__ Pm)
{
    __shared__ float As[32][65];
    __shared__ float Bs[32][65];
    const int tid = threadIdx.x;
    const int m0 = blockIdx.y * 64;
    const int n0 = blockIdx.x * 64;

    const float* wbase; const float* bias; int nloc; int region;
    if (n0 < 256)       { wbase = wmu; bias = bmu; nloc = n0;        region = 0; }
    else if (n0 < 4352) { wbase = wD;  bias = bD;  nloc = n0 - 256;  region = 1; }
    else                { wbase = wB;  bias = bB;  nloc = n0 - 4352; region = 2; }

    const int tx = tid & 15, ty = tid >> 4;
    const int srow = tid >> 2, sq = (tid & 3) * 8;
    float acc[4][4] = {};
    for (int k0 = 0; k0 < 1024; k0 += 32) {
        {
            const float* ha = h + (m0 + srow) * 1024 + k0 + sq;
            const float* wa = wbase + (nloc + srow) * 1024 + k0 + sq;
            float4 a0 = *(const float4*)(ha);
            float4 a1 = *(const float4*)(ha + 4);
            float4 b0 = *(const float4*)(wa);
            float4 b1 = *(const float4*)(wa + 4);
            As[sq + 0][srow] = a0.x; As[sq + 1][srow] = a0.y;
            As[sq + 2][srow] = a0.z; As[sq + 3][srow] = a0.w;
            As[sq + 4][srow] = a1.x; As[sq + 5][srow] = a1.y;
            As[sq + 6][srow] = a1.z; As[sq + 7][srow] = a1.w;
            Bs[sq + 0][srow] = b0.x; Bs[sq + 1][srow] = b0.y;
            Bs[sq + 2][srow] = b0.z; Bs[sq + 3][srow] = b0.w;
            Bs[sq + 4][srow] = b1.x; Bs[sq + 5][srow] = b1.y;
            Bs[sq + 6][srow] = b1.z; Bs[sq + 7][srow] = b1.w;
        }
        __syncthreads();
        #pragma unroll
        for (int kk = 0; kk < 32; kk++) {
            float av[4], bv[4];
            #pragma unroll
            for (int i = 0; i < 4; i++) av[i] = As[kk][ty * 4 + i];
            #pragma unroll
            for (int j = 0; j < 4; j++) bv[j] = Bs[kk][tx * 4 + j];
            #pragma unroll
            for (int i = 0; i < 4; i++)
                #pragma unroll
                for (int j = 0; j < 4; j++) acc[i][j] = fmaf(av[i], bv[j], acc[i][j]);
        }
        __syncthreads();
    }
    #pragma unroll
    for (int i = 0; i < 4; i++) {
        int m = m0 + ty * 4 + i;
        size_t pbase = (size_t)m * 65536;
        #pragma unroll
        for (int j = 0; j < 4; j++) {
            int nc = nloc + tx * 4 + j;
            float v = acc[i][j] + bias[nc];
            if (region == 0) {
                mu[m * 256 + nc] = v;
            } else {
                int t = nc >> 8, pi = (nc >> 4) & 15, pj = nc & 15;
                if (region == 1) {
                    int row = t * 16 + pi, col = t * 16 + pj;
                    Pm[pbase + row * 256 + col] = v + (pi == pj ? ALPHA : 0.f);
                } else {
                    int row = (t + 1) * 16 + pi, col = t * 16 + pj;
                    Pm[pbase + row * 256 + col] = v;      // sub-diagonal
                    Pm[pbase + col * 256 + row] = v;      // super-diagonal (transposed)
                }
            }
        }
    }
}

// ============================================================================
// chol_inv_z: banded Cholesky + cov=inv(L) + z = mu + cov@eps in one kernel.
// z-phase added this round: block b's cov writes are L2-hot; a barrier (with
// vmcnt drain) gives within-block visibility, then zvec's exact fma order.
// ============================================================================
__global__ __launch_bounds__(256) void chol_inv_z(
    const float* __restrict__ Pm, float* __restrict__ cov,
    const float* __restrict__ mu, const float* __restrict__ eps,
    float* __restrict__ z)
{
    __shared__ __align__(16) float Lb[256 * 32 + 32];   // 8224 fl (+pad)
    __shared__ float Ds[4096];
    __shared__ float Bs2[3840];                          // total 64640 B
    const int b = blockIdx.x, tid = threadIdx.x;
    const float* Pb = Pm + (size_t)b * 65536;

    // stage (256-thread wide)
    for (int i = tid; i < 8224; i += 256) Lb[i] = 0.f;
    for (int i = tid; i < 4096; i += 256) {
        int t = i >> 8, r = (i >> 4) & 15, c = i & 15;
        Ds[i] = Pb[(t * 16 + r) * 256 + t * 16 + c];
    }
    for (int i = tid; i < 3840; i += 256) {
        int t = i >> 8, r = (i >> 4) & 15, c = i & 15;
        Bs2[i] = Pb[((t + 1) * 16 + r) * 256 + t * 16 + c];
    }
    __syncthreads();

    // ---- chol phase (wave 0 computes; others idle at barriers) ----
    const int d = tid;
    for (int j = 0; j < 256; j++) {
        const int i = j + d;
        float s = 0.f;
        if (d < 32 && i < 256) {
            int bi = i >> 4, bj = j >> 4, pi = i & 15, pj = j & 15;
            float a;
            if (bi == bj)           a = Ds[bi * 256 + pi * 16 + pj];
            else if (bi == bj + 1)  a = Bs2[bj * 256 + pi * 16 + pj];
            else                    a = 0.f;

            float c[32], p[32];
            const float* cp = Lb + j * 32;
            #pragma unroll
            for (int q = 0; q < 8; q++)
                *(float4*)(c + 4 * q) = *(const float4*)(cp + 4 * q);
            const float* pp = Lb + i * 32 + d;
            #pragma unroll
            for (int m = 1; m < 32; m++) p[m] = pp[m];

            float s0 = 0.f, s1 = 0.f, s2 = 0.f, s3 = 0.f;
            #pragma unroll
            for (int m = 1; m <= 28; m += 4) {
                s0 = fmaf(p[m],     c[m],     s0);
                s1 = fmaf(p[m + 1], c[m + 1], s1);
                s2 = fmaf(p[m + 2], c[m + 2], s2);
                s3 = fmaf(p[m + 3], c[m + 3], s3);
            }
            s0 = fmaf(p[29], c[29], s0);
            s1 = fmaf(p[30], c[30], s1);
            s2 = fmaf(p[31], c[31], s2);
            s = a - ((s0 + s1) + (s2 + s3));
        }
        float diag = __shfl(s, 0);
        float Ljj = sqrtf(diag);
        if (d == 0)                  Lb[j * 32] = Ljj;
        else if (d < 32 && i < 256)  Lb[i * 32 + d] = s / Ljj;
        __syncthreads();
    }

    // ---- inv phase (Lb in place; rs aliases dead Ds) ----
    float* rs = Ds;
    const int j = tid;
    rs[j] = 1.f / Lb[j * 32];
    __syncthreads();

    float* covb = cov + (size_t)b * 65536;
    const int w = __builtin_amdgcn_readfirstlane(j >> 6);
    const int istart = w * 64;                 // 32-aligned, <= any j in wave

    for (int i = 0; i < istart; i++) covb[i * 256 + j] = 0.f;

    float g[32];
    #pragma unroll
    for (int q = 0; q < 32; q++) g[q] = 0.f;

    for (int c = istart; c < 256; c += 32) {
        #pragma unroll
        for (int u = 0; u < 32; u++) {
            const int i = c + u;                       // wave-uniform
            const float* Lr = Lb + i * 32;             // broadcast LDS reads
            float lrow[32];
            #pragma unroll
            for (int q = 0; q < 8; q++)
                *(float4*)(lrow + 4 * q) = *(const float4*)(Lr + 4 * q);
            float s0 = 0.f, s1 = 0.f, s2 = 0.f, s3 = 0.f;
            #pragma unroll
            for (int dd = 1; dd < 32; dd += 4) {
                s0 = fmaf(lrow[dd],     g[(u - dd) & 31],     s0);
                if (dd + 1 < 32) s1 = fmaf(lrow[dd + 1], g[(u - dd - 1) & 31], s1);
                if (dd + 2 < 32) s2 = fmaf(lrow[dd + 2], g[(u - dd - 2) & 31], s2);
                if (dd + 3 < 32) s3 = fmaf(lrow[dd + 3], g[(u - dd - 3) & 31], s3);
            }
            float s = (s0 + s1) + (s2 + s3);
            float gi = (((i == j) ? 1.f : 0.f) - s) * rs[i];
            g[u & 31] = gi;
            covb[i * 256 + j] = gi;                    // coalesced
        }
    }

    // ---- z phase: cov writes drained by barrier -> within-block visible ----
    __syncthreads();
    float* es = Ds + 256;   // Ds[0..256)=rs no longer needed after this point,
                            // but keep es disjoint anyway
    es[tid] = eps[b * 256 + tid];
    __syncthreads();
    {
        const float4* row = (const float4*)(covb + (size_t)tid * 256);
        float s = 0.f;
        #pragma unroll 8
        for (int k = 0; k < 64; k++) {
            float4 v = row[k];
            s = fmaf(v.x, es[4 * k], s);
            s = fmaf(v.y, es[4 * k + 1], s);
            s = fmaf(v.z, es[4 * k + 2], s);
            s = fmaf(v.w, es[4 * k + 3], s);
        }
        z[b * 256 + tid] = mu[b * 256 + tid] + s;
    }
}

// ============================================================================
// fc_dec + mu_fix fused (unchanged)
// ============================================================================
__global__ __launch_bounds__(256) void fc_dec_mu(
    const float* __restrict__ z, const float* __restrict__ w,
    const float* __restrict__ bias, float* __restrict__ hd0,
    const float* __restrict__ h, const float* __restrict__ wmu,
    const float* __restrict__ bmu, float* __restrict__ mu)
{
    __shared__ float sh[1024];
    const int blk = blockIdx.x;
    if (blk < 1024) {
        // fc_dec
        const int b = blk >> 2;
        const int f = ((blk & 3) << 8) + threadIdx.x;
        sh[threadIdx.x] = z[b * 256 + threadIdx.x];
        __syncthreads();
        const float4* wr = (const float4*)(w + f * 256);
        float s = 0.f;
        #pragma unroll 8
        for (int k = 0; k < 64; k++) {
            float4 v = wr[k];
            s = fmaf(v.x, sh[4 * k], s);
            s = fmaf(v.y, sh[4 * k + 1], s);
            s = fmaf(v.z, sh[4 * k + 2], s);
            s = fmaf(v.w, sh[4 * k + 3], s);
        }
        hd0[b * 1024 + f] = s + bias[f];
    } else {
        // mu_fix
        const int b = blk - 1024, p = threadIdx.x;
        #pragma unroll
        for (int i = 0; i < 4; i++) sh[p + 256 * i] = h[b * 1024 + p + 256 * i];
        __syncthreads();
        const float4* wr = (const float4*)(wmu + p * 1024);
        float s = 0.f;
        #pragma unroll 8
        for (int k = 0; k < 256; k++) {
            float4 v = wr[k];
            s = fmaf(v.x, sh[4 * k], s);
            s = fmaf(v.y, sh[4 * k + 1], s);
            s = fmaf(v.z, sh[4 * k + 2], s);
            s = fmaf(v.w, sh[4 * k + 3], s);
        }
        mu[b * 256 + p] = s + bmu[p];
    }
}

// ============================================================================
// Decoder: EXACT round-6 form (234 µs measured, confirmed round 9).
// ============================================================================
__device__ __forceinline__ float eluf(float v) { return v > 0.f ? v : expf(v) - 1.f; }

template<int PY, int PX, int HIN, int WIN, class F>
__device__ __forceinline__ void for_taps(int ey, int ex, F&& f) {
    if (PY == 0) {
        if (PX == 0) { f(4, ey, ex, true); }
        else         { f(5, ey, ex, true); f(3, ey, ex + 1, ex + 1 < WIN); }
    } else {
        if (PX == 0) { f(7, ey, ex, true); f(1, ey + 1, ex, ey + 1 < HIN); }
        else {
            f(8, ey, ex, true);
            f(6, ey, ex + 1, ex + 1 < WIN);
            f(2, ey + 1, ex, ey + 1 < HIN);
            f(0, ey + 1, ex + 1, (ey + 1 < HIN) && (ex + 1 < WIN));
        }
    }
}

template<int OY>
__device__ __forceinline__ void t4_row(
    const float* __restrict__ wt4t, const float* __restrict__ bt4,
    const float* __restrict__ d1, float* __restrict__ d2, int co)
{
    float a0 = 0.f, a1 = 0.f, a2 = 0.f, a3 = 0.f;
    const float* wb = wt4t + co;
    for (int ci = 0; ci < 64; ci++) {
        const float* base = d1 + ci * 12;
        if (OY % 2 == 0) {
            float4 r = *(const float4*)(base + (OY / 2) * 4);
            float w10 = wb[3 * 4096 + ci * 64];
            float w11 = wb[4 * 4096 + ci * 64];
            float w12 = wb[5 * 4096 + ci * 64];
            a0 = fmaf(r.x, w11, a0);
            a1 = fmaf(r.x, w12, a1); a1 = fmaf(r.y, w10, a1);
            a2 = fmaf(r.y, w11, a2);
            a3 = fmaf(r.y, w12, a3); a3 = fmaf(r.z, w10, a3);
        } else {
            float4 ra = *(const float4*)(base + ((OY - 1) / 2) * 4);
            float4 rb = *(const float4*)(base + ((OY + 1) / 2) * 4);
            float w20 = wb[6 * 4096 + ci * 64], w21 = wb[7 * 4096 + ci * 64], w22 = wb[8 * 4096 + ci * 64];
            float w00 = wb[0 * 4096 + ci * 64], w01 = wb[1 * 4096 + ci * 64], w02 = wb[2 * 4096 + ci * 64];
            a0 = fmaf(ra.x, w21, a0); a0 = fmaf(rb.x, w01, a0);
            a1 = fmaf(ra.x, w22, a1); a1 = fmaf(ra.y, w20, a1);
            a1 = fmaf(rb.x, w02, a1); a1 = fmaf(rb.y, w00, a1);
            a2 = fmaf(ra.y, w21, a2); a2 = fmaf(rb.y, w01, a2);
            a3 = fmaf(ra.y, w22, a3); a3 = fmaf(ra.z, w20, a3);
            a3 = fmaf(rb.y, w02, a3); a3 = fmaf(rb.z, w00, a3);
        }
    }
    float b = bt4[co];
    float4 o = make_float4(eluf(a0 + b), eluf(a1 + b), eluf(a2 + b), eluf(a3 + b));
    *(float4*)(d2 + co * 44 + OY * 8) = o;
}

template<int M>
__device__ __forceinline__ void xrow(float* acc, const float* R, float w0, float w1, float w2)
{
    #pragma unroll
    for (int m = 0; m < M; m++) {
        acc[2 * m]     = fmaf(R[m], w1, acc[2 * m]);
        acc[2 * m + 1] = fmaf(R[m], w2, acc[2 * m + 1]);
        acc[2 * m + 1] = fmaf(R[m + 1], w0, acc[2 * m + 1]);
    }
}

__global__ __launch_bounds__(256, 4) void dec_fused(
    const float* __restrict__ hd0,
    const float* __restrict__ wt5t, const float* __restrict__ bt5,
    const float* __restrict__ wt4t, const float* __restrict__ bt4,
    const float* __restrict__ wt3t, const float* __restrict__ bt3,
    const float* __restrict__ wt2t, const float* __restrict__ bt2,
    const float* __restrict__ wt1,  const float* __restrict__ bt1,
    float* __restrict__ xr)
{
    __shared__ __align__(16) float smem[9664];   // 38656 B -> 4 blocks/CU
    float* d0  = smem;            // 64
    float* d1  = smem + 64;       // [64][3][4] pitch 12
    float* d2  = smem + 832;      // [64][44], rows pitch 8 (5 rows)
    float* scr = smem + 3648;     // [128][20]
    float* d3  = smem + 6208;     // [32][108], rows pitch 12 (9 rows)
    float* d4  = smem;            // [32][260] overlays A+scr+d3 after T2 barrier

    const int n = blockIdx.x, tid = threadIdx.x;

    for (int i = tid; i < 3584; i += 256) smem[64 + i] = 0.f;
    for (int i = tid; i < 3456; i += 256) d3[i] = 0.f;
    if (tid < 64) d0[tid] = hd0[n * 64 + tid];
    __syncthreads();

    // T5
    {
        const int co = tid & 63;
        const int wv = __builtin_amdgcn_readfirstlane(tid >> 6);
        const int oy = wv >> 1, ox = wv & 1;
        const int wk = (oy + 1) * 3 + (ox + 1);
        const float* wp = wt5t + wk * 4096 + co;
        float s = bt5[co];
        for (int ci = 0; ci < 64; ci++)
            s = fmaf(d0[ci], wp[ci * 64], s);
        d1[co * 12 + oy * 4 + ox] = eluf(s);
    }
    __syncthreads();

    // T4
    {
        const int co = tid & 63;
        const int oyw = __builtin_amdgcn_readfirstlane(tid >> 6);
        if (oyw == 0)      t4_row<0>(wt4t, bt4, d1, d2, co);
        else if (oyw == 1) t4_row<1>(wt4t, bt4, d1, d2, co);
        else if (oyw == 2) t4_row<2>(wt4t, bt4, d1, d2, co);
        else               t4_row<3>(wt4t, bt4, d1, d2, co);
    }
    __syncthreads();

    // T3
    {
        const int co = tid & 31, pr = (tid >> 5) & 3, cih = tid >> 7;
        const int e = (pr & 1) ? 7 - pr : pr;
        const int o = (pr & 1) ? pr : 7 - pr;
        const int iy_e = e >> 1, iy_o2 = (o - 1) >> 1, iy_o0 = (o + 1) >> 1;
        float acce[8] = {}, acco[8] = {};
        const float* wb = wt3t + co;
        for (int c = 0; c < 32; c++) {
            const int ci = cih * 32 + c;
            const float* base = d2 + ci * 44;
            float re[8], ro2[8], ro0[8];
            *(float4*)(re)      = *(const float4*)(base + iy_e * 8);
            *(float4*)(re + 4)  = *(const float4*)(base + iy_e * 8 + 4);
            *(float4*)(ro2)     = *(const float4*)(base + iy_o2 * 8);
            *(float4*)(ro2 + 4) = *(const float4*)(base + iy_o2 * 8 + 4);
            *(float4*)(ro0)     = *(const float4*)(base + iy_o0 * 8);
            *(float4*)(ro0 + 4) = *(const float4*)(base + iy_o0 * 8 + 4);
            float w10 = wb[3 * 2048 + ci * 32], w11 = wb[4 * 2048 + ci * 32], w12 = wb[5 * 2048 + ci * 32];
            float w20 = wb[6 * 2048 + ci * 32], w21 = wb[7 * 2048 + ci * 32], w22 = wb[8 * 2048 + ci * 32];
            float w00 = wb[0 * 2048 + ci * 32], w01 = wb[1 * 2048 + ci * 32], w02 = wb[2 * 2048 + ci * 32];
            xrow<4>(acce, re, w10, w11, w12);
            xrow<4>(acco, ro2, w20, w21, w22);
            xrow<4>(acco, ro0, w00, w01, w02);
        }
        if (cih == 1) {
            float* s = scr + (tid - 128) * 20;
            #pragma unroll
            for (int k = 0; k < 8; k++) { s[k] = acce[k]; s[8 + k] = acco[k]; }
        }
        __syncthreads();
        if (cih == 0) {
            const float* s = scr + tid * 20;
            const float b = bt3[co];
            float* oe = d3 + co * 108 + e * 12;
            float* oo = d3 + co * 108 + o * 12;
            #pragma unroll
            for (int k = 0; k < 8; k++) {
                oe[k] = eluf(acce[k] + s[k] + b);
                oo[k] = eluf(acco[k] + s[8 + k] + b);
            }
        }
    }
    __syncthreads();

    // T2 — register-staged output: accumulate (reads d3), barrier, store d4.
    {
        const int co = tid & 31, org = tid >> 5;
        float acc0[16] = {}, acc1[16] = {};
        const float* wb = wt2t + co;
        for (int ci = 0; ci < 32; ci++) {
            const float* base = d3 + ci * 108 + org * 12;
            float A[12], B[12];
            #pragma unroll
            for (int q = 0; q < 3; q++) {
                *(float4*)(A + 4 * q) = *(const float4*)(base + 4 * q);
                *(float4*)(B + 4 * q) = *(const float4*)(base + 12 + 4 * q);
            }
            float w10 = wb[3 * 1024 + ci * 32], w11 = wb[4 * 1024 + ci * 32], w12 = wb[5 * 1024 + ci * 32];
            float w20 = wb[6 * 1024 + ci * 32], w21 = wb[7 * 1024 + ci * 32], w22 = wb[8 * 1024 + ci * 32];
            float w00 = wb[0 * 1024 + ci * 32], w01 = wb[1 * 1024 + ci * 32], w02 = wb[2 * 1024 + ci * 32];
            xrow<8>(acc0, A, w10, w11, w12);
            xrow<8>(acc1, A, w20, w21, w22);
            xrow<8>(acc1, B, w00, w01, w02);
        }
        __syncthreads();   // all d3 reads drained -> d4 may overlay d3
        const float b = bt2[co];
        float* o0 = d4 + co * 260 + (2 * org) * 16;
        float* o1 = o0 + 16;
        #pragma unroll
        for (int q = 0; q < 4; q++) {
            float4 v0 = make_float4(eluf(acc0[4 * q] + b), eluf(acc0[4 * q + 1] + b),
                                    eluf(acc0[4 * q + 2] + b), eluf(acc0[4 * q + 3] + b));
            float4 v1 = make_float4(eluf(acc1[4 * q] + b), eluf(acc1[4 * q + 1] + b),
                                    eluf(acc1[4 * q + 2] + b), eluf(acc1[4 * q + 3] + b));
            *(float4*)(o0 + 4 * q) = v0;
            *(float4*)(o1 + 4 * q) = v1;
        }
    }
    __syncthreads();

    // T1 (exact round-6 form)
    {
        const int ey = tid >> 4, ex = tid & 15;
        const float bb = bt1[0];
        float* xi = xr + n * 1024;
        float acc[4] = {};
        for (int ci = 0; ci < 32; ci++) {
            const float* a = d4 + ci * 260;
            const float* w = wt1 + ci * 9;
            for_taps<0, 0, 16, 16>(ey, ex, [&](int wk, int iy, int ix, bool v) {
                acc[0] = fmaf(v ? a[iy * 16 + ix] : 0.f, w[wk], acc[0]); });
            for_taps<0, 1, 16, 16>(ey, ex, [&](int wk, int iy, int ix, bool v) {
                acc[1] = fmaf(v ? a[iy * 16 + ix] : 0.f, w[wk], acc[1]); });
            for_taps<1, 0, 16, 16>(ey, ex, [&](int wk, int iy, int ix, bool v) {
                acc[2] = fmaf(v ? a[iy * 16 + ix] : 0.f, w[wk], acc[2]); });
            for_taps<1, 1, 16, 16>(ey, ex, [&](int wk, int iy, int ix, bool v) {
                acc[3] = fmaf(v ? a[iy * 16 + ix] : 0.f, w[wk], acc[3]); });
        }
        xi[(2 * ey) * 32 + 2 * ex]         = 1.f / (1.f + expf(-(acc[0] + bb)));
        xi[(2 * ey) * 32 + 2 * ex + 1]     = 1.f / (1.f + expf(-(acc[1] + bb)));
        xi[(2 * ey + 1) * 32 + 2 * ex]     = 1.f / (1.f + expf(-(acc[2] + bb)));
        xi[(2 * ey + 1) * 32 + 2 * ex + 1] = 1.f / (1.f + expf(-(acc[3] + bb)));
    }
}

// ============================================================================
extern "C" void kernel_launch(void* const* d_in, const int* in_sizes, int n_in,
                              void* d_out, int out_size, void* d_ws, size_t ws_size,
                              hipStream_t stream)
{
    (void)in_sizes; (void)n_in; (void)out_size; (void)ws_size;
    const float* x    = (const float*)d_in[0];
    const float* eps  = (const float*)d_in[1];
    const float* w1 = (const float*)d_in[2];  const float* b1 = (const float*)d_in[3];
    const float* w2 = (const float*)d_in[4];  const float* b2 = (const float*)d_in[5];
    const float* w3 = (const float*)d_in[6];  const float* b3 = (const float*)d_in[7];
    const float* w4 = (const float*)d_in[8];  const float* b4 = (const float*)d_in[9];
    const float* w5 = (const float*)d_in[10]; const float* b5 = (const float*)d_in[11];
    const float* fc_mu_w = (const float*)d_in[12]; const float* fc_mu_b = (const float*)d_in[13];
    const float* fc_D_w  = (const float*)d_in[14]; const float* fc_D_b  = (const float*)d_in[15];
    const float* fc_B_w  = (const float*)d_in[16]; const float* fc_B_b  = (const float*)d_in[17];
    const float* fc_dec_w = (const float*)d_in[18]; const float* fc_dec_b = (const float*)d_in[19];
    const float* wt5 = (const float*)d_in[20]; const float* bt5 = (const float*)d_in[21];
    const float* wt4 = (const float*)d_in[22]; const float* bt4 = (const float*)d_in[23];
    const float* wt3 = (const float*)d_in[24]; const float* bt3 = (const float*)d_in[25];
    const float* wt2 = (const float*)d_in[26]; const float* bt2 = (const float*)d_in[27];
    const float* wt1 = (const float*)d_in[28]; const float* bt1 = (const float*)d_in[29];

    // workspace layout (floats)
    float* ws   = (float*)d_ws;
    float* h    = ws;                  // 262144  [4096][64]
    float* z    = ws + 2359296;        // 65536
    float* hd0  = ws + 2424832;        // 262144  [4096][64]
    float* wt5t = ws + 2686976;        // 36864   [9][64][64]
    float* wt4t = ws + 2723840;        // 36864   [9][64][64]
    float* wt3t = ws + 2760704;        // 18432   [9][64][32]
    float* wt2t = ws + 2779136;        // 9216    [9][32][32]
    float* w2t  = ws + 2788352;        // 9216    [9][32][32]
    float* w3t  = ws + 2797568;        // 18432   [9][32][64]
    float* w4t  = ws + 2816000;        // 36864   [9][64][64]
    float* w5t  = ws + 2852864;        // 36864   [9][64][64]

    // output layout: xr | mu | cov | Pm
    float* out = (float*)d_out;
    float* xr  = out;                 // 4194304
    float* mu  = out + 4194304;       // 65536
    float* cov = out + 4259840;       // 16777216
    float* Pm  = out + 21037056;      // 16777216

    prep_all<<<17176, 256, 0, stream>>>(wt5, wt4, wt3, wt2, w2, w3, w4, w5,
                                        wt5t, wt4t, wt3t, wt2t, w2t, w3t, w4t, w5t,
                                        (float4*)Pm);
    enc_fused<<<4096, 256, 0, stream>>>(x, w1, b1, w2t, b2, w3t, b3, w4t, b4, w5t, b5, h);
    fc_enc<<<dim3(128, 4), 256, 0, stream>>>(h, fc_mu_w, fc_mu_b, fc_D_w, fc_D_b,
                                             fc_B_w, fc_B_b, mu, Pm);
    chol_inv_z<<<256, 256, 0, stream>>>(Pm, cov, mu, eps, z);
    fc_dec_mu<<<1280, 256, 0, stream>>>(z, fc_dec_w, fc_dec_b, hd0,
                                        h, fc_mu_w, fc_mu_b, mu);
    dec_fused<<<4096, 256, 0, stream>>>(hd0, wt5t, bt5, wt4t, bt4, wt3t, bt3,
                                        wt2t, bt2, wt1, bt1, xr);
}

// Round 11
// 933.430 us; speedup vs baseline: 1.0634x; 1.0225x over previous
//
#include <hip/hip_runtime.h>
#include <cmath>

#define ALPHA 0.5f

// ============================================================================
// prep_all: pm_zero (16384 blocks) + weight transpose (792 blocks) fused.
// ============================================================================
__global__ __launch_bounds__(256) void prep_all(
    const float* __restrict__ dw5, const float* __restrict__ dw4,
    const float* __restrict__ dw3, const float* __restrict__ dw2,
    const float* __restrict__ ew2, const float* __restrict__ ew3,
    const float* __restrict__ ew4, const float* __restrict__ ew5,
    float* __restrict__ t5, float* __restrict__ t4,
    float* __restrict__ t3, float* __restrict__ t2,
    float* __restrict__ e2, float* __restrict__ e3,
    float* __restrict__ e4, float* __restrict__ e5,
    float4* __restrict__ Pm4)
{
    const int bid = blockIdx.x;
    if (bid < 16384) {
        Pm4[bid * 256 + threadIdx.x] = make_float4(0.f, 0.f, 0.f, 0.f);
        return;
    }
    int idx = (bid - 16384) * 256 + threadIdx.x;   // total 202752
    if (idx >= 202752) return;
    const float* w; float* t; int CIN, COUT, loc; bool enc = false;
    if (idx < 36864)       { w = dw5; t = t5; CIN = 64; COUT = 64; loc = idx; }
    else if (idx < 73728)  { w = dw4; t = t4; CIN = 64; COUT = 64; loc = idx - 36864; }
    else if (idx < 92160)  { w = dw3; t = t3; CIN = 64; COUT = 32; loc = idx - 73728; }
    else if (idx < 101376) { w = dw2; t = t2; CIN = 32; COUT = 32; loc = idx - 92160; }
    else if (idx < 110592) { w = ew2; t = e2; CIN = 32; COUT = 32; loc = idx - 101376; enc = true; }
    else if (idx < 129024) { w = ew3; t = e3; CIN = 32; COUT = 64; loc = idx - 110592; enc = true; }
    else if (idx < 165888) { w = ew4; t = e4; CIN = 64; COUT = 64; loc = idx - 129024; enc = true; }
    else                   { w = ew5; t = e5; CIN = 64; COUT = 64; loc = idx - 165888; enc = true; }
    int wk = loc % 9; int r = loc / 9; int ci, co;
    if (enc) { ci = r % CIN;  co = r / CIN;  }   // src [co][ci][k]
    else     { co = r % COUT; ci = r / COUT; }   // src [ci][co][k]
    t[wk * CIN * COUT + ci * COUT + co] = w[loc];
}

// ============================================================================
// Encoder: ROUND-9 form restored (40960 B, 4 blocks/CU). Round-10's 32768 B
// variant could not fit 5 blocks (5x32768 = exactly 160 KiB; HW won't allocate
// the full capacity) and its extra conv1 barrier cost ~5 µs. Lesson: only
// claim occupancy wins when blocks x LDS < capacity with slack.
// ============================================================================
__device__ __forceinline__ int a1map(int iy, int col) {
    return (col & 7)
         | ((iy & 2) << 2)                   // iy[1]        -> bit3
         | (((iy ^ (iy >> 2)) & 1) << 4)     // iy[0]^iy[2]  -> bit4
         | ((col & 8) << 2)                  // col[3]       -> bit5
         | ((iy & 4) << 4)                   // iy[2]        -> bit6
         | ((iy & 8) << 4);                  // iy[3]        -> bit7
}

__global__ __launch_bounds__(256, 4) void enc_fused(
    const float* __restrict__ x,
    const float* __restrict__ w1,  const float* __restrict__ b1,
    const float* __restrict__ w2t, const float* __restrict__ b2,
    const float* __restrict__ w3t, const float* __restrict__ b3,
    const float* __restrict__ w4t, const float* __restrict__ b4,
    const float* __restrict__ w5t, const float* __restrict__ b5,
    float* __restrict__ hout)
{
    __shared__ __align__(16) float smem[10240];   // 40960 B -> 4 blocks/CU
    float* a1s  = smem;          // [32][256] permuted conv1 output (8192 fl)
    float* bse  = smem + 8192;   // region B (2048 fl): aliased by phase
    float* imgs = bse;           // phase0: [32][40] = 1280
    float* a2s  = bse;           // phase1+: [32][64] = 2048
    float* a3s  = smem;          // post-conv2 overlay of a1s: [64][16] = 1024
    float* a4s  = smem + 1024;   // [64][4] = 256
    float* reds = smem + 1280;   // [4][64] = 256

    const int n = blockIdx.x;
    const int tid = threadIdx.x;

    const float* xi = x + n * 1024;
    #pragma unroll
    for (int i = 0; i < 4; i++) {
        int idx = tid + 256 * i;
        int iy = idx >> 5, ix = idx & 31;
        int col = (ix & 1) ? 20 + (ix >> 1) : (ix >> 1);
        imgs[iy * 40 + col] = xi[idx];
    }
    __syncthreads();

    // conv1
    {
        const int oy = tid >> 4, ox = tid & 15;
        float patch[9];
        #pragma unroll
        for (int ky = 0; ky < 3; ky++) {
            const int iy = 2 * oy - 1 + ky;
            #pragma unroll
            for (int kx = 0; kx < 3; kx++) {
                const int ix = 2 * ox - 1 + kx;
                bool v = (iy >= 0) && (ix >= 0);
                int col = (ix & 1) ? 20 + (ix >> 1) : (ix >> 1);
                patch[ky * 3 + kx] = v ? imgs[iy * 40 + col] : 0.f;
            }
        }
        const int ocol = (ox & 1) ? 8 + (ox >> 1) : (ox >> 1);
        const int sidx = a1map(oy, ocol);
        for (int c = 0; c < 32; c++) {
            float acc = b1[c];
            #pragma unroll
            for (int k = 0; k < 9; k++) acc = fmaf(patch[k], w1[c * 9 + k], acc);
            a1s[c * 256 + sidx] = fmaxf(acc, 0.f);
        }
    }
    __syncthreads();

    // conv2 (4 waves, 8 co per thread)
    {
        const int p = tid & 63, oy = p >> 3, ox = p & 7;
        const int c0u = __builtin_amdgcn_readfirstlane(tid >> 6);
        const int cobase = c0u * 8;
        float acc[8];
        #pragma unroll
        for (int r = 0; r < 8; r++) acc[r] = b2[cobase + r];
        int offs[9]; bool val[9];
        #pragma unroll
        for (int ky = 0; ky < 3; ky++) {
            const int iy = 2 * oy - 1 + ky;
            #pragma unroll
            for (int kx = 0; kx < 3; kx++) {
                const int ix = 2 * ox - 1 + kx;
                const bool v = (iy >= 0) && (ix >= 0);
                const int col = (ix & 1) ? 8 + (ix >> 1) : (ix >> 1);
                offs[ky * 3 + kx] = v ? a1map(iy, col) : 0;
                val[ky * 3 + kx] = v;
            }
        }
        for (int ci = 0; ci < 32; ci++) {
            float patch[9];
            #pragma unroll
            for (int k = 0; k < 9; k++)
                patch[k] = val[k] ? a1s[ci * 256 + offs[k]] : 0.f;
            const float* wci = w2t + ci * 32 + cobase;
            #pragma unroll
            for (int k = 0; k < 9; k++) {
                #pragma unroll
                for (int r = 0; r < 8; r++)
                    acc[r] = fmaf(patch[k], wci[k * 1024 + r], acc[r]);
            }
        }
        __syncthreads();
        #pragma unroll
        for (int r = 0; r < 8; r++)
            a2s[(cobase + r) * 64 + p] = fmaxf(acc[r], 0.f);
    }
    __syncthreads();

    // conv3 (4 waves, 4 co per thread)
    {
        const int px = tid & 15, oy = px >> 2, ox = px & 3;
        const int cg = tid >> 4;
        float4 bv = ((const float4*)b3)[cg];
        float acc[4] = {bv.x, bv.y, bv.z, bv.w};
        for (int ci = 0; ci < 32; ci++) {
            float patch[9];
            #pragma unroll
            for (int ky = 0; ky < 3; ky++) {
                const int iy = 2 * oy - 1 + ky;
                #pragma unroll
                for (int kx = 0; kx < 3; kx++) {
                    const int ix = 2 * ox - 1 + kx;
                    bool v = (iy >= 0) && (ix >= 0);
                    patch[ky * 3 + kx] = v ? a2s[ci * 64 + iy * 8 + ix] : 0.f;
                }
            }
            #pragma unroll
            for (int k = 0; k < 9; k++) {
                float4 wv = *(const float4*)(w3t + k * 2048 + ci * 64 + cg * 4);
                acc[0] = fmaf(patch[k], wv.x, acc[0]);
                acc[1] = fmaf(patch[k], wv.y, acc[1]);
                acc[2] = fmaf(patch[k], wv.z, acc[2]);
                acc[3] = fmaf(patch[k], wv.w, acc[3]);
            }
        }
        #pragma unroll
        for (int r = 0; r < 4; r++)
            a3s[(cg * 4 + r) * 16 + px] = fmaxf(acc[r], 0.f);
    }
    __syncthreads();

    // conv4 (round-5 restructured form)
    {
        const int co = tid & 63;
        const int part = __builtin_amdgcn_readfirstlane(tid >> 6);
        float a0 = 0.f, a1 = 0.f, a2 = 0.f, a3 = 0.f;
        for (int ci = part * 16; ci < part * 16 + 16; ci++) {
            const float* wp = w4t + ci * 64 + co;
            const float w0 = wp[0];
            const float w1 = wp[4096];
            const float w2 = wp[8192];
            const float w3 = wp[12288];
            const float w4 = wp[16384];
            const float w5 = wp[20480];
            const float w6 = wp[24576];
            const float w7 = wp[28672];
            const float w8 = wp[32768];
            const float4 r0 = *(const float4*)(a3s + ci * 16);
            const float4 r1 = *(const float4*)(a3s + ci * 16 + 4);
            const float4 r2 = *(const float4*)(a3s + ci * 16 + 8);
            const float4 r3 = *(const float4*)(a3s + ci * 16 + 12);
            a0 = fmaf(r0.x, w4, a0); a0 = fmaf(r0.y, w5, a0);
            a0 = fmaf(r1.x, w7, a0); a0 = fmaf(r1.y, w8, a0);
            a1 = fmaf(r0.y, w3, a1); a1 = fmaf(r0.z, w4, a1); a1 = fmaf(r0.w, w5, a1);
            a1 = fmaf(r1.y, w6, a1); a1 = fmaf(r1.z, w7, a1); a1 = fmaf(r1.w, w8, a1);
            a2 = fmaf(r1.x, w1, a2); a2 = fmaf(r1.y, w2, a2);
            a2 = fmaf(r2.x, w4, a2); a2 = fmaf(r2.y, w5, a2);
            a2 = fmaf(r3.x, w7, a2); a2 = fmaf(r3.y, w8, a2);
            a3 = fmaf(r1.y, w0, a3); a3 = fmaf(r1.z, w1, a3); a3 = fmaf(r1.w, w2, a3);
            a3 = fmaf(r2.y, w3, a3); a3 = fmaf(r2.z, w4, a3); a3 = fmaf(r2.w, w5, a3);
            a3 = fmaf(r3.y, w6, a3); a3 = fmaf(r3.z, w7, a3); a3 = fmaf(r3.w, w8, a3);
        }
        float* reds2 = bse;   // a2s dead after conv3
        reds2[part * 256 +   0 + co] = a0;
        reds2[part * 256 +  64 + co] = a1;
        reds2[part * 256 + 128 + co] = a2;
        reds2[part * 256 + 192 + co] = a3;
        __syncthreads();
        {
            const int co2 = tid & 63;
            const int cls2 = __builtin_amdgcn_readfirstlane(tid >> 6);
            float s = b4[co2]
                    + reds2[      cls2 * 64 + co2] + reds2[256 + cls2 * 64 + co2]
                    + reds2[512 + cls2 * 64 + co2] + reds2[768 + cls2 * 64 + co2];
            a4s[co2 * 4 + cls2] = fmaxf(s, 0.f);
        }
    }
    __syncthreads();

    // conv5
    {
        const int c = tid & 63, part = tid >> 6;
        float s = 0.f;
        for (int ci = part * 16; ci < part * 16 + 16; ci++) {
            const float4 av = *(const float4*)(a4s + ci * 4);
            s = fmaf(av.x, w5t[4 * 4096 + ci * 64 + c], s);
            s = fmaf(av.y, w5t[5 * 4096 + ci * 64 + c], s);
            s = fmaf(av.z, w5t[7 * 4096 + ci * 64 + c], s);
            s = fmaf(av.w, w5t[8 * 4096 + ci * 64 + c], s);
        }
        reds[part * 64 + c] = s;
    }
    __syncthreads();
    if (tid < 64) {
        float v = b5[tid] + reds[tid] + reds[64 + tid] + reds[128 + tid] + reds[192 + tid];
        hout[n * 64 + tid] = fmaxf(v, 0.f);
    }
}

// ============================================================================
// FC heads (round-10 vectorized staging — kept).
// ============================================================================
__global__ __launch_bounds__(256) void fc_enc(
    const float* __restrict__ h,
    const float* __restrict__ wmu, const float* __restrict__ bmu,
    const float* __restrict__ wD,  const float* __restrict__ bD,
    const float* __restrict__ wB,  const float* __restrict__ bB,
    float* __restrict__ mu, float* __restrict__ Pm)
{
    __shared__ float As[32][65];
    __shared__ float Bs[32][65];
    const int tid = threadIdx.x;
    const int m0 = blockIdx.y * 64;
    const int n0 = blockIdx.x * 64;

    const float* wbase; const float* bias; int nloc; int region;
    if (n0 < 256)       { wbase = wmu; bias = bmu; nloc = n0;        region = 0; }
    else if (n0 < 4352) { wbase = wD;  bias = bD;  nloc = n0 - 256;  region = 1; }
    else                { wbase = wB;  bias = bB;  nloc = n0 - 4352; region = 2; }

    const int tx = tid & 15, ty = tid >> 4;
    const int srow = tid >> 2, sq = (tid & 3) * 8;
    float acc[4][4] = {};
    for (int k0 = 0; k0 < 1024; k0 += 32) {
        {
            const float* ha = h + (m0 + srow) * 1024 + k0 + sq;
            const float* wa = wbase + (nloc + srow) * 1024 + k0 + sq;
            float4 a0 = *(const float4*)(ha);
            float4 a1 = *(const float4*)(ha + 4);
            float4 b0 = *(const float4*)(wa);
            float4 b1 = *(const float4*)(wa + 4);
            As[sq + 0][srow] = a0.x; As[sq + 1][srow] = a0.y;
            As[sq + 2][srow] = a0.z; As[sq + 3][srow] = a0.w;
            As[sq + 4][srow] = a1.x; As[sq + 5][srow] = a1.y;
            As[sq + 6][srow] = a1.z; As[sq + 7][srow] = a1.w;
            Bs[sq + 0][srow] = b0.x; Bs[sq + 1][srow] = b0.y;
            Bs[sq + 2][srow] = b0.z; Bs[sq + 3][srow] = b0.w;
            Bs[sq + 4][srow] = b1.x; Bs[sq + 5][srow] = b1.y;
            Bs[sq + 6][srow] = b1.z; Bs[sq + 7][srow] = b1.w;
        }
        __syncthreads();
        #pragma unroll
        for (int kk = 0; kk < 32; kk++) {
            float av[4], bv[4];
            #pragma unroll
            for (int i = 0; i < 4; i++) av[i] = As[kk][ty * 4 + i];
            #pragma unroll
            for (int j = 0; j < 4; j++) bv[j] = Bs[kk][tx * 4 + j];
            #pragma unroll
            for (int i = 0; i < 4; i++)
                #pragma unroll
                for (int j = 0; j < 4; j++) acc[i][j] = fmaf(av[i], bv[j], acc[i][j]);
        }
        __syncthreads();
    }
    #pragma unroll
    for (int i = 0; i < 4; i++) {
        int m = m0 + ty * 4 + i;
        size_t pbase = (size_t)m * 65536;
        #pragma unroll
        for (int j = 0; j < 4; j++) {
            int nc = nloc + tx * 4 + j;
            float v = acc[i][j] + bias[nc];
            if (region == 0) {
                mu[m * 256 + nc] = v;
            } else {
                int t = nc >> 8, pi = (nc >> 4) & 15, pj = nc & 15;
                if (region == 1) {
                    int row = t * 16 + pi, col = t * 16 + pj;
                    Pm[pbase + row * 256 + col] = v + (pi == pj ? ALPHA : 0.f);
                } else {
                    int row = (t + 1) * 16 + pi, col = t * 16 + pj;
                    Pm[pbase + row * 256 + col] = v;      // sub-diagonal
                    Pm[pbase + col * 256 + row] = v;      // super-diagonal (transposed)
                }
            }
        }
    }
}

// ============================================================================
// chol_inv_z v2: chol phase now BARRIER-FREE — only wave 0 ever computes, and
// within one wave LDS write->read ordering is guaranteed by program order
// (compiler-inserted lgkmcnt waits; __shfl is wave-local). The other 3 waves
// skip straight to one barrier instead of marching through 256 barriers on
// the serial critical path (1 block/CU -> nothing else hides them).
// Arithmetic identical -> absmax unchanged.
// ============================================================================
__global__ __launch_bounds__(256) void chol_inv_z(
    const float* __restrict__ Pm, float* __restrict__ cov,
    const float* __restrict__ mu, const float* __restrict__ eps,
    float* __restrict__ z)
{
    __shared__ __align__(16) float Lb[256 * 32 + 32];   // 8224 fl (+pad)
    __shared__ float Ds[4096];
    __shared__ float Bs2[3840];                          // total 64640 B
    const int b = blockIdx.x, tid = threadIdx.x;
    const float* Pb = Pm + (size_t)b * 65536;

    // stage (256-thread wide)
    for (int i = tid; i < 8224; i += 256) Lb[i] = 0.f;
    for (int i = tid; i < 4096; i += 256) {
        int t = i >> 8, r = (i >> 4) & 15, c = i & 15;
        Ds[i] = Pb[(t * 16 + r) * 256 + t * 16 + c];
    }
    for (int i = tid; i < 3840; i += 256) {
        int t = i >> 8, r = (i >> 4) & 15, c = i & 15;
        Bs2[i] = Pb[((t + 1) * 16 + r) * 256 + t * 16 + c];
    }
    __syncthreads();

    // ---- chol phase: wave 0 only, no barriers (wave-lockstep LDS order) ----
    if (tid < 64) {
        const int d = tid;
        for (int j = 0; j < 256; j++) {
            const int i = j + d;
            float s = 0.f;
            if (d < 32 && i < 256) {
                int bi = i >> 4, bj = j >> 4, pi = i & 15, pj = j & 15;
                float a;
                if (bi == bj)           a = Ds[bi * 256 + pi * 16 + pj];
                else if (bi == bj + 1)  a = Bs2[bj * 256 + pi * 16 + pj];
                else                    a = 0.f;

                float c[32], p[32];
                const float* cp = Lb + j * 32;
                #pragma unroll
                for (int q = 0; q < 8; q++)
                    *(float4*)(c + 4 * q) = *(const float4*)(cp + 4 * q);
                const float* pp = Lb + i * 32 + d;
                #pragma unroll
                for (int m = 1; m < 32; m++) p[m] = pp[m];

                float s0 = 0.f, s1 = 0.f, s2 = 0.f, s3 = 0.f;
                #pragma unroll
                for (int m = 1; m <= 28; m += 4) {
                    s0 = fmaf(p[m],     c[m],     s0);
                    s1 = fmaf(p[m + 1], c[m + 1], s1);
                    s2 = fmaf(p[m + 2], c[m + 2], s2);
                    s3 = fmaf(p[m + 3], c[m + 3], s3);
                }
                s0 = fmaf(p[29], c[29], s0);
                s1 = fmaf(p[30], c[30], s1);
                s2 = fmaf(p[31], c[31], s2);
                s = a - ((s0 + s1) + (s2 + s3));
            }
            float diag = __shfl(s, 0);
            float Ljj = sqrtf(diag);
            if (d == 0)                  Lb[j * 32] = Ljj;
            else if (d < 32 && i < 256)  Lb[i * 32 + d] = s / Ljj;
        }
    }
    __syncthreads();   // band complete & visible to all waves

    // ---- inv phase (Lb in place; rs aliases dead Ds) ----
    float* rs = Ds;
    const int j = tid;
    rs[j] = 1.f / Lb[j * 32];
    __syncthreads();

    float* covb = cov + (size_t)b * 65536;
    const int w = __builtin_amdgcn_readfirstlane(j >> 6);
    const int istart = w * 64;                 // 32-aligned, <= any j in wave

    for (int i = 0; i < istart; i++) covb[i * 256 + j] = 0.f;

    float g[32];
    #pragma unroll
    for (int q = 0; q < 32; q++) g[q] = 0.f;

    for (int c = istart; c < 256; c += 32) {
        #pragma unroll
        for (int u = 0; u < 32; u++) {
            const int i = c + u;                       // wave-uniform
            const float* Lr = Lb + i * 32;             // broadcast LDS reads
            float lrow[32];
            #pragma unroll
            for (int q = 0; q < 8; q++)
                *(float4*)(lrow + 4 * q) = *(const float4*)(Lr + 4 * q);
            float s0 = 0.f, s1 = 0.f, s2 = 0.f, s3 = 0.f;
            #pragma unroll
            for (int dd = 1; dd < 32; dd += 4) {
                s0 = fmaf(lrow[dd],     g[(u - dd) & 31],     s0);
                if (dd + 1 < 32) s1 = fmaf(lrow[dd + 1], g[(u - dd - 1) & 31], s1);
                if (dd + 2 < 32) s2 = fmaf(lrow[dd + 2], g[(u - dd - 2) & 31], s2);
                if (dd + 3 < 32) s3 = fmaf(lrow[dd + 3], g[(u - dd - 3) & 31], s3);
            }
            float s = (s0 + s1) + (s2 + s3);
            float gi = (((i == j) ? 1.f : 0.f) - s) * rs[i];
            g[u & 31] = gi;
            covb[i * 256 + j] = gi;                    // coalesced
        }
    }

    // ---- z phase: cov writes drained by barrier -> within-block visible ----
    __syncthreads();
    float* es = Ds + 256;
    es[tid] = eps[b * 256 + tid];
    __syncthreads();
    {
        const float4* row = (const float4*)(covb + (size_t)tid * 256);
        float s = 0.f;
        #pragma unroll 8
        for (int k = 0; k < 64; k++) {
            float4 v = row[k];
            s = fmaf(v.x, es[4 * k], s);
            s = fmaf(v.y, es[4 * k + 1], s);
            s = fmaf(v.z, es[4 * k + 2], s);
            s = fmaf(v.w, es[4 * k + 3], s);
        }
        z[b * 256 + tid] = mu[b * 256 + tid] + s;
    }
}

// ============================================================================
// fc_dec + mu_fix fused (unchanged)
// ============================================================================
__global__ __launch_bounds__(256) void fc_dec_mu(
    const float* __restrict__ z, const float* __restrict__ w,
    const float* __restrict__ bias, float* __restrict__ hd0,
    const float* __restrict__ h, const float* __restrict__ wmu,
    const float* __restrict__ bmu, float* __restrict__ mu)
{
    __shared__ float sh[1024];
    const int blk = blockIdx.x;
    if (blk < 1024) {
        // fc_dec
        const int b = blk >> 2;
        const int f = ((blk & 3) << 8) + threadIdx.x;
        sh[threadIdx.x] = z[b * 256 + threadIdx.x];
        __syncthreads();
        const float4* wr = (const float4*)(w + f * 256);
        float s = 0.f;
        #pragma unroll 8
        for (int k = 0; k < 64; k++) {
            float4 v = wr[k];
            s = fmaf(v.x, sh[4 * k], s);
            s = fmaf(v.y, sh[4 * k + 1], s);
            s = fmaf(v.z, sh[4 * k + 2], s);
            s = fmaf(v.w, sh[4 * k + 3], s);
        }
        hd0[b * 1024 + f] = s + bias[f];
    } else {
        // mu_fix
        const int b = blk - 1024, p = threadIdx.x;
        #pragma unroll
        for (int i = 0; i < 4; i++) sh[p + 256 * i] = h[b * 1024 + p + 256 * i];
        __syncthreads();
        const float4* wr = (const float4*)(wmu + p * 1024);
        float s = 0.f;
        #pragma unroll 8
        for (int k = 0; k < 256; k++) {
            float4 v = wr[k];
            s = fmaf(v.x, sh[4 * k], s);
            s = fmaf(v.y, sh[4 * k + 1], s);
            s = fmaf(v.z, sh[4 * k + 2], s);
            s = fmaf(v.w, sh[4 * k + 3], s);
        }
        mu[b * 256 + p] = s + bmu[p];
    }
}

// ============================================================================
// Decoder: EXACT round-6 form (234 µs measured, confirmed rounds 9/10).
// ============================================================================
__device__ __forceinline__ float eluf(float v) { return v > 0.f ? v : expf(v) - 1.f; }

template<int PY, int PX, int HIN, int WIN, class F>
__device__ __forceinline__ void for_taps(int ey, int ex, F&& f) {
    if (PY == 0) {
        if (PX == 0) { f(4, ey, ex, true); }
        else         { f(5, ey, ex, true); f(3, ey, ex + 1, ex + 1 < WIN); }
    } else {
        if (PX == 0) { f(7, ey, ex, true); f(1, ey + 1, ex, ey + 1 < HIN); }
        else {
            f(8, ey, ex, true);
            f(6, ey, ex + 1, ex + 1 < WIN);
            f(2, ey + 1, ex, ey + 1 < HIN);
            f(0, ey + 1, ex + 1, (ey + 1 < HIN) && (ex + 1 < WIN));
        }
    }
}

template<int OY>
__device__ __forceinline__ void t4_row(
    const float* __restrict__ wt4t, const float* __restrict__ bt4,
    const float* __restrict__ d1, float* __restrict__ d2, int co)
{
    float a0 = 0.f, a1 = 0.f, a2 = 0.f, a3 = 0.f;
    const float* wb = wt4t + co;
    for (int ci = 0; ci < 64; ci++) {
        const float* base = d1 + ci * 12;
        if (OY % 2 == 0) {
            float4 r = *(const float4*)(base + (OY / 2) * 4);
            float w10 = wb[3 * 4096 + ci * 64];
            float w11 = wb[4 * 4096 + ci * 64];
            float w12 = wb[5 * 4096 + ci * 64];
            a0 = fmaf(r.x, w11, a0);
            a1 = fmaf(r.x, w12, a1); a1 = fmaf(r.y, w10, a1);
            a2 = fmaf(r.y, w11, a2);
            a3 = fmaf(r.y, w12, a3); a3 = fmaf(r.z, w10, a3);
        } else {
            float4 ra = *(const float4*)(base + ((OY - 1) / 2) * 4);
            float4 rb = *(const float4*)(base + ((OY + 1) / 2) * 4);
            float w20 = wb[6 * 4096 + ci * 64], w21 = wb[7 * 4096 + ci * 64], w22 = wb[8 * 4096 + ci * 64];
            float w00 = wb[0 * 4096 + ci * 64], w01 = wb[1 * 4096 + ci * 64], w02 = wb[2 * 4096 + ci * 64];
            a0 = fmaf(ra.x, w21, a0); a0 = fmaf(rb.x, w01, a0);
            a1 = fmaf(ra.x, w22, a1); a1 = fmaf(ra.y, w20, a1);
            a1 = fmaf(rb.x, w02, a1); a1 = fmaf(rb.y, w00, a1);
            a2 = fmaf(ra.y, w21, a2); a2 = fmaf(rb.y, w01, a2);
            a3 = fmaf(ra.y, w22, a3); a3 = fmaf(ra.z, w20, a3);
            a3 = fmaf(rb.y, w02, a3); a3 = fmaf(rb.z, w00, a3);
        }
    }
    float b = bt4[co];
    float4 o = make_float4(eluf(a0 + b), eluf(a1 + b), eluf(a2 + b), eluf(a3 + b));
    *(float4*)(d2 + co * 44 + OY * 8) = o;
}

template<int M>
__device__ __forceinline__ void xrow(float* acc, const float* R, float w0, float w1, float w2)
{
    #pragma unroll
    for (int m = 0; m < M; m++) {
        acc[2 * m]     = fmaf(R[m], w1, acc[2 * m]);
        acc[2 * m + 1] = fmaf(R[m], w2, acc[2 * m + 1]);
        acc[2 * m + 1] = fmaf(R[m + 1], w0, acc[2 * m + 1]);
    }
}

__global__ __launch_bounds__(256, 4) void dec_fused(
    const float* __restrict__ hd0,
    const float* __restrict__ wt5t, const float* __restrict__ bt5,
    const float* __restrict__ wt4t, const float* __restrict__ bt4,
    const float* __restrict__ wt3t, const float* __restrict__ bt3,
    const float* __restrict__ wt2t, const float* __restrict__ bt2,
    const float* __restrict__ wt1,  const float* __restrict__ bt1,
    float* __restrict__ xr)
{
    __shared__ __align__(16) float smem[9664];   // 38656 B -> 4 blocks/CU
    float* d0  = smem;            // 64
    float* d1  = smem + 64;       // [64][3][4] pitch 12
    float* d2  = smem + 832;      // [64][44], rows pitch 8 (5 rows)
    float* scr = smem + 3648;     // [128][20]
    float* d3  = smem + 6208;     // [32][108], rows pitch 12 (9 rows)
    float* d4  = smem;            // [32][260] overlays A+scr+d3 after T2 barrier

    const int n = blockIdx.x, tid = threadIdx.x;

    for (int i = tid; i < 3584; i += 256) smem[64 + i] = 0.f;
    for (int i = tid; i < 3456; i += 256) d3[i] = 0.f;
    if (tid < 64) d0[tid] = hd0[n * 64 + tid];
    __syncthreads();

    // T5
    {
        const int co = tid & 63;
        const int wv = __builtin_amdgcn_readfirstlane(tid >> 6);
        const int oy = wv >> 1, ox = wv & 1;
        const int wk = (oy + 1) * 3 + (ox + 1);
        const float* wp = wt5t + wk * 4096 + co;
        float s = bt5[co];
        for (int ci = 0; ci < 64; ci++)
            s = fmaf(d0[ci], wp[ci * 64], s);
        d1[co * 12 + oy * 4 + ox] = eluf(s);
    }
    __syncthreads();

    // T4
    {
        const int co = tid & 63;
        const int oyw = __builtin_amdgcn_readfirstlane(tid >> 6);
        if (oyw == 0)      t4_row<0>(wt4t, bt4, d1, d2, co);
        else if (oyw == 1) t4_row<1>(wt4t, bt4, d1, d2, co);
        else if (oyw == 2) t4_row<2>(wt4t, bt4, d1, d2, co);
        else               t4_row<3>(wt4t, bt4, d1, d2, co);
    }
    __syncthreads();

    // T3
    {
        const int co = tid & 31, pr = (tid >> 5) & 3, cih = tid >> 7;
        const int e = (pr & 1) ? 7 - pr : pr;
        const int o = (pr & 1) ? pr : 7 - pr;
        const int iy_e = e >> 1, iy_o2 = (o - 1) >> 1, iy_o0 = (o + 1) >> 1;
        float acce[8] = {}, acco[8] = {};
        const float* wb = wt3t + co;
        for (int c = 0; c < 32; c++) {
            const int ci = cih * 32 + c;
            const float* base = d2 + ci * 44;
            float re[8], ro2[8], ro0[8];
            *(float4*)(re)      = *(const float4*)(base + iy_e * 8);
            *(float4*)(re + 4)  = *(const float4*)(base + iy_e * 8 + 4);
            *(float4*)(ro2)     = *(const float4*)(base + iy_o2 * 8);
            *(float4*)(ro2 + 4) = *(const float4*)(base + iy_o2 * 8 + 4);
            *(float4*)(ro0)     = *(const float4*)(base + iy_o0 * 8);
            *(float4*)(ro0 + 4) = *(const float4*)(base + iy_o0 * 8 + 4);
            float w10 = wb[3 * 2048 + ci * 32], w11 = wb[4 * 2048 + ci * 32], w12 = wb[5 * 2048 + ci * 32];
            float w20 = wb[6 * 2048 + ci * 32], w21 = wb[7 * 2048 + ci * 32], w22 = wb[8 * 2048 + ci * 32];
            float w00 = wb[0 * 2048 + ci * 32], w01 = wb[1 * 2048 + ci * 32], w02 = wb[2 * 2048 + ci * 32];
            xrow<4>(acce, re, w10, w11, w12);
            xrow<4>(acco, ro2, w20, w21, w22);
            xrow<4>(acco, ro0, w00, w01, w02);
        }
        if (cih == 1) {
            float* s = scr + (tid - 128) * 20;
            #pragma unroll
            for (int k = 0; k < 8; k++) { s[k] = acce[k]; s[8 + k] = acco[k]; }
        }
        __syncthreads();
        if (cih == 0) {
            const float* s = scr + tid * 20;
            const float b = bt3[co];
            float* oe = d3 + co * 108 + e * 12;
            float* oo = d3 + co * 108 + o * 12;
            #pragma unroll
            for (int k = 0; k < 8; k++) {
                oe[k] = eluf(acce[k] + s[k] + b);
                oo[k] = eluf(acco[k] + s[8 + k] + b);
            }
        }
    }
    __syncthreads();

    // T2 — register-staged output: accumulate (reads d3), barrier, store d4.
    {
        const int co = tid & 31, org = tid >> 5;
        float acc0[16] = {}, acc1[16] = {};
        const float* wb = wt2t + co;
        for (int ci = 0; ci < 32; ci++) {
            const float* base = d3 + ci * 108 + org * 12;
            float A[12], B[12];
            #pragma unroll
            for (int q = 0; q < 3; q++) {
                *(float4*)(A + 4 * q) = *(const float4*)(base + 4 * q);
                *(float4*)(B + 4 * q) = *(const float4*)(base + 12 + 4 * q);
            }
            float w10 = wb[3 * 1024 + ci * 32], w11 = wb[4 * 1024 + ci * 32], w12 = wb[5 * 1024 + ci * 32];
            float w20 = wb[6 * 1024 + ci * 32], w21 = wb[7 * 1024 + ci * 32], w22 = wb[8 * 1024 + ci * 32];
            float w00 = wb[0 * 1024 + ci * 32], w01 = wb[1 * 1024 + ci * 32], w02 = wb[2 * 1024 + ci * 32];
            xrow<8>(acc0, A, w10, w11, w12);
            xrow<8>(acc1, A, w20, w21, w22);
            xrow<8>(acc1, B, w00, w01, w02);
        }
        __syncthreads();   // all d3 reads drained -> d4 may overlay d3
        const float b = bt2[co];
        float* o0 = d4 + co * 260 + (2 * org) * 16;
        float* o1 = o0 + 16;
        #pragma unroll
        for (int q = 0; q < 4; q++) {
            float4 v0 = make_float4(eluf(acc0[4 * q] + b), eluf(acc0[4 * q + 1] + b),
                                    eluf(acc0[4 * q + 2] + b), eluf(acc0[4 * q + 3] + b));
            float4 v1 = make_float4(eluf(acc1[4 * q] + b), eluf(acc1[4 * q + 1] + b),
                                    eluf(acc1[4 * q + 2] + b), eluf(acc1[4 * q + 3] + b));
            *(float4*)(o0 + 4 * q) = v0;
            *(float4*)(o1 + 4 * q) = v1;
        }
    }
    __syncthreads();

    // T1 (exact round-6 form)
    {
        const int ey = tid >> 4, ex = tid & 15;
        const float bb = bt1[0];
        float* xi = xr + n * 1024;
        float acc[4] = {};
        for (int ci = 0; ci < 32; ci++) {
            const float* a = d4 + ci * 260;
            const float* w = wt1 + ci * 9;
            for_taps<0, 0, 16, 16>(ey, ex, [&](int wk, int iy, int ix, bool v) {
                acc[0] = fmaf(v ? a[iy * 16 + ix] : 0.f, w[wk], acc[0]); });
            for_taps<0, 1, 16, 16>(ey, ex, [&](int wk, int iy, int ix, bool v) {
                acc[1] = fmaf(v ? a[iy * 16 + ix] : 0.f, w[wk], acc[1]); });
            for_taps<1, 0, 16, 16>(ey, ex, [&](int wk, int iy, int ix, bool v) {
                acc[2] = fmaf(v ? a[iy * 16 + ix] : 0.f, w[wk], acc[2]); });
            for_taps<1, 1, 16, 16>(ey, ex, [&](int wk, int iy, int ix, bool v) {
                acc[3] = fmaf(v ? a[iy * 16 + ix] : 0.f, w[wk], acc[3]); });
        }
        xi[(2 * ey) * 32 + 2 * ex]         = 1.f / (1.f + expf(-(acc[0] + bb)));
        xi[(2 * ey) * 32 + 2 * ex + 1]     = 1.f / (1.f + expf(-(acc[1] + bb)));
        xi[(2 * ey + 1) * 32 + 2 * ex]     = 1.f / (1.f + expf(-(acc[2] + bb)));
        xi[(2 * ey + 1) * 32 + 2 * ex + 1] = 1.f / (1.f + expf(-(acc[3] + bb)));
    }
}

// ============================================================================
extern "C" void kernel_launch(void* const* d_in, const int* in_sizes, int n_in,
                              void* d_out, int out_size, void* d_ws, size_t ws_size,
                              hipStream_t stream)
{
    (void)in_sizes; (void)n_in; (void)out_size; (void)ws_size;
    const float* x    = (const float*)d_in[0];
    const float* eps  = (const float*)d_in[1];
    const float* w1 = (const float*)d_in[2];  const float* b1 = (const float*)d_in[3];
    const float* w2 = (const float*)d_in[4];  const float* b2 = (const float*)d_in[5];
    const float* w3 = (const float*)d_in[6];  const float* b3 = (const float*)d_in[7];
    const float* w4 = (const float*)d_in[8];  const float* b4 = (const float*)d_in[9];
    const float* w5 = (const float*)d_in[10]; const float* b5 = (const float*)d_in[11];
    const float* fc_mu_w = (const float*)d_in[12]; const float* fc_mu_b = (const float*)d_in[13];
    const float* fc_D_w  = (const float*)d_in[14]; const float* fc_D_b  = (const float*)d_in[15];
    const float* fc_B_w  = (const float*)d_in[16]; const float* fc_B_b  = (const float*)d_in[17];
    const float* fc_dec_w = (const float*)d_in[18]; const float* fc_dec_b = (const float*)d_in[19];
    const float* wt5 = (const float*)d_in[20]; const float* bt5 = (const float*)d_in[21];
    const float* wt4 = (const float*)d_in[22]; const float* bt4 = (const float*)d_in[23];
    const float* wt3 = (const float*)d_in[24]; const float* bt3 = (const float*)d_in[25];
    const float* wt2 = (const float*)d_in[26]; const float* bt2 = (const float*)d_in[27];
    const float* wt1 = (const float*)d_in[28]; const float* bt1 = (const float*)d_in[29];

    // workspace layout (floats)
    float* ws   = (float*)d_ws;
    float* h    = ws;                  // 262144  [4096][64]
    float* z    = ws + 2359296;        // 65536
    float* hd0  = ws + 2424832;        // 262144  [4096][64]
    float* wt5t = ws + 2686976;        // 36864   [9][64][64]
    float* wt4t = ws + 2723840;        // 36864   [9][64][64]
    float* wt3t = ws + 2760704;        // 18432   [9][64][32]
    float* wt2t = ws + 2779136;        // 9216    [9][32][32]
    float* w2t  = ws + 2788352;        // 9216    [9][32][32]
    float* w3t  = ws + 2797568;        // 18432   [9][32][64]
    float* w4t  = ws + 2816000;        // 36864   [9][64][64]
    float* w5t  = ws + 2852864;        // 36864   [9][64][64]

    // output layout: xr | mu | cov | Pm
    float* out = (float*)d_out;
    float* xr  = out;                 // 4194304
    float* mu  = out + 4194304;       // 65536
    float* cov = out + 4259840;       // 16777216
    float* Pm  = out + 21037056;      // 16777216

    prep_all<<<17176, 256, 0, stream>>>(wt5, wt4, wt3, wt2, w2, w3, w4, w5,
                                        wt5t, wt4t, wt3t, wt2t, w2t, w3t, w4t, w5t,
                                        (float4*)Pm);
    enc_fused<<<4096, 256, 0, stream>>>(x, w1, b1, w2t, b2, w3t, b3, w4t, b4, w5t, b5, h);
    fc_enc<<<dim3(128, 4), 256, 0, stream>>>(h, fc_mu_w, fc_mu_b, fc_D_w, fc_D_b,
                                             fc_B_w, fc_B_b, mu, Pm);
    chol_inv_z<<<256, 256, 0, stream>>>(Pm, cov, mu, eps, z);
    fc_dec_mu<<<1280, 256, 0, stream>>>(z, fc_dec_w, fc_dec_b, hd0,
                                        h, fc_mu_w, fc_mu_b, mu);
    dec_fused<<<4096, 256, 0, stream>>>(hd0, wt5t, bt5, wt4t, bt4, wt3t, bt3,
                                        wt2t, bt2, wt1, bt1, xr);
}